// Round 10
// baseline (199.331 us; speedup 1.0000x reference)
//
#include <hip/hip_runtime.h>
#include <math.h>

#define NV 6890
#define N3 20670       // NV*3
#define NJNT 24
#define NBETA 10
#define NPF 207
#define NJO 19
#define NBATCH 512
#define NJK 456        // NJO*NJNT
#define NJKP 512       // padded jk (GEMM N)
#define NCOEF 218      // [pf 207 | beta 10 | 1]
#define PROWSP 704     // padded P rows (GEMM M)
#define KPAD 6912      // 12 * 576
#define KSPLIT 12
#define KCH 576        // 9 * 64
#define CSTR 224       // pfc row stride
#define CSTRV 6912     // padded jrT/wT row stride (float4-safe)

// kA role boundaries
#define TRB 646        // ceil(NV*NJNT/256)
#define SJB 264        // 24*11
// kCm: 512*1728 short4 -> 3456 blocks
#define C4R 1728       // short4 per Cb row
// kPm role boundaries
#define PMA 5913       // 219 rows * 27 chunks
#define PMO 27         // ones-row chunks
#define PMZ 1323       // 49 pad rows * 27

typedef __attribute__((ext_vector_type(8))) short bfx8;
typedef __attribute__((ext_vector_type(4))) float fx4;

__constant__ int d_par[NJNT] = {0,0,0,0,1,2,3,4,5,6,7,8,9,9,9,12,13,14,16,17,18,19,20,21};
// ancestor path (root..j) per joint, -1 padded; max depth 9
__constant__ int d_path[NJNT][9] = {
  {0,-1,-1,-1,-1,-1,-1,-1,-1},
  {0,1,-1,-1,-1,-1,-1,-1,-1},
  {0,2,-1,-1,-1,-1,-1,-1,-1},
  {0,3,-1,-1,-1,-1,-1,-1,-1},
  {0,1,4,-1,-1,-1,-1,-1,-1},
  {0,2,5,-1,-1,-1,-1,-1,-1},
  {0,3,6,-1,-1,-1,-1,-1,-1},
  {0,1,4,7,-1,-1,-1,-1,-1},
  {0,2,5,8,-1,-1,-1,-1,-1},
  {0,3,6,9,-1,-1,-1,-1,-1},
  {0,1,4,7,10,-1,-1,-1,-1},
  {0,2,5,8,11,-1,-1,-1,-1},
  {0,3,6,9,12,-1,-1,-1,-1},
  {0,3,6,9,13,-1,-1,-1,-1},
  {0,3,6,9,14,-1,-1,-1,-1},
  {0,3,6,9,12,15,-1,-1,-1},
  {0,3,6,9,13,16,-1,-1,-1},
  {0,3,6,9,14,17,-1,-1,-1},
  {0,3,6,9,13,16,18,-1,-1},
  {0,3,6,9,14,17,19,-1,-1},
  {0,3,6,9,13,16,18,20,-1},
  {0,3,6,9,14,17,19,21,-1},
  {0,3,6,9,13,16,18,20,22},
  {0,3,6,9,14,17,19,21,23}};

__device__ inline short f2bf(float f) {
  union { float f; unsigned u; } x; x.f = f;
  unsigned r = (x.u + 0x7fffu + ((x.u >> 16) & 1u)) >> 16;
  return (short)r;
}

// ============ kA: transpose (padded-stride) || SJ || rodrigues ============
__global__ void __launch_bounds__(256) kA(const float* __restrict__ jr,
                                          const float* __restrict__ lbs,
                                          const float* __restrict__ Jreg,
                                          const float* __restrict__ sdirs,
                                          const float* __restrict__ vtmpl,
                                          const float* __restrict__ theta,
                                          const float* __restrict__ beta,
                                          float* __restrict__ jrT, float* __restrict__ wT,
                                          float* __restrict__ SJ, float* __restrict__ Rs,
                                          float* __restrict__ pfc) {
  __shared__ float red[4][3];
  int bx = blockIdx.x, tid = threadIdx.x;
  if (bx < TRB) {
    int idx = bx * 256 + tid;
    if (idx < NV * NJO)  { int v = idx / NJO,  j = idx - v * NJO;  jrT[(size_t)j * CSTRV + v] = jr[idx]; }
    if (idx < NV * NJNT) { int v = idx / NJNT, k = idx - v * NJNT; wT[(size_t)k * CSTRV + v]  = lbs[idx]; }
  } else if (bx < TRB + SJB) {
    int s = bx - TRB;
    int j = s % NJNT, k = s / NJNT;
    const float* src = (k < NBETA) ? (sdirs + (size_t)k * N3) : vtmpl;
    float a0 = 0.f, a1 = 0.f, a2 = 0.f;
    for (int v = tid; v < NV; v += 256) {
      float w = Jreg[v * NJNT + j];
      a0 += w * src[v * 3 + 0];
      a1 += w * src[v * 3 + 1];
      a2 += w * src[v * 3 + 2];
    }
    int lane = tid & 63, wid = tid >> 6;
#pragma unroll
    for (int s2 = 1; s2 < 64; s2 <<= 1) {
      a0 += __shfl_xor(a0, s2); a1 += __shfl_xor(a1, s2); a2 += __shfl_xor(a2, s2);
    }
    if (lane == 0) { red[wid][0] = a0; red[wid][1] = a1; red[wid][2] = a2; }
    __syncthreads();
    if (tid == 0) {
      float* o = SJ + (k * NJNT + j) * 3;
      o[0] = red[0][0] + red[1][0] + red[2][0] + red[3][0];
      o[1] = red[0][1] + red[1][1] + red[2][1] + red[3][1];
      o[2] = red[0][2] + red[1][2] + red[2][2] + red[3][2];
    }
  } else {
    int b = (bx - TRB - SJB) * 256 + tid;
    if (b >= NBATCH) return;
    for (int j = 0; j < NJNT; ++j) {
      float a0 = theta[b * 72 + j * 3 + 0];
      float a1 = theta[b * 72 + j * 3 + 1];
      float a2 = theta[b * 72 + j * 3 + 2];
      float e0 = a0 + 1e-8f, e1 = a1 + 1e-8f, e2 = a2 + 1e-8f;
      float ang = sqrtf(e0 * e0 + e1 * e1 + e2 * e2);
      float inv = 1.0f / ang;
      float h = 0.5f * ang;
      float w = cosf(h), s = sinf(h);
      float x = a0 * inv * s, y = a1 * inv * s, z = a2 * inv * s;
      float R[9];
      R[0] = w*w + x*x - y*y - z*z; R[1] = 2.f*(x*y - w*z); R[2] = 2.f*(x*z + w*y);
      R[3] = 2.f*(x*y + w*z); R[4] = w*w - x*x + y*y - z*z; R[5] = 2.f*(y*z - w*x);
      R[6] = 2.f*(x*z - w*y); R[7] = 2.f*(y*z + w*x); R[8] = w*w - x*x - y*y + z*z;
#pragma unroll
      for (int r = 0; r < 9; ++r) Rs[b * 216 + j * 9 + r] = R[r];
      if (j >= 1) {
#pragma unroll
        for (int r = 0; r < 9; ++r)
          pfc[b * CSTR + (j - 1) * 9 + r] = R[r] - ((r % 4 == 0) ? 1.0f : 0.0f);
      }
    }
#pragma unroll
    for (int i = 0; i < NBETA; ++i) pfc[b * CSTR + NPF + i] = beta[b * NBETA + i];
    pfc[b * CSTR + NPF + NBETA] = 1.0f;
  }
}

// ============ k_Jsmall ============
__global__ void k_Jsmall(const float* __restrict__ beta, const float* __restrict__ SJ,
                         float* __restrict__ J) {
  int idx = blockIdx.x * 256 + threadIdx.x;
  if (idx >= NBATCH * 72) return;
  int b = idx / 72, r = idx - b * 72;
  float acc = SJ[NBETA * 72 + r];
  const float* bb = beta + b * NBETA;
#pragma unroll
  for (int k = 0; k < NBETA; ++k) acc += bb[k] * SJ[k * 72 + r];
  J[idx] = acc;
}

// ============ k_chainP: parallel path-product chain; thread = (b, j) ============
__global__ void __launch_bounds__(256) k_chainP(const float* __restrict__ Rs,
                                                const float* __restrict__ Jin,
                                                float* __restrict__ A) {
  int idx = blockIdx.x * 256 + threadIdx.x;
  if (idx >= NBATCH * NJNT) return;
  int b = idx / NJNT, j = idx - b * NJNT;
  const float* Rb = Rs + b * 216;
  const float* Jb = Jin + b * 72;
  float T[12];
#pragma unroll
  for (int r = 0; r < 3; ++r) {
    T[r * 4 + 0] = Rb[r * 3 + 0];
    T[r * 4 + 1] = Rb[r * 3 + 1];
    T[r * 4 + 2] = Rb[r * 3 + 2];
    T[r * 4 + 3] = Jb[r];
  }
  for (int d = 1; d < 9; ++d) {
    int i = d_path[j][d];
    if (i < 0) break;
    int p = d_par[i];
    const float* R = Rb + i * 9;
    float R0 = R[0], R1 = R[1], R2 = R[2], R3 = R[3], R4 = R[4];
    float R5 = R[5], R6 = R[6], R7 = R[7], R8 = R[8];
    float t0 = Jb[i * 3 + 0] - Jb[p * 3 + 0];
    float t1 = Jb[i * 3 + 1] - Jb[p * 3 + 1];
    float t2 = Jb[i * 3 + 2] - Jb[p * 3 + 2];
#pragma unroll
    for (int r = 0; r < 3; ++r) {
      float a0 = T[r * 4 + 0], a1 = T[r * 4 + 1], a2 = T[r * 4 + 2];
      T[r * 4 + 0] = a0 * R0 + a1 * R3 + a2 * R6;
      T[r * 4 + 1] = a0 * R1 + a1 * R4 + a2 * R7;
      T[r * 4 + 2] = a0 * R2 + a1 * R5 + a2 * R8;
      T[r * 4 + 3] = a0 * t0 + a1 * t1 + a2 * t2 + T[r * 4 + 3];
    }
  }
  float jx = Jb[j * 3 + 0], jy = Jb[j * 3 + 1], jz = Jb[j * 3 + 2];
  float* Ab = A + b * 288 + j * 12;
#pragma unroll
  for (int r = 0; r < 3; ++r) {
    float o0 = T[r * 4 + 0], o1 = T[r * 4 + 1], o2 = T[r * 4 + 2];
    Ab[r * 4 + 0] = o0;
    Ab[r * 4 + 1] = o1;
    Ab[r * 4 + 2] = o2;
    Ab[r * 4 + 3] = T[r * 4 + 3] - (o0 * jx + o1 * jy + o2 * jz);
  }
}

// ============ kCm: one-shot; thread = one short4 of Cb ============
__global__ void __launch_bounds__(256) kCm(const float* __restrict__ jrT,
                                           const float* __restrict__ wT,
                                           short* __restrict__ Cb) {
  int idx = blockIdx.x * 256 + threadIdx.x;   // 3456*256 = 512*1728
  int jk = idx / C4R;
  int c4 = idx - jk * C4R;
  int v0 = c4 * 4;
  short4 o;
  if (jk < NJK) {
    int j = jk / NJNT, k = jk - j * NJNT;
    float4 a = *(const float4*)(jrT + (size_t)j * CSTRV + v0);
    float4 w = *(const float4*)(wT + (size_t)k * CSTRV + v0);
    o.x = (v0 + 0 < NV) ? f2bf(a.x * w.x) : (short)0;
    o.y = (v0 + 1 < NV) ? f2bf(a.y * w.y) : (short)0;
    o.z = (v0 + 2 < NV) ? f2bf(a.z * w.z) : (short)0;
    o.w = (v0 + 3 < NV) ? f2bf(a.w * w.w) : (short)0;
  } else {
    o.x = o.y = o.z = o.w = (short)0;
  }
  *(short4*)(Cb + (size_t)jk * KPAD + v0) = o;
}

// ============ kPm: one-shot; block = (src-row, 256-chunk); no LDS/barriers ============
__global__ void __launch_bounds__(256) kPm(const float* __restrict__ pdirs,
                                           const float* __restrict__ sdirs,
                                           const float* __restrict__ vtmpl,
                                           short* __restrict__ Pb) {
  int bx = blockIdx.x, tid = threadIdx.x;
  if (bx < PMA) {
    int s = bx / 27, g = bx - s * 27;
    const float* src; int base;
    if (s < 207)      { src = pdirs + (size_t)s * N3;         base = 3 * s; }
    else if (s < 217) { src = sdirs + (size_t)(s - 207) * N3; base = 621 + 3 * (s - 207); }
    else              { src = vtmpl;                           base = 651; }
    int v = g * 256 + tid;
    float x = 0.f, y = 0.f, z = 0.f;
    if (v < NV) { x = src[3 * v]; y = src[3 * v + 1]; z = src[3 * v + 2]; }
    Pb[(size_t)(base + 0) * KPAD + v] = f2bf(x);
    Pb[(size_t)(base + 1) * KPAD + v] = f2bf(y);
    Pb[(size_t)(base + 2) * KPAD + v] = f2bf(z);
  } else if (bx < PMA + PMO) {
    int g = bx - PMA;
    int v = g * 256 + tid;
    Pb[(size_t)654 * KPAD + v] = (v < NV) ? f2bf(1.0f) : (short)0;
  } else {
    int s = bx - PMA - PMO;
    int row = 655 + s / 27, g = s % 27;
    Pb[(size_t)row * KPAD + g * 256 + tid] = (short)0;
  }
}

// ============ MFMA GEMM: Dpart[z][m][n] = sum_k P[m][k]*C[n][k] ============
__global__ void __launch_bounds__(256) k_gemm(const short* __restrict__ Pb,
                                              const short* __restrict__ Cb,
                                              float* __restrict__ Dpart) {
  int m0 = blockIdx.x * 64;
  int n0 = blockIdx.y * 64;
  int kb0 = blockIdx.z * KCH;
  __shared__ __align__(16) short As[64 * 64];
  __shared__ __align__(16) short Bs[64 * 64];
  int t = threadIdx.x;
  int wid = t >> 6, lane = t & 63;
  int frow = wid * 16 + (lane & 15);
  int fgrp = lane >> 4;
  fx4 acc[4];
#pragma unroll
  for (int j = 0; j < 4; ++j)
#pragma unroll
    for (int r = 0; r < 4; ++r) acc[j][r] = 0.f;

  int c0 = t, c1 = t + 256;
  int row0 = c0 >> 3, g0 = c0 & 7, sw0 = g0 ^ (row0 & 7);
  int row1 = c1 >> 3, g1 = c1 & 7, sw1 = g1 ^ (row1 & 7);

  for (int kk = 0; kk < KCH / 64; ++kk) {
    int kb = kb0 + kk * 64;
    *(bfx8*)(As + row0 * 64 + sw0 * 8) = *(const bfx8*)(Pb + (size_t)(m0 + row0) * KPAD + kb + g0 * 8);
    *(bfx8*)(As + row1 * 64 + sw1 * 8) = *(const bfx8*)(Pb + (size_t)(m0 + row1) * KPAD + kb + g1 * 8);
    *(bfx8*)(Bs + row0 * 64 + sw0 * 8) = *(const bfx8*)(Cb + (size_t)(n0 + row0) * KPAD + kb + g0 * 8);
    *(bfx8*)(Bs + row1 * 64 + sw1 * 8) = *(const bfx8*)(Cb + (size_t)(n0 + row1) * KPAD + kb + g1 * 8);
    __syncthreads();
#pragma unroll
    for (int ks = 0; ks < 2; ++ks) {
      int ga = ks * 4 + fgrp;
      bfx8 a = *(const bfx8*)(As + frow * 64 + (ga ^ (frow & 7)) * 8);
#pragma unroll
      for (int j = 0; j < 4; ++j) {
        int bcol = j * 16 + (lane & 15);
        bfx8 b = *(const bfx8*)(Bs + bcol * 64 + (ga ^ (bcol & 7)) * 8);
        acc[j] = __builtin_amdgcn_mfma_f32_16x16x32_bf16(a, b, acc[j], 0, 0, 0);
      }
    }
    __syncthreads();
  }
  float* dst = Dpart + (size_t)blockIdx.z * PROWSP * NJKP
             + (size_t)(m0 + wid * 16 + (lane >> 4) * 4) * NJKP + n0 + (lane & 15);
#pragma unroll
  for (int j = 0; j < 4; ++j)
#pragma unroll
    for (int r = 0; r < 4; ++r)
      dst[(size_t)r * NJKP + j * 16] = acc[j][r];
}

// ============ reduce K-split partials (float4) ============
__global__ void k_redD(const float* __restrict__ Dpart, float* __restrict__ D) {
  int i = blockIdx.x * 256 + threadIdx.x;
  if (i >= PROWSP * NJKP / 4) return;
  const float4* dp = (const float4*)Dpart;
  float4 s = dp[i];
#pragma unroll
  for (int z = 1; z < KSPLIT; ++z) {
    float4 v = dp[(size_t)z * (PROWSP * NJKP / 4) + i];
    s.x += v.x; s.y += v.y; s.z += v.z; s.w += v.w;
  }
  ((float4*)D)[i] = s;
}

// ============ k_S4: LDS-staged S[b][jk][q] = sum_r pfc[b][r]*D[3r+q][jk] ============
// grid (8 jk-tiles, 64 b-tiles of 8). Stage D in 32-r chunks (96 rows x 64 jk = 24KB).
__global__ void __launch_bounds__(256) k_S4(const float* __restrict__ D,
                                            const float* __restrict__ pfc,
                                            float* __restrict__ S) {
  int n0 = blockIdx.x * 64;
  int b0 = blockIdx.y * 8;
  int tid = threadIdx.x;
  __shared__ float cf[8][NCOEF + 2];
  __shared__ float Ds[96 * 64];
  for (int i = tid; i < 8 * NCOEF; i += 256) {
    int b = i / NCOEF, r = i - b * NCOEF;
    cf[b][r] = pfc[(b0 + b) * CSTR + r];
  }
  int jk = tid & 63;
  int bg = (tid >> 6) * 2;
  float a00=0.f,a01=0.f,a02=0.f,a10=0.f,a11=0.f,a12=0.f;
  for (int rc = 0; rc < 7; ++rc) {
    int r0 = rc * 32;
    __syncthreads();
    // stage rows [3*r0, 3*r0+96) x [n0, n0+64): 1536 float4, 6 per thread
#pragma unroll
    for (int it = 0; it < 6; ++it) {
      int i = tid + it * 256;
      int row = i >> 4, col4 = i & 15;
      *(float4*)(Ds + row * 64 + col4 * 4) =
        *(const float4*)(D + (size_t)(3 * r0 + row) * NJKP + n0 + col4 * 4);
    }
    __syncthreads();
    int rcnt = (rc == 6) ? (NCOEF - 192) : 32;
    for (int rr = 0; rr < rcnt; ++rr) {
      float d0 = Ds[(rr * 3 + 0) * 64 + jk];
      float d1 = Ds[(rr * 3 + 1) * 64 + jk];
      float d2 = Ds[(rr * 3 + 2) * 64 + jk];
      float c0 = cf[bg + 0][r0 + rr];
      float c1 = cf[bg + 1][r0 + rr];
      a00 += c0 * d0; a01 += c0 * d1; a02 += c0 * d2;
      a10 += c1 * d0; a11 += c1 * d1; a12 += c1 * d2;
    }
  }
  int jkg = n0 + jk;
  if (jkg < NJK) {
    float* o0 = S + ((size_t)(b0 + bg + 0) * NJK + jkg) * 3;
    float* o1 = S + ((size_t)(b0 + bg + 1) * NJK + jkg) * 3;
    o0[0] = a00; o0[1] = a01; o0[2] = a02;
    o1[0] = a10; o1[1] = a11; o1[2] = a12;
  }
}

// ============ final: joints[b,j,c] = sum_k A[b,k,c,:].[S, c0] ============
__global__ void k_final(const float* __restrict__ S, const float* __restrict__ D,
                        const float* __restrict__ A, float* __restrict__ out) {
  int idx = blockIdx.x * 256 + threadIdx.x;
  if (idx >= NBATCH * NJO * 3) return;
  int b = idx / 57, r = idx - b * 57;
  int j = r / 3, c = r - j * 3;
  const float* c0 = D + (size_t)654 * NJKP + j * NJNT;
  float acc = 0.f;
#pragma unroll
  for (int k = 0; k < NJNT; ++k) {
    const float* Ar = A + b * 288 + k * 12 + c * 4;
    const float* Sr = S + ((size_t)b * NJK + j * NJNT + k) * 3;
    acc += Ar[0] * Sr[0] + Ar[1] * Sr[1] + Ar[2] * Sr[2] + Ar[3] * c0[k];
  }
  out[idx] = acc;
}

extern "C" void kernel_launch(void* const* d_in, const int* in_sizes, int n_in,
                              void* d_out, int out_size, void* d_ws, size_t ws_size,
                              hipStream_t stream) {
  const float* beta  = (const float*)d_in[0];
  const float* theta = (const float*)d_in[1];
  const float* vtmpl = (const float*)d_in[2];
  const float* sdirs = (const float*)d_in[3];
  const float* Jreg  = (const float*)d_in[4];
  const float* pdirs = (const float*)d_in[5];
  const float* lbs   = (const float*)d_in[6];
  const float* jreg2 = (const float*)d_in[7];
  float* out = (float*)d_out;

  float* ws    = (float*)d_ws;
  short* Cb    = (short*)ws;                              // 512*6912 bf16
  short* Pb    = Cb + (size_t)NJKP * KPAD;                // 704*6912 bf16
  float* Dpart = (float*)(Pb + (size_t)PROWSP * KPAD);    // 12*704*512 f32
  float* D     = Dpart + (size_t)KSPLIT * PROWSP * NJKP;  // 704*512
  float* S     = D     + (size_t)PROWSP * NJKP;           // 512*456*3
  float* pfc   = S     + (size_t)NBATCH * NJK * 3;        // 512*224
  float* Rs    = pfc   + (size_t)NBATCH * CSTR;           // 512*216
  float* Jout  = Rs    + (size_t)NBATCH * 216;            // 512*72
  float* A     = Jout  + (size_t)NBATCH * 72;             // 512*288
  float* jrT   = A     + (size_t)NBATCH * 288;            // 19*6912 (padded)
  float* wT    = jrT   + (size_t)NJO * CSTRV;             // 24*6912 (padded)
  float* SJ    = wT    + (size_t)NJNT * CSTRV;            // 11*72

  kA<<<dim3(TRB + SJB + 2), 256, 0, stream>>>(jreg2, lbs, Jreg, sdirs, vtmpl, theta, beta,
                                              jrT, wT, SJ, Rs, pfc);
  k_Jsmall<<<dim3((NBATCH * 72 + 255) / 256), 256, 0, stream>>>(beta, SJ, Jout);
  k_chainP<<<dim3((NBATCH * NJNT + 255) / 256), 256, 0, stream>>>(Rs, Jout, A);
  kCm<<<dim3(NJKP * C4R / 256), 256, 0, stream>>>(jrT, wT, Cb);
  kPm<<<dim3(PMA + PMO + PMZ), 256, 0, stream>>>(pdirs, sdirs, vtmpl, Pb);
  k_gemm<<<dim3(PROWSP / 64, NJKP / 64, KSPLIT), 256, 0, stream>>>(Pb, Cb, Dpart);
  k_redD<<<dim3(PROWSP * NJKP / 4 / 256), 256, 0, stream>>>(Dpart, D);
  k_S4<<<dim3(NJKP / 64, NBATCH / 8), 256, 0, stream>>>(D, pfc, S);
  k_final<<<dim3((NBATCH * NJO * 3 + 255) / 256), 256, 0, stream>>>(S, D, A, out);
}

// Round 11
// 143.465 us; speedup vs baseline: 1.3894x; 1.3894x over previous
//
#include <hip/hip_runtime.h>
#include <math.h>

#define NV 6890
#define N3 20670       // NV*3
#define NJNT 24
#define NBETA 10
#define NPF 207
#define NJO 19
#define NBATCH 512
#define NJK 456        // NJO*NJNT
#define NJKP 512       // padded jk (GEMM N)
#define NCOEF 218      // [pf 207 | beta 10 | 1]
#define PROWSP 704     // padded P rows (GEMM M)
#define KPAD 6912      // 12 * 576
#define KSPLIT 12
#define KCH 576        // 9 * 64
#define CSTR 224       // pfc row stride
#define CSTRV 6912     // padded jrT/wT row stride (float4-safe)

// kA role boundaries
#define TRB 646        // ceil(NV*NJNT/256)
#define SJB 264        // 24*11
// kCm: 512*1728 short4 -> 3456 blocks
#define C4R 1728       // short4 per Cb row
// kPm role boundaries
#define PMA 5913       // 219 rows * 27 chunks
#define PMO 27         // ones-row chunks
#define PMZ 1323       // 49 pad rows * 27
// k_S5 r-split
#define RSP 4
#define RCH 56         // 4*56 = 224 >= 218

typedef __attribute__((ext_vector_type(8))) short bfx8;
typedef __attribute__((ext_vector_type(4))) float fx4;

__constant__ int d_par[NJNT] = {0,0,0,0,1,2,3,4,5,6,7,8,9,9,9,12,13,14,16,17,18,19,20,21};
// ancestor path (root..j) per joint, -1 padded; max depth 9
__constant__ int d_path[NJNT][9] = {
  {0,-1,-1,-1,-1,-1,-1,-1,-1},
  {0,1,-1,-1,-1,-1,-1,-1,-1},
  {0,2,-1,-1,-1,-1,-1,-1,-1},
  {0,3,-1,-1,-1,-1,-1,-1,-1},
  {0,1,4,-1,-1,-1,-1,-1,-1},
  {0,2,5,-1,-1,-1,-1,-1,-1},
  {0,3,6,-1,-1,-1,-1,-1,-1},
  {0,1,4,7,-1,-1,-1,-1,-1},
  {0,2,5,8,-1,-1,-1,-1,-1},
  {0,3,6,9,-1,-1,-1,-1,-1},
  {0,1,4,7,10,-1,-1,-1,-1},
  {0,2,5,8,11,-1,-1,-1,-1},
  {0,3,6,9,12,-1,-1,-1,-1},
  {0,3,6,9,13,-1,-1,-1,-1},
  {0,3,6,9,14,-1,-1,-1,-1},
  {0,3,6,9,12,15,-1,-1,-1},
  {0,3,6,9,13,16,-1,-1,-1},
  {0,3,6,9,14,17,-1,-1,-1},
  {0,3,6,9,13,16,18,-1,-1},
  {0,3,6,9,14,17,19,-1,-1},
  {0,3,6,9,13,16,18,20,-1},
  {0,3,6,9,14,17,19,21,-1},
  {0,3,6,9,13,16,18,20,22},
  {0,3,6,9,14,17,19,21,23}};

__device__ inline short f2bf(float f) {
  union { float f; unsigned u; } x; x.f = f;
  unsigned r = (x.u + 0x7fffu + ((x.u >> 16) & 1u)) >> 16;
  return (short)r;
}

// ============ kA: transpose (padded-stride) || SJ || rodrigues ============
__global__ void __launch_bounds__(256) kA(const float* __restrict__ jr,
                                          const float* __restrict__ lbs,
                                          const float* __restrict__ Jreg,
                                          const float* __restrict__ sdirs,
                                          const float* __restrict__ vtmpl,
                                          const float* __restrict__ theta,
                                          const float* __restrict__ beta,
                                          float* __restrict__ jrT, float* __restrict__ wT,
                                          float* __restrict__ SJ, float* __restrict__ Rs,
                                          float* __restrict__ pfc) {
  __shared__ float red[4][3];
  int bx = blockIdx.x, tid = threadIdx.x;
  if (bx < TRB) {
    int idx = bx * 256 + tid;
    if (idx < NV * NJO)  { int v = idx / NJO,  j = idx - v * NJO;  jrT[(size_t)j * CSTRV + v] = jr[idx]; }
    if (idx < NV * NJNT) { int v = idx / NJNT, k = idx - v * NJNT; wT[(size_t)k * CSTRV + v]  = lbs[idx]; }
  } else if (bx < TRB + SJB) {
    int s = bx - TRB;
    int j = s % NJNT, k = s / NJNT;
    const float* src = (k < NBETA) ? (sdirs + (size_t)k * N3) : vtmpl;
    float a0 = 0.f, a1 = 0.f, a2 = 0.f;
    for (int v = tid; v < NV; v += 256) {
      float w = Jreg[v * NJNT + j];
      a0 += w * src[v * 3 + 0];
      a1 += w * src[v * 3 + 1];
      a2 += w * src[v * 3 + 2];
    }
    int lane = tid & 63, wid = tid >> 6;
#pragma unroll
    for (int s2 = 1; s2 < 64; s2 <<= 1) {
      a0 += __shfl_xor(a0, s2); a1 += __shfl_xor(a1, s2); a2 += __shfl_xor(a2, s2);
    }
    if (lane == 0) { red[wid][0] = a0; red[wid][1] = a1; red[wid][2] = a2; }
    __syncthreads();
    if (tid == 0) {
      float* o = SJ + (k * NJNT + j) * 3;
      o[0] = red[0][0] + red[1][0] + red[2][0] + red[3][0];
      o[1] = red[0][1] + red[1][1] + red[2][1] + red[3][1];
      o[2] = red[0][2] + red[1][2] + red[2][2] + red[3][2];
    }
  } else {
    int b = (bx - TRB - SJB) * 256 + tid;
    if (b >= NBATCH) return;
    for (int j = 0; j < NJNT; ++j) {
      float a0 = theta[b * 72 + j * 3 + 0];
      float a1 = theta[b * 72 + j * 3 + 1];
      float a2 = theta[b * 72 + j * 3 + 2];
      float e0 = a0 + 1e-8f, e1 = a1 + 1e-8f, e2 = a2 + 1e-8f;
      float ang = sqrtf(e0 * e0 + e1 * e1 + e2 * e2);
      float inv = 1.0f / ang;
      float h = 0.5f * ang;
      float w = cosf(h), s = sinf(h);
      float x = a0 * inv * s, y = a1 * inv * s, z = a2 * inv * s;
      float R[9];
      R[0] = w*w + x*x - y*y - z*z; R[1] = 2.f*(x*y - w*z); R[2] = 2.f*(x*z + w*y);
      R[3] = 2.f*(x*y + w*z); R[4] = w*w - x*x + y*y - z*z; R[5] = 2.f*(y*z - w*x);
      R[6] = 2.f*(x*z - w*y); R[7] = 2.f*(y*z + w*x); R[8] = w*w - x*x - y*y + z*z;
#pragma unroll
      for (int r = 0; r < 9; ++r) Rs[b * 216 + j * 9 + r] = R[r];
      if (j >= 1) {
#pragma unroll
        for (int r = 0; r < 9; ++r)
          pfc[b * CSTR + (j - 1) * 9 + r] = R[r] - ((r % 4 == 0) ? 1.0f : 0.0f);
      }
    }
#pragma unroll
    for (int i = 0; i < NBETA; ++i) pfc[b * CSTR + NPF + i] = beta[b * NBETA + i];
    pfc[b * CSTR + NPF + NBETA] = 1.0f;
  }
}

// ============ k_Jsmall ============
__global__ void k_Jsmall(const float* __restrict__ beta, const float* __restrict__ SJ,
                         float* __restrict__ J) {
  int idx = blockIdx.x * 256 + threadIdx.x;
  if (idx >= NBATCH * 72) return;
  int b = idx / 72, r = idx - b * 72;
  float acc = SJ[NBETA * 72 + r];
  const float* bb = beta + b * NBETA;
#pragma unroll
  for (int k = 0; k < NBETA; ++k) acc += bb[k] * SJ[k * 72 + r];
  J[idx] = acc;
}

// ============ k_chainP: parallel path-product chain; thread = (b, j) ============
__global__ void __launch_bounds__(256) k_chainP(const float* __restrict__ Rs,
                                                const float* __restrict__ Jin,
                                                float* __restrict__ A) {
  int idx = blockIdx.x * 256 + threadIdx.x;
  if (idx >= NBATCH * NJNT) return;
  int b = idx / NJNT, j = idx - b * NJNT;
  const float* Rb = Rs + b * 216;
  const float* Jb = Jin + b * 72;
  float T[12];
#pragma unroll
  for (int r = 0; r < 3; ++r) {
    T[r * 4 + 0] = Rb[r * 3 + 0];
    T[r * 4 + 1] = Rb[r * 3 + 1];
    T[r * 4 + 2] = Rb[r * 3 + 2];
    T[r * 4 + 3] = Jb[r];
  }
  for (int d = 1; d < 9; ++d) {
    int i = d_path[j][d];
    if (i < 0) break;
    int p = d_par[i];
    const float* R = Rb + i * 9;
    float R0 = R[0], R1 = R[1], R2 = R[2], R3 = R[3], R4 = R[4];
    float R5 = R[5], R6 = R[6], R7 = R[7], R8 = R[8];
    float t0 = Jb[i * 3 + 0] - Jb[p * 3 + 0];
    float t1 = Jb[i * 3 + 1] - Jb[p * 3 + 1];
    float t2 = Jb[i * 3 + 2] - Jb[p * 3 + 2];
#pragma unroll
    for (int r = 0; r < 3; ++r) {
      float a0 = T[r * 4 + 0], a1 = T[r * 4 + 1], a2 = T[r * 4 + 2];
      T[r * 4 + 0] = a0 * R0 + a1 * R3 + a2 * R6;
      T[r * 4 + 1] = a0 * R1 + a1 * R4 + a2 * R7;
      T[r * 4 + 2] = a0 * R2 + a1 * R5 + a2 * R8;
      T[r * 4 + 3] = a0 * t0 + a1 * t1 + a2 * t2 + T[r * 4 + 3];
    }
  }
  float jx = Jb[j * 3 + 0], jy = Jb[j * 3 + 1], jz = Jb[j * 3 + 2];
  float* Ab = A + b * 288 + j * 12;
#pragma unroll
  for (int r = 0; r < 3; ++r) {
    float o0 = T[r * 4 + 0], o1 = T[r * 4 + 1], o2 = T[r * 4 + 2];
    Ab[r * 4 + 0] = o0;
    Ab[r * 4 + 1] = o1;
    Ab[r * 4 + 2] = o2;
    Ab[r * 4 + 3] = T[r * 4 + 3] - (o0 * jx + o1 * jy + o2 * jz);
  }
}

// ============ kCm: one-shot; thread = one short4 of Cb ============
__global__ void __launch_bounds__(256) kCm(const float* __restrict__ jrT,
                                           const float* __restrict__ wT,
                                           short* __restrict__ Cb) {
  int idx = blockIdx.x * 256 + threadIdx.x;   // 3456*256 = 512*1728
  int jk = idx / C4R;
  int c4 = idx - jk * C4R;
  int v0 = c4 * 4;
  short4 o;
  if (jk < NJK) {
    int j = jk / NJNT, k = jk - j * NJNT;
    float4 a = *(const float4*)(jrT + (size_t)j * CSTRV + v0);
    float4 w = *(const float4*)(wT + (size_t)k * CSTRV + v0);
    o.x = (v0 + 0 < NV) ? f2bf(a.x * w.x) : (short)0;
    o.y = (v0 + 1 < NV) ? f2bf(a.y * w.y) : (short)0;
    o.z = (v0 + 2 < NV) ? f2bf(a.z * w.z) : (short)0;
    o.w = (v0 + 3 < NV) ? f2bf(a.w * w.w) : (short)0;
  } else {
    o.x = o.y = o.z = o.w = (short)0;
  }
  *(short4*)(Cb + (size_t)jk * KPAD + v0) = o;
}

// ============ kPm: one-shot; block = (src-row, 256-chunk); no LDS/barriers ============
__global__ void __launch_bounds__(256) kPm(const float* __restrict__ pdirs,
                                           const float* __restrict__ sdirs,
                                           const float* __restrict__ vtmpl,
                                           short* __restrict__ Pb) {
  int bx = blockIdx.x, tid = threadIdx.x;
  if (bx < PMA) {
    int s = bx / 27, g = bx - s * 27;
    const float* src; int base;
    if (s < 207)      { src = pdirs + (size_t)s * N3;         base = 3 * s; }
    else if (s < 217) { src = sdirs + (size_t)(s - 207) * N3; base = 621 + 3 * (s - 207); }
    else              { src = vtmpl;                           base = 651; }
    int v = g * 256 + tid;
    float x = 0.f, y = 0.f, z = 0.f;
    if (v < NV) { x = src[3 * v]; y = src[3 * v + 1]; z = src[3 * v + 2]; }
    Pb[(size_t)(base + 0) * KPAD + v] = f2bf(x);
    Pb[(size_t)(base + 1) * KPAD + v] = f2bf(y);
    Pb[(size_t)(base + 2) * KPAD + v] = f2bf(z);
  } else if (bx < PMA + PMO) {
    int g = bx - PMA;
    int v = g * 256 + tid;
    Pb[(size_t)654 * KPAD + v] = (v < NV) ? f2bf(1.0f) : (short)0;
  } else {
    int s = bx - PMA - PMO;
    int row = 655 + s / 27, g = s % 27;
    Pb[(size_t)row * KPAD + g * 256 + tid] = (short)0;
  }
}

// ============ MFMA GEMM: Dpart[z][m][n] = sum_k P[m][k]*C[n][k] ============
__global__ void __launch_bounds__(256) k_gemm(const short* __restrict__ Pb,
                                              const short* __restrict__ Cb,
                                              float* __restrict__ Dpart) {
  int m0 = blockIdx.x * 64;
  int n0 = blockIdx.y * 64;
  int kb0 = blockIdx.z * KCH;
  __shared__ __align__(16) short As[64 * 64];
  __shared__ __align__(16) short Bs[64 * 64];
  int t = threadIdx.x;
  int wid = t >> 6, lane = t & 63;
  int frow = wid * 16 + (lane & 15);
  int fgrp = lane >> 4;
  fx4 acc[4];
#pragma unroll
  for (int j = 0; j < 4; ++j)
#pragma unroll
    for (int r = 0; r < 4; ++r) acc[j][r] = 0.f;

  int c0 = t, c1 = t + 256;
  int row0 = c0 >> 3, g0 = c0 & 7, sw0 = g0 ^ (row0 & 7);
  int row1 = c1 >> 3, g1 = c1 & 7, sw1 = g1 ^ (row1 & 7);

  for (int kk = 0; kk < KCH / 64; ++kk) {
    int kb = kb0 + kk * 64;
    *(bfx8*)(As + row0 * 64 + sw0 * 8) = *(const bfx8*)(Pb + (size_t)(m0 + row0) * KPAD + kb + g0 * 8);
    *(bfx8*)(As + row1 * 64 + sw1 * 8) = *(const bfx8*)(Pb + (size_t)(m0 + row1) * KPAD + kb + g1 * 8);
    *(bfx8*)(Bs + row0 * 64 + sw0 * 8) = *(const bfx8*)(Cb + (size_t)(n0 + row0) * KPAD + kb + g0 * 8);
    *(bfx8*)(Bs + row1 * 64 + sw1 * 8) = *(const bfx8*)(Cb + (size_t)(n0 + row1) * KPAD + kb + g1 * 8);
    __syncthreads();
#pragma unroll
    for (int ks = 0; ks < 2; ++ks) {
      int ga = ks * 4 + fgrp;
      bfx8 a = *(const bfx8*)(As + frow * 64 + (ga ^ (frow & 7)) * 8);
#pragma unroll
      for (int j = 0; j < 4; ++j) {
        int bcol = j * 16 + (lane & 15);
        bfx8 b = *(const bfx8*)(Bs + bcol * 64 + (ga ^ (bcol & 7)) * 8);
        acc[j] = __builtin_amdgcn_mfma_f32_16x16x32_bf16(a, b, acc[j], 0, 0, 0);
      }
    }
    __syncthreads();
  }
  float* dst = Dpart + (size_t)blockIdx.z * PROWSP * NJKP
             + (size_t)(m0 + wid * 16 + (lane >> 4) * 4) * NJKP + n0 + (lane & 15);
#pragma unroll
  for (int j = 0; j < 4; ++j)
#pragma unroll
    for (int r = 0; r < 4; ++r)
      dst[(size_t)r * NJKP + j * 16] = acc[j][r];
}

// ============ reduce K-split partials (float4) ============
__global__ void k_redD(const float* __restrict__ Dpart, float* __restrict__ D) {
  int i = blockIdx.x * 256 + threadIdx.x;
  if (i >= PROWSP * NJKP / 4) return;
  const float4* dp = (const float4*)Dpart;
  float4 s = dp[i];
#pragma unroll
  for (int z = 1; z < KSPLIT; ++z) {
    float4 v = dp[(size_t)z * (PROWSP * NJKP / 4) + i];
    s.x += v.x; s.y += v.y; s.z += v.z; s.w += v.w;
  }
  ((float4*)D)[i] = s;
}

// ============ k_S5: r-split atomic; S[b][jk][q] += sum_{r in chunk} pfc[b][r]*D[3r+q][jk]
// grid (8 jk, 64 b, 4 r). 256 thr = 64 jk-lanes x 4 wave-groups x 2 b. No LDS, tiny VGPR.
__global__ void __launch_bounds__(256) k_S5(const float* __restrict__ D,
                                            const float* __restrict__ pfc,
                                            float* __restrict__ S) {
  int n0 = blockIdx.x * 64;
  int b0 = blockIdx.y * 8;
  int r0 = blockIdx.z * RCH;
  int r1 = r0 + RCH; if (r1 > NCOEF) r1 = NCOEF;
  int tid = threadIdx.x;
  int jk = tid & 63;
  int bg = (tid >> 6) * 2;          // wave-uniform
  const float* Dp  = D + n0 + jk;
  const float* c0p = pfc + (size_t)(b0 + bg + 0) * CSTR;  // wave-uniform base
  const float* c1p = pfc + (size_t)(b0 + bg + 1) * CSTR;
  float a00 = 0.f, a01 = 0.f, a02 = 0.f, a10 = 0.f, a11 = 0.f, a12 = 0.f;
#pragma unroll 2
  for (int r = r0; r < r1; ++r) {
    float d0 = Dp[(size_t)(3 * r + 0) * NJKP];
    float d1 = Dp[(size_t)(3 * r + 1) * NJKP];
    float d2 = Dp[(size_t)(3 * r + 2) * NJKP];
    float c0 = c0p[r];               // s_load (uniform)
    float c1 = c1p[r];
    a00 += c0 * d0; a01 += c0 * d1; a02 += c0 * d2;
    a10 += c1 * d0; a11 += c1 * d1; a12 += c1 * d2;
  }
  int jkg = n0 + jk;
  if (jkg < NJK) {
    float* o0 = S + ((size_t)(b0 + bg + 0) * NJK + jkg) * 3;
    float* o1 = S + ((size_t)(b0 + bg + 1) * NJK + jkg) * 3;
    atomicAdd(o0 + 0, a00); atomicAdd(o0 + 1, a01); atomicAdd(o0 + 2, a02);
    atomicAdd(o1 + 0, a10); atomicAdd(o1 + 1, a11); atomicAdd(o1 + 2, a12);
  }
}

// ============ final: joints[b,j,c] = sum_k A[b,k,c,:].[S, c0] ============
__global__ void k_final(const float* __restrict__ S, const float* __restrict__ D,
                        const float* __restrict__ A, float* __restrict__ out) {
  int idx = blockIdx.x * 256 + threadIdx.x;
  if (idx >= NBATCH * NJO * 3) return;
  int b = idx / 57, r = idx - b * 57;
  int j = r / 3, c = r - j * 3;
  const float* c0 = D + (size_t)654 * NJKP + j * NJNT;
  float acc = 0.f;
#pragma unroll
  for (int k = 0; k < NJNT; ++k) {
    const float* Ar = A + b * 288 + k * 12 + c * 4;
    const float* Sr = S + ((size_t)b * NJK + j * NJNT + k) * 3;
    acc += Ar[0] * Sr[0] + Ar[1] * Sr[1] + Ar[2] * Sr[2] + Ar[3] * c0[k];
  }
  out[idx] = acc;
}

extern "C" void kernel_launch(void* const* d_in, const int* in_sizes, int n_in,
                              void* d_out, int out_size, void* d_ws, size_t ws_size,
                              hipStream_t stream) {
  const float* beta  = (const float*)d_in[0];
  const float* theta = (const float*)d_in[1];
  const float* vtmpl = (const float*)d_in[2];
  const float* sdirs = (const float*)d_in[3];
  const float* Jreg  = (const float*)d_in[4];
  const float* pdirs = (const float*)d_in[5];
  const float* lbs   = (const float*)d_in[6];
  const float* jreg2 = (const float*)d_in[7];
  float* out = (float*)d_out;

  float* ws    = (float*)d_ws;
  short* Cb    = (short*)ws;                              // 512*6912 bf16
  short* Pb    = Cb + (size_t)NJKP * KPAD;                // 704*6912 bf16
  float* Dpart = (float*)(Pb + (size_t)PROWSP * KPAD);    // 12*704*512 f32
  float* D     = Dpart + (size_t)KSPLIT * PROWSP * NJKP;  // 704*512
  float* S     = D     + (size_t)PROWSP * NJKP;           // 512*456*3
  float* pfc   = S     + (size_t)NBATCH * NJK * 3;        // 512*224
  float* Rs    = pfc   + (size_t)NBATCH * CSTR;           // 512*216
  float* Jout  = Rs    + (size_t)NBATCH * 216;            // 512*72
  float* A     = Jout  + (size_t)NBATCH * 72;             // 512*288
  float* jrT   = A     + (size_t)NBATCH * 288;            // 19*6912 (padded)
  float* wT    = jrT   + (size_t)NJO * CSTRV;             // 24*6912 (padded)
  float* SJ    = wT    + (size_t)NJNT * CSTRV;            // 11*72

  hipMemsetAsync(S, 0, (size_t)NBATCH * NJK * 3 * sizeof(float), stream);
  kA<<<dim3(TRB + SJB + 2), 256, 0, stream>>>(jreg2, lbs, Jreg, sdirs, vtmpl, theta, beta,
                                              jrT, wT, SJ, Rs, pfc);
  k_Jsmall<<<dim3((NBATCH * 72 + 255) / 256), 256, 0, stream>>>(beta, SJ, Jout);
  k_chainP<<<dim3((NBATCH * NJNT + 255) / 256), 256, 0, stream>>>(Rs, Jout, A);
  kCm<<<dim3(NJKP * C4R / 256), 256, 0, stream>>>(jrT, wT, Cb);
  kPm<<<dim3(PMA + PMO + PMZ), 256, 0, stream>>>(pdirs, sdirs, vtmpl, Pb);
  k_gemm<<<dim3(PROWSP / 64, NJKP / 64, KSPLIT), 256, 0, stream>>>(Pb, Cb, Dpart);
  k_redD<<<dim3(PROWSP * NJKP / 4 / 256), 256, 0, stream>>>(Dpart, D);
  k_S5<<<dim3(NJKP / 64, NBATCH / 8, RSP), 256, 0, stream>>>(D, pfc, S);
  k_final<<<dim3((NBATCH * NJO * 3 + 255) / 256), 256, 0, stream>>>(S, D, A, out);
}

// Round 12
// 125.759 us; speedup vs baseline: 1.5850x; 1.1408x over previous
//
#include <hip/hip_runtime.h>
#include <math.h>

#define NV 6890
#define N3 20670       // NV*3
#define NJNT 24
#define NBETA 10
#define NPF 207
#define NJO 19
#define NBATCH 512
#define NJK 456        // NJO*NJNT
#define NJKP 512       // padded jk (GEMM N)
#define NCOEF 218      // [pf 207 | beta 10 | 1]
#define PROWSP 704     // padded P rows (GEMM M)
#define KPAD 6912      // 12 * 576
#define KSPLIT 12
#define KCH 576        // 9 * 64
#define CSTR 224       // pfc row stride
#define CSTRV 6912     // padded jrT/wT row stride (float4-safe)

// kA role boundaries
#define TRB 646        // ceil(NV*NJNT/256)
#define SJB 264        // 24*11
// kCm: 512*1728 short4 -> 3456 blocks
#define C4R 1728       // short4 per Cb row
// kPm role boundaries
#define PMA 5913       // 219 rows * 27 chunks
#define PMO 27         // ones-row chunks
#define PMZ 1323       // 49 pad rows * 27
// k_S5b r-split
#define RSP 4
#define RCH 56         // 4*56 = 224 >= 218
#define SSTRIDE ((size_t)NBATCH * 3 * NJK)   // one Spart slice

typedef __attribute__((ext_vector_type(8))) short bfx8;
typedef __attribute__((ext_vector_type(4))) float fx4;

__constant__ int d_par[NJNT] = {0,0,0,0,1,2,3,4,5,6,7,8,9,9,9,12,13,14,16,17,18,19,20,21};
// ancestor path (root..j) per joint, -1 padded; max depth 9
__constant__ int d_path[NJNT][9] = {
  {0,-1,-1,-1,-1,-1,-1,-1,-1},
  {0,1,-1,-1,-1,-1,-1,-1,-1},
  {0,2,-1,-1,-1,-1,-1,-1,-1},
  {0,3,-1,-1,-1,-1,-1,-1,-1},
  {0,1,4,-1,-1,-1,-1,-1,-1},
  {0,2,5,-1,-1,-1,-1,-1,-1},
  {0,3,6,-1,-1,-1,-1,-1,-1},
  {0,1,4,7,-1,-1,-1,-1,-1},
  {0,2,5,8,-1,-1,-1,-1,-1},
  {0,3,6,9,-1,-1,-1,-1,-1},
  {0,1,4,7,10,-1,-1,-1,-1},
  {0,2,5,8,11,-1,-1,-1,-1},
  {0,3,6,9,12,-1,-1,-1,-1},
  {0,3,6,9,13,-1,-1,-1,-1},
  {0,3,6,9,14,-1,-1,-1,-1},
  {0,3,6,9,12,15,-1,-1,-1},
  {0,3,6,9,13,16,-1,-1,-1},
  {0,3,6,9,14,17,-1,-1,-1},
  {0,3,6,9,13,16,18,-1,-1},
  {0,3,6,9,14,17,19,-1,-1},
  {0,3,6,9,13,16,18,20,-1},
  {0,3,6,9,14,17,19,21,-1},
  {0,3,6,9,13,16,18,20,22},
  {0,3,6,9,14,17,19,21,23}};

__device__ inline short f2bf(float f) {
  union { float f; unsigned u; } x; x.f = f;
  unsigned r = (x.u + 0x7fffu + ((x.u >> 16) & 1u)) >> 16;
  return (short)r;
}

// ============ kA: transpose (padded-stride) || SJ || rodrigues ============
__global__ void __launch_bounds__(256) kA(const float* __restrict__ jr,
                                          const float* __restrict__ lbs,
                                          const float* __restrict__ Jreg,
                                          const float* __restrict__ sdirs,
                                          const float* __restrict__ vtmpl,
                                          const float* __restrict__ theta,
                                          const float* __restrict__ beta,
                                          float* __restrict__ jrT, float* __restrict__ wT,
                                          float* __restrict__ SJ, float* __restrict__ Rs,
                                          float* __restrict__ pfc) {
  __shared__ float red[4][3];
  int bx = blockIdx.x, tid = threadIdx.x;
  if (bx < TRB) {
    int idx = bx * 256 + tid;
    if (idx < NV * NJO)  { int v = idx / NJO,  j = idx - v * NJO;  jrT[(size_t)j * CSTRV + v] = jr[idx]; }
    if (idx < NV * NJNT) { int v = idx / NJNT, k = idx - v * NJNT; wT[(size_t)k * CSTRV + v]  = lbs[idx]; }
  } else if (bx < TRB + SJB) {
    int s = bx - TRB;
    int j = s % NJNT, k = s / NJNT;
    const float* src = (k < NBETA) ? (sdirs + (size_t)k * N3) : vtmpl;
    float a0 = 0.f, a1 = 0.f, a2 = 0.f;
    for (int v = tid; v < NV; v += 256) {
      float w = Jreg[v * NJNT + j];
      a0 += w * src[v * 3 + 0];
      a1 += w * src[v * 3 + 1];
      a2 += w * src[v * 3 + 2];
    }
    int lane = tid & 63, wid = tid >> 6;
#pragma unroll
    for (int s2 = 1; s2 < 64; s2 <<= 1) {
      a0 += __shfl_xor(a0, s2); a1 += __shfl_xor(a1, s2); a2 += __shfl_xor(a2, s2);
    }
    if (lane == 0) { red[wid][0] = a0; red[wid][1] = a1; red[wid][2] = a2; }
    __syncthreads();
    if (tid == 0) {
      float* o = SJ + (k * NJNT + j) * 3;
      o[0] = red[0][0] + red[1][0] + red[2][0] + red[3][0];
      o[1] = red[0][1] + red[1][1] + red[2][1] + red[3][1];
      o[2] = red[0][2] + red[1][2] + red[2][2] + red[3][2];
    }
  } else {
    int b = (bx - TRB - SJB) * 256 + tid;
    if (b >= NBATCH) return;
    for (int j = 0; j < NJNT; ++j) {
      float a0 = theta[b * 72 + j * 3 + 0];
      float a1 = theta[b * 72 + j * 3 + 1];
      float a2 = theta[b * 72 + j * 3 + 2];
      float e0 = a0 + 1e-8f, e1 = a1 + 1e-8f, e2 = a2 + 1e-8f;
      float ang = sqrtf(e0 * e0 + e1 * e1 + e2 * e2);
      float inv = 1.0f / ang;
      float h = 0.5f * ang;
      float w = cosf(h), s = sinf(h);
      float x = a0 * inv * s, y = a1 * inv * s, z = a2 * inv * s;
      float R[9];
      R[0] = w*w + x*x - y*y - z*z; R[1] = 2.f*(x*y - w*z); R[2] = 2.f*(x*z + w*y);
      R[3] = 2.f*(x*y + w*z); R[4] = w*w - x*x + y*y - z*z; R[5] = 2.f*(y*z - w*x);
      R[6] = 2.f*(x*z - w*y); R[7] = 2.f*(y*z + w*x); R[8] = w*w - x*x - y*y + z*z;
#pragma unroll
      for (int r = 0; r < 9; ++r) Rs[b * 216 + j * 9 + r] = R[r];
      if (j >= 1) {
#pragma unroll
        for (int r = 0; r < 9; ++r)
          pfc[b * CSTR + (j - 1) * 9 + r] = R[r] - ((r % 4 == 0) ? 1.0f : 0.0f);
      }
    }
#pragma unroll
    for (int i = 0; i < NBETA; ++i) pfc[b * CSTR + NPF + i] = beta[b * NBETA + i];
    pfc[b * CSTR + NPF + NBETA] = 1.0f;
  }
}

// ============ k_Jsmall ============
__global__ void k_Jsmall(const float* __restrict__ beta, const float* __restrict__ SJ,
                         float* __restrict__ J) {
  int idx = blockIdx.x * 256 + threadIdx.x;
  if (idx >= NBATCH * 72) return;
  int b = idx / 72, r = idx - b * 72;
  float acc = SJ[NBETA * 72 + r];
  const float* bb = beta + b * NBETA;
#pragma unroll
  for (int k = 0; k < NBETA; ++k) acc += bb[k] * SJ[k * 72 + r];
  J[idx] = acc;
}

// ============ k_chainP: parallel path-product chain; thread = (b, j) ============
__global__ void __launch_bounds__(256) k_chainP(const float* __restrict__ Rs,
                                                const float* __restrict__ Jin,
                                                float* __restrict__ A) {
  int idx = blockIdx.x * 256 + threadIdx.x;
  if (idx >= NBATCH * NJNT) return;
  int b = idx / NJNT, j = idx - b * NJNT;
  const float* Rb = Rs + b * 216;
  const float* Jb = Jin + b * 72;
  float T[12];
#pragma unroll
  for (int r = 0; r < 3; ++r) {
    T[r * 4 + 0] = Rb[r * 3 + 0];
    T[r * 4 + 1] = Rb[r * 3 + 1];
    T[r * 4 + 2] = Rb[r * 3 + 2];
    T[r * 4 + 3] = Jb[r];
  }
  for (int d = 1; d < 9; ++d) {
    int i = d_path[j][d];
    if (i < 0) break;
    int p = d_par[i];
    const float* R = Rb + i * 9;
    float R0 = R[0], R1 = R[1], R2 = R[2], R3 = R[3], R4 = R[4];
    float R5 = R[5], R6 = R[6], R7 = R[7], R8 = R[8];
    float t0 = Jb[i * 3 + 0] - Jb[p * 3 + 0];
    float t1 = Jb[i * 3 + 1] - Jb[p * 3 + 1];
    float t2 = Jb[i * 3 + 2] - Jb[p * 3 + 2];
#pragma unroll
    for (int r = 0; r < 3; ++r) {
      float a0 = T[r * 4 + 0], a1 = T[r * 4 + 1], a2 = T[r * 4 + 2];
      T[r * 4 + 0] = a0 * R0 + a1 * R3 + a2 * R6;
      T[r * 4 + 1] = a0 * R1 + a1 * R4 + a2 * R7;
      T[r * 4 + 2] = a0 * R2 + a1 * R5 + a2 * R8;
      T[r * 4 + 3] = a0 * t0 + a1 * t1 + a2 * t2 + T[r * 4 + 3];
    }
  }
  float jx = Jb[j * 3 + 0], jy = Jb[j * 3 + 1], jz = Jb[j * 3 + 2];
  float* Ab = A + b * 288 + j * 12;
#pragma unroll
  for (int r = 0; r < 3; ++r) {
    float o0 = T[r * 4 + 0], o1 = T[r * 4 + 1], o2 = T[r * 4 + 2];
    Ab[r * 4 + 0] = o0;
    Ab[r * 4 + 1] = o1;
    Ab[r * 4 + 2] = o2;
    Ab[r * 4 + 3] = T[r * 4 + 3] - (o0 * jx + o1 * jy + o2 * jz);
  }
}

// ============ kCm: one-shot; thread = one short4 of Cb ============
__global__ void __launch_bounds__(256) kCm(const float* __restrict__ jrT,
                                           const float* __restrict__ wT,
                                           short* __restrict__ Cb) {
  int idx = blockIdx.x * 256 + threadIdx.x;   // 3456*256 = 512*1728
  int jk = idx / C4R;
  int c4 = idx - jk * C4R;
  int v0 = c4 * 4;
  short4 o;
  if (jk < NJK) {
    int j = jk / NJNT, k = jk - j * NJNT;
    float4 a = *(const float4*)(jrT + (size_t)j * CSTRV + v0);
    float4 w = *(const float4*)(wT + (size_t)k * CSTRV + v0);
    o.x = (v0 + 0 < NV) ? f2bf(a.x * w.x) : (short)0;
    o.y = (v0 + 1 < NV) ? f2bf(a.y * w.y) : (short)0;
    o.z = (v0 + 2 < NV) ? f2bf(a.z * w.z) : (short)0;
    o.w = (v0 + 3 < NV) ? f2bf(a.w * w.w) : (short)0;
  } else {
    o.x = o.y = o.z = o.w = (short)0;
  }
  *(short4*)(Cb + (size_t)jk * KPAD + v0) = o;
}

// ============ kPm: one-shot; block = (src-row, 256-chunk); no LDS/barriers ============
__global__ void __launch_bounds__(256) kPm(const float* __restrict__ pdirs,
                                           const float* __restrict__ sdirs,
                                           const float* __restrict__ vtmpl,
                                           short* __restrict__ Pb) {
  int bx = blockIdx.x, tid = threadIdx.x;
  if (bx < PMA) {
    int s = bx / 27, g = bx - s * 27;
    const float* src; int base;
    if (s < 207)      { src = pdirs + (size_t)s * N3;         base = 3 * s; }
    else if (s < 217) { src = sdirs + (size_t)(s - 207) * N3; base = 621 + 3 * (s - 207); }
    else              { src = vtmpl;                           base = 651; }
    int v = g * 256 + tid;
    float x = 0.f, y = 0.f, z = 0.f;
    if (v < NV) { x = src[3 * v]; y = src[3 * v + 1]; z = src[3 * v + 2]; }
    Pb[(size_t)(base + 0) * KPAD + v] = f2bf(x);
    Pb[(size_t)(base + 1) * KPAD + v] = f2bf(y);
    Pb[(size_t)(base + 2) * KPAD + v] = f2bf(z);
  } else if (bx < PMA + PMO) {
    int g = bx - PMA;
    int v = g * 256 + tid;
    Pb[(size_t)654 * KPAD + v] = (v < NV) ? f2bf(1.0f) : (short)0;
  } else {
    int s = bx - PMA - PMO;
    int row = 655 + s / 27, g = s % 27;
    Pb[(size_t)row * KPAD + g * 256 + tid] = (short)0;
  }
}

// ============ MFMA GEMM: Dpart[z][m][n] = sum_k P[m][k]*C[n][k] ============
__global__ void __launch_bounds__(256) k_gemm(const short* __restrict__ Pb,
                                              const short* __restrict__ Cb,
                                              float* __restrict__ Dpart) {
  int m0 = blockIdx.x * 64;
  int n0 = blockIdx.y * 64;
  int kb0 = blockIdx.z * KCH;
  __shared__ __align__(16) short As[64 * 64];
  __shared__ __align__(16) short Bs[64 * 64];
  int t = threadIdx.x;
  int wid = t >> 6, lane = t & 63;
  int frow = wid * 16 + (lane & 15);
  int fgrp = lane >> 4;
  fx4 acc[4];
#pragma unroll
  for (int j = 0; j < 4; ++j)
#pragma unroll
    for (int r = 0; r < 4; ++r) acc[j][r] = 0.f;

  int c0 = t, c1 = t + 256;
  int row0 = c0 >> 3, g0 = c0 & 7, sw0 = g0 ^ (row0 & 7);
  int row1 = c1 >> 3, g1 = c1 & 7, sw1 = g1 ^ (row1 & 7);

  for (int kk = 0; kk < KCH / 64; ++kk) {
    int kb = kb0 + kk * 64;
    *(bfx8*)(As + row0 * 64 + sw0 * 8) = *(const bfx8*)(Pb + (size_t)(m0 + row0) * KPAD + kb + g0 * 8);
    *(bfx8*)(As + row1 * 64 + sw1 * 8) = *(const bfx8*)(Pb + (size_t)(m0 + row1) * KPAD + kb + g1 * 8);
    *(bfx8*)(Bs + row0 * 64 + sw0 * 8) = *(const bfx8*)(Cb + (size_t)(n0 + row0) * KPAD + kb + g0 * 8);
    *(bfx8*)(Bs + row1 * 64 + sw1 * 8) = *(const bfx8*)(Cb + (size_t)(n0 + row1) * KPAD + kb + g1 * 8);
    __syncthreads();
#pragma unroll
    for (int ks = 0; ks < 2; ++ks) {
      int ga = ks * 4 + fgrp;
      bfx8 a = *(const bfx8*)(As + frow * 64 + (ga ^ (frow & 7)) * 8);
#pragma unroll
      for (int j = 0; j < 4; ++j) {
        int bcol = j * 16 + (lane & 15);
        bfx8 b = *(const bfx8*)(Bs + bcol * 64 + (ga ^ (bcol & 7)) * 8);
        acc[j] = __builtin_amdgcn_mfma_f32_16x16x32_bf16(a, b, acc[j], 0, 0, 0);
      }
    }
    __syncthreads();
  }
  float* dst = Dpart + (size_t)blockIdx.z * PROWSP * NJKP
             + (size_t)(m0 + wid * 16 + (lane >> 4) * 4) * NJKP + n0 + (lane & 15);
#pragma unroll
  for (int j = 0; j < 4; ++j)
#pragma unroll
    for (int r = 0; r < 4; ++r)
      dst[(size_t)r * NJKP + j * 16] = acc[j][r];
}

// ============ reduce K-split partials (float4) ============
__global__ void k_redD(const float* __restrict__ Dpart, float* __restrict__ D) {
  int i = blockIdx.x * 256 + threadIdx.x;
  if (i >= PROWSP * NJKP / 4) return;
  const float4* dp = (const float4*)Dpart;
  float4 s = dp[i];
#pragma unroll
  for (int z = 1; z < KSPLIT; ++z) {
    float4 v = dp[(size_t)z * (PROWSP * NJKP / 4) + i];
    s.x += v.x; s.y += v.y; s.z += v.z; s.w += v.w;
  }
  ((float4*)D)[i] = s;
}

// ============ k_S5b: r-split, NO atomics; Spart[z][b][q][jk] (SoA-q, coalesced) ======
// grid (8 jk, 64 b, 4 r). 256 thr = 64 jk-lanes x 4 wave-groups x 2 b.
__global__ void __launch_bounds__(256) k_S5b(const float* __restrict__ D,
                                             const float* __restrict__ pfc,
                                             float* __restrict__ Spart) {
  int n0 = blockIdx.x * 64;
  int b0 = blockIdx.y * 8;
  int r0 = blockIdx.z * RCH;
  int r1 = r0 + RCH; if (r1 > NCOEF) r1 = NCOEF;
  int tid = threadIdx.x;
  int jk = tid & 63;
  int bg = (tid >> 6) * 2;          // wave-uniform
  const float* Dp  = D + n0 + jk;
  const float* c0p = pfc + (size_t)(b0 + bg + 0) * CSTR;  // wave-uniform base
  const float* c1p = pfc + (size_t)(b0 + bg + 1) * CSTR;
  float a00 = 0.f, a01 = 0.f, a02 = 0.f, a10 = 0.f, a11 = 0.f, a12 = 0.f;
#pragma unroll 2
  for (int r = r0; r < r1; ++r) {
    float d0 = Dp[(size_t)(3 * r + 0) * NJKP];
    float d1 = Dp[(size_t)(3 * r + 1) * NJKP];
    float d2 = Dp[(size_t)(3 * r + 2) * NJKP];
    float c0 = c0p[r];               // s_load (uniform)
    float c1 = c1p[r];
    a00 += c0 * d0; a01 += c0 * d1; a02 += c0 * d2;
    a10 += c1 * d0; a11 += c1 * d1; a12 += c1 * d2;
  }
  int jkg = n0 + jk;
  if (jkg < NJK) {
    float* base = Spart + (size_t)blockIdx.z * SSTRIDE;
    float* o0 = base + ((size_t)(b0 + bg + 0) * 3) * NJK + jkg;
    float* o1 = base + ((size_t)(b0 + bg + 1) * 3) * NJK + jkg;
    o0[0 * NJK] = a00; o0[1 * NJK] = a01; o0[2 * NJK] = a02;
    o1[0 * NJK] = a10; o1[1 * NJK] = a11; o1[2 * NJK] = a12;
  }
}

// ============ k_redS: fold RSP partials into S[b][q][jk] (float4) ============
__global__ void k_redS(const float* __restrict__ Spart, float* __restrict__ S) {
  int i = blockIdx.x * 256 + threadIdx.x;
  if (i >= (int)(SSTRIDE / 4)) return;
  const float4* sp = (const float4*)Spart;
  float4 s = sp[i];
#pragma unroll
  for (int z = 1; z < RSP; ++z) {
    float4 v = sp[(size_t)z * (SSTRIDE / 4) + i];
    s.x += v.x; s.y += v.y; s.z += v.z; s.w += v.w;
  }
  ((float4*)S)[i] = s;
}

// ============ final: joints[b,j,c] = sum_k A[b,k,c,:].[S, c0]; S is [b][q][jk] ========
__global__ void k_final(const float* __restrict__ S, const float* __restrict__ D,
                        const float* __restrict__ A, float* __restrict__ out) {
  int idx = blockIdx.x * 256 + threadIdx.x;
  if (idx >= NBATCH * NJO * 3) return;
  int b = idx / 57, r = idx - b * 57;
  int j = r / 3, c = r - j * 3;
  const float* c0 = D + (size_t)654 * NJKP + j * NJNT;
  const float* S0 = S + ((size_t)b * 3 + 0) * NJK + j * NJNT;
  const float* S1 = S + ((size_t)b * 3 + 1) * NJK + j * NJNT;
  const float* S2 = S + ((size_t)b * 3 + 2) * NJK + j * NJNT;
  float acc = 0.f;
#pragma unroll
  for (int k = 0; k < NJNT; ++k) {
    const float* Ar = A + b * 288 + k * 12 + c * 4;
    acc += Ar[0] * S0[k] + Ar[1] * S1[k] + Ar[2] * S2[k] + Ar[3] * c0[k];
  }
  out[idx] = acc;
}

extern "C" void kernel_launch(void* const* d_in, const int* in_sizes, int n_in,
                              void* d_out, int out_size, void* d_ws, size_t ws_size,
                              hipStream_t stream) {
  const float* beta  = (const float*)d_in[0];
  const float* theta = (const float*)d_in[1];
  const float* vtmpl = (const float*)d_in[2];
  const float* sdirs = (const float*)d_in[3];
  const float* Jreg  = (const float*)d_in[4];
  const float* pdirs = (const float*)d_in[5];
  const float* lbs   = (const float*)d_in[6];
  const float* jreg2 = (const float*)d_in[7];
  float* out = (float*)d_out;

  float* ws    = (float*)d_ws;
  short* Cb    = (short*)ws;                              // 512*6912 bf16
  short* Pb    = Cb + (size_t)NJKP * KPAD;                // 704*6912 bf16
  float* Dpart = (float*)(Pb + (size_t)PROWSP * KPAD);    // 12*704*512 f32
  float* D     = Dpart + (size_t)KSPLIT * PROWSP * NJKP;  // 704*512
  float* S     = D     + (size_t)PROWSP * NJKP;           // 512*3*456
  float* Spart = S     + SSTRIDE;                         // 4*512*3*456
  float* pfc   = Spart + (size_t)RSP * SSTRIDE;           // 512*224
  float* Rs    = pfc   + (size_t)NBATCH * CSTR;           // 512*216
  float* Jout  = Rs    + (size_t)NBATCH * 216;            // 512*72
  float* A     = Jout  + (size_t)NBATCH * 72;             // 512*288
  float* jrT   = A     + (size_t)NBATCH * 288;            // 19*6912 (padded)
  float* wT    = jrT   + (size_t)NJO * CSTRV;             // 24*6912 (padded)
  float* SJ    = wT    + (size_t)NJNT * CSTRV;            // 11*72

  kA<<<dim3(TRB + SJB + 2), 256, 0, stream>>>(jreg2, lbs, Jreg, sdirs, vtmpl, theta, beta,
                                              jrT, wT, SJ, Rs, pfc);
  k_Jsmall<<<dim3((NBATCH * 72 + 255) / 256), 256, 0, stream>>>(beta, SJ, Jout);
  k_chainP<<<dim3((NBATCH * NJNT + 255) / 256), 256, 0, stream>>>(Rs, Jout, A);
  kCm<<<dim3(NJKP * C4R / 256), 256, 0, stream>>>(jrT, wT, Cb);
  kPm<<<dim3(PMA + PMO + PMZ), 256, 0, stream>>>(pdirs, sdirs, vtmpl, Pb);
  k_gemm<<<dim3(PROWSP / 64, NJKP / 64, KSPLIT), 256, 0, stream>>>(Pb, Cb, Dpart);
  k_redD<<<dim3(PROWSP * NJKP / 4 / 256), 256, 0, stream>>>(Dpart, D);
  k_S5b<<<dim3(NJKP / 64, NBATCH / 8, RSP), 256, 0, stream>>>(D, pfc, Spart);
  k_redS<<<dim3((SSTRIDE / 4 + 255) / 256), 256, 0, stream>>>(Spart, S);
  k_final<<<dim3((NBATCH * NJO * 3 + 255) / 256), 256, 0, stream>>>(S, D, A, out);
}

// Round 14
// 96.159 us; speedup vs baseline: 2.0729x; 1.3078x over previous
//
#include <hip/hip_runtime.h>
#include <math.h>

#define NV 6890
#define N3 20670       // NV*3
#define NJNT 24
#define NBETA 10
#define NPF 207
#define NJO 19
#define NBATCH 512
#define NJK 456        // NJO*NJNT
#define NJKP 512       // padded jk (GEMM N)
#define NCOEF 218      // [pf 207 | beta 10 | 1]
#define PROWSP 704     // padded P rows (GEMM M)
#define KPAD 6912      // 12 * 576
#define KSPLIT 12
#define KCH 576        // 9 * 64
#define CSTR 224       // pfc row stride
#define CSTRV 6912     // padded jrT/wT row stride (float4-safe)

// kA role boundaries
#define TRB 646        // transpose: ceil(NV*NJNT/256)
#define RODB 48        // rodrigues: NBATCH*NJNT/256
#define SJB 264        // SJ: 24*11
#define PMA 5913       // Pm rows: 219 * 27 chunks
#define PMO 27         // ones-row chunks
#define PMZ 1323       // 49 pad rows * 27
#define PMT (PMA + PMO + PMZ)
// kCm
#define C4R 1728       // short4 per Cb row
// k_S5b r-split
#define RSP 4
#define RCH 56         // 4*56 = 224 >= 218
#define SSTRIDE ((size_t)NBATCH * 3 * NJK)   // one Spart slice

typedef __attribute__((ext_vector_type(8))) short bfx8;
typedef __attribute__((ext_vector_type(4))) float fx4;

__constant__ int d_par[NJNT] = {0,0,0,0,1,2,3,4,5,6,7,8,9,9,9,12,13,14,16,17,18,19,20,21};
// ancestor path (root..j) per joint, -1 padded; max depth 9
__constant__ int d_path[NJNT][9] = {
  {0,-1,-1,-1,-1,-1,-1,-1,-1},
  {0,1,-1,-1,-1,-1,-1,-1,-1},
  {0,2,-1,-1,-1,-1,-1,-1,-1},
  {0,3,-1,-1,-1,-1,-1,-1,-1},
  {0,1,4,-1,-1,-1,-1,-1,-1},
  {0,2,5,-1,-1,-1,-1,-1,-1},
  {0,3,6,-1,-1,-1,-1,-1,-1},
  {0,1,4,7,-1,-1,-1,-1,-1},
  {0,2,5,8,-1,-1,-1,-1,-1},
  {0,3,6,9,-1,-1,-1,-1,-1},
  {0,1,4,7,10,-1,-1,-1,-1},
  {0,2,5,8,11,-1,-1,-1,-1},
  {0,3,6,9,12,-1,-1,-1,-1},
  {0,3,6,9,13,-1,-1,-1,-1},
  {0,3,6,9,14,-1,-1,-1,-1},
  {0,3,6,9,12,15,-1,-1,-1},
  {0,3,6,9,13,16,-1,-1,-1},
  {0,3,6,9,14,17,-1,-1,-1},
  {0,3,6,9,13,16,18,-1,-1},
  {0,3,6,9,14,17,19,-1,-1},
  {0,3,6,9,13,16,18,20,-1},
  {0,3,6,9,14,17,19,21,-1},
  {0,3,6,9,13,16,18,20,22},
  {0,3,6,9,14,17,19,21,23}};

__device__ inline short f2bf(float f) {
  union { float f; unsigned u; } x; x.f = f;
  unsigned r = (x.u + 0x7fffu + ((x.u >> 16) & 1u)) >> 16;
  return (short)r;
}

// ============ kA: transpose || rodrigues(b,j) || SJ(reads INPUT Jreg — no intra-
// dispatch dependency) || Pm.  All roles consume only kernel INPUTS. ============
__global__ void __launch_bounds__(256) kA(const float* __restrict__ jr,
                                          const float* __restrict__ lbs,
                                          const float* __restrict__ Jreg,
                                          const float* __restrict__ sdirs,
                                          const float* __restrict__ vtmpl,
                                          const float* __restrict__ theta,
                                          const float* __restrict__ beta,
                                          const float* __restrict__ pdirs,
                                          float* __restrict__ jrT, float* __restrict__ wT,
                                          float* __restrict__ SJ, float* __restrict__ Rs,
                                          float* __restrict__ pfc,
                                          short* __restrict__ Pb) {
  __shared__ float red[4][3];
  int bx = blockIdx.x, tid = threadIdx.x;
  if (bx < TRB) {
    // ---- transposes (coalesced reads, scattered row writes) ----
    int idx = bx * 256 + tid;
    if (idx < NV * NJO)  { int v = idx / NJO,  j = idx - v * NJO;  jrT[(size_t)j * CSTRV + v] = jr[idx]; }
    if (idx < NV * NJNT) {
      int v = idx / NJNT, k = idx - v * NJNT;
      wT[(size_t)k * CSTRV + v] = lbs[idx];
    }
  } else if (bx < TRB + RODB) {
    // ---- Rodrigues: thread = (b, j); one sincos each ----
    int t2 = (bx - TRB) * 256 + tid;
    int b = t2 / NJNT, j = t2 - b * NJNT;
    float a0 = theta[b * 72 + j * 3 + 0];
    float a1 = theta[b * 72 + j * 3 + 1];
    float a2 = theta[b * 72 + j * 3 + 2];
    float e0 = a0 + 1e-8f, e1 = a1 + 1e-8f, e2 = a2 + 1e-8f;
    float ang = sqrtf(e0 * e0 + e1 * e1 + e2 * e2);
    float inv = 1.0f / ang;
    float h = 0.5f * ang;
    float w = cosf(h), s = sinf(h);
    float x = a0 * inv * s, y = a1 * inv * s, z = a2 * inv * s;
    float R[9];
    R[0] = w*w + x*x - y*y - z*z; R[1] = 2.f*(x*y - w*z); R[2] = 2.f*(x*z + w*y);
    R[3] = 2.f*(x*y + w*z); R[4] = w*w - x*x + y*y - z*z; R[5] = 2.f*(y*z - w*x);
    R[6] = 2.f*(x*z - w*y); R[7] = 2.f*(y*z + w*x); R[8] = w*w - x*x - y*y + z*z;
#pragma unroll
    for (int r = 0; r < 9; ++r) Rs[b * 216 + j * 9 + r] = R[r];
    if (j >= 1) {
#pragma unroll
      for (int r = 0; r < 9; ++r)
        pfc[b * CSTR + (j - 1) * 9 + r] = R[r] - ((r % 4 == 0) ? 1.0f : 0.0f);
    } else {
#pragma unroll
      for (int i = 0; i < NBETA; ++i) pfc[b * CSTR + NPF + i] = beta[b * NBETA + i];
      pfc[b * CSTR + NPF + NBETA] = 1.0f;
    }
  } else if (bx < TRB + RODB + SJB) {
    // ---- SJ[k][j][c] = sum_v Jreg[v,j]*src[v,c]  (Jreg read from INPUT) ----
    int s = bx - TRB - RODB;
    int j = s % NJNT, k = s / NJNT;
    const float* src = (k < NBETA) ? (sdirs + (size_t)k * N3) : vtmpl;
    float a0 = 0.f, a1 = 0.f, a2 = 0.f;
    for (int v = tid; v < NV; v += 256) {
      float w = Jreg[v * NJNT + j];
      a0 += w * src[v * 3 + 0];
      a1 += w * src[v * 3 + 1];
      a2 += w * src[v * 3 + 2];
    }
    int lane = tid & 63, wid = tid >> 6;
#pragma unroll
    for (int s2 = 1; s2 < 64; s2 <<= 1) {
      a0 += __shfl_xor(a0, s2); a1 += __shfl_xor(a1, s2); a2 += __shfl_xor(a2, s2);
    }
    if (lane == 0) { red[wid][0] = a0; red[wid][1] = a1; red[wid][2] = a2; }
    __syncthreads();
    if (tid == 0) {
      float* o = SJ + (k * NJNT + j) * 3;
      o[0] = red[0][0] + red[1][0] + red[2][0] + red[3][0];
      o[1] = red[0][1] + red[1][1] + red[2][1] + red[3][1];
      o[2] = red[0][2] + red[1][2] + red[2][2] + red[3][2];
    }
  } else {
    // ---- Pm build (one-shot streaming; depends only on inputs) ----
    int s4 = bx - TRB - RODB - SJB;
    if (s4 < PMA) {
      int s = s4 / 27, g = s4 - s * 27;
      const float* src; int base;
      if (s < 207)      { src = pdirs + (size_t)s * N3;         base = 3 * s; }
      else if (s < 217) { src = sdirs + (size_t)(s - 207) * N3; base = 621 + 3 * (s - 207); }
      else              { src = vtmpl;                           base = 651; }
      int v = g * 256 + tid;
      float x = 0.f, y = 0.f, z = 0.f;
      if (v < NV) { x = src[3 * v]; y = src[3 * v + 1]; z = src[3 * v + 2]; }
      Pb[(size_t)(base + 0) * KPAD + v] = f2bf(x);
      Pb[(size_t)(base + 1) * KPAD + v] = f2bf(y);
      Pb[(size_t)(base + 2) * KPAD + v] = f2bf(z);
    } else if (s4 < PMA + PMO) {
      int g = s4 - PMA;
      int v = g * 256 + tid;
      Pb[(size_t)654 * KPAD + v] = (v < NV) ? f2bf(1.0f) : (short)0;
    } else {
      int s = s4 - PMA - PMO;
      int row = 655 + s / 27, g = s % 27;
      Pb[(size_t)row * KPAD + g * 256 + tid] = (short)0;
    }
  }
}

// ============ J from SJ/beta, in registers (same summation order as k_Jsmall) ========
__device__ inline void getJ(const float* __restrict__ SJ, const float* bb, int i,
                            float& o0, float& o1, float& o2) {
  int r = i * 3;
  float a0 = SJ[NBETA * 72 + r + 0];
  float a1 = SJ[NBETA * 72 + r + 1];
  float a2 = SJ[NBETA * 72 + r + 2];
#pragma unroll
  for (int k = 0; k < NBETA; ++k) {
    a0 += bb[k] * SJ[k * 72 + r + 0];
    a1 += bb[k] * SJ[k * 72 + r + 1];
    a2 += bb[k] * SJ[k * 72 + r + 2];
  }
  o0 = a0; o1 = a1; o2 = a2;
}

// ============ k_chainP: path-product chain, J fused; thread = (b, j) ============
__global__ void __launch_bounds__(256) k_chainP(const float* __restrict__ beta,
                                                const float* __restrict__ SJ,
                                                const float* __restrict__ Rs,
                                                float* __restrict__ A) {
  int idx = blockIdx.x * 256 + threadIdx.x;
  if (idx >= NBATCH * NJNT) return;
  int b = idx / NJNT, j = idx - b * NJNT;
  const float* Rb = Rs + b * 216;
  float bb[NBETA];
#pragma unroll
  for (int k = 0; k < NBETA; ++k) bb[k] = beta[b * NBETA + k];
  float jp0, jp1, jp2;
  getJ(SJ, bb, 0, jp0, jp1, jp2);
  float T[12];
#pragma unroll
  for (int r = 0; r < 3; ++r) {
    T[r * 4 + 0] = Rb[r * 3 + 0];
    T[r * 4 + 1] = Rb[r * 3 + 1];
    T[r * 4 + 2] = Rb[r * 3 + 2];
  }
  T[3] = jp0; T[7] = jp1; T[11] = jp2;
  for (int d = 1; d < 9; ++d) {
    int i = d_path[j][d];
    if (i < 0) break;
    float ji0, ji1, ji2;
    getJ(SJ, bb, i, ji0, ji1, ji2);
    float t0 = ji0 - jp0, t1 = ji1 - jp1, t2 = ji2 - jp2;
    const float* R = Rb + i * 9;
    float R0 = R[0], R1 = R[1], R2 = R[2], R3 = R[3], R4 = R[4];
    float R5 = R[5], R6 = R[6], R7 = R[7], R8 = R[8];
#pragma unroll
    for (int r = 0; r < 3; ++r) {
      float a0 = T[r * 4 + 0], a1 = T[r * 4 + 1], a2 = T[r * 4 + 2];
      T[r * 4 + 0] = a0 * R0 + a1 * R3 + a2 * R6;
      T[r * 4 + 1] = a0 * R1 + a1 * R4 + a2 * R7;
      T[r * 4 + 2] = a0 * R2 + a1 * R5 + a2 * R8;
      T[r * 4 + 3] = a0 * t0 + a1 * t1 + a2 * t2 + T[r * 4 + 3];
    }
    jp0 = ji0; jp1 = ji1; jp2 = ji2;
  }
  // own joint position = jp (path ends at j)
  float* Ab = A + b * 288 + j * 12;
#pragma unroll
  for (int r = 0; r < 3; ++r) {
    float o0 = T[r * 4 + 0], o1 = T[r * 4 + 1], o2 = T[r * 4 + 2];
    Ab[r * 4 + 0] = o0;
    Ab[r * 4 + 1] = o1;
    Ab[r * 4 + 2] = o2;
    Ab[r * 4 + 3] = T[r * 4 + 3] - (o0 * jp0 + o1 * jp1 + o2 * jp2);
  }
}

// ============ kCm: one-shot; thread = one short4 of Cb ============
__global__ void __launch_bounds__(256) kCm(const float* __restrict__ jrT,
                                           const float* __restrict__ wT,
                                           short* __restrict__ Cb) {
  int idx = blockIdx.x * 256 + threadIdx.x;   // 3456*256 = 512*1728
  int jk = idx / C4R;
  int c4 = idx - jk * C4R;
  int v0 = c4 * 4;
  short4 o;
  if (jk < NJK) {
    int j = jk / NJNT, k = jk - j * NJNT;
    float4 a = *(const float4*)(jrT + (size_t)j * CSTRV + v0);
    float4 w = *(const float4*)(wT + (size_t)k * CSTRV + v0);
    o.x = (v0 + 0 < NV) ? f2bf(a.x * w.x) : (short)0;
    o.y = (v0 + 1 < NV) ? f2bf(a.y * w.y) : (short)0;
    o.z = (v0 + 2 < NV) ? f2bf(a.z * w.z) : (short)0;
    o.w = (v0 + 3 < NV) ? f2bf(a.w * w.w) : (short)0;
  } else {
    o.x = o.y = o.z = o.w = (short)0;
  }
  *(short4*)(Cb + (size_t)jk * KPAD + v0) = o;
}

// ============ MFMA GEMM: Dpart[z][m][n] = sum_k P[m][k]*C[n][k] ============
__global__ void __launch_bounds__(256) k_gemm(const short* __restrict__ Pb,
                                              const short* __restrict__ Cb,
                                              float* __restrict__ Dpart) {
  int m0 = blockIdx.x * 64;
  int n0 = blockIdx.y * 64;
  int kb0 = blockIdx.z * KCH;
  __shared__ __align__(16) short As[64 * 64];
  __shared__ __align__(16) short Bs[64 * 64];
  int t = threadIdx.x;
  int wid = t >> 6, lane = t & 63;
  int frow = wid * 16 + (lane & 15);
  int fgrp = lane >> 4;
  fx4 acc[4];
#pragma unroll
  for (int j = 0; j < 4; ++j)
#pragma unroll
    for (int r = 0; r < 4; ++r) acc[j][r] = 0.f;

  int c0 = t, c1 = t + 256;
  int row0 = c0 >> 3, g0 = c0 & 7, sw0 = g0 ^ (row0 & 7);
  int row1 = c1 >> 3, g1 = c1 & 7, sw1 = g1 ^ (row1 & 7);

  for (int kk = 0; kk < KCH / 64; ++kk) {
    int kb = kb0 + kk * 64;
    *(bfx8*)(As + row0 * 64 + sw0 * 8) = *(const bfx8*)(Pb + (size_t)(m0 + row0) * KPAD + kb + g0 * 8);
    *(bfx8*)(As + row1 * 64 + sw1 * 8) = *(const bfx8*)(Pb + (size_t)(m0 + row1) * KPAD + kb + g1 * 8);
    *(bfx8*)(Bs + row0 * 64 + sw0 * 8) = *(const bfx8*)(Cb + (size_t)(n0 + row0) * KPAD + kb + g0 * 8);
    *(bfx8*)(Bs + row1 * 64 + sw1 * 8) = *(const bfx8*)(Cb + (size_t)(n0 + row1) * KPAD + kb + g1 * 8);
    __syncthreads();
#pragma unroll
    for (int ks = 0; ks < 2; ++ks) {
      int ga = ks * 4 + fgrp;
      bfx8 a = *(const bfx8*)(As + frow * 64 + (ga ^ (frow & 7)) * 8);
#pragma unroll
      for (int j = 0; j < 4; ++j) {
        int bcol = j * 16 + (lane & 15);
        bfx8 b = *(const bfx8*)(Bs + bcol * 64 + (ga ^ (bcol & 7)) * 8);
        acc[j] = __builtin_amdgcn_mfma_f32_16x16x32_bf16(a, b, acc[j], 0, 0, 0);
      }
    }
    __syncthreads();
  }
  float* dst = Dpart + (size_t)blockIdx.z * PROWSP * NJKP
             + (size_t)(m0 + wid * 16 + (lane >> 4) * 4) * NJKP + n0 + (lane & 15);
#pragma unroll
  for (int j = 0; j < 4; ++j)
#pragma unroll
    for (int r = 0; r < 4; ++r)
      dst[(size_t)r * NJKP + j * 16] = acc[j][r];
}

// ============ reduce K-split partials (float4) ============
__global__ void k_redD(const float* __restrict__ Dpart, float* __restrict__ D) {
  int i = blockIdx.x * 256 + threadIdx.x;
  if (i >= PROWSP * NJKP / 4) return;
  const float4* dp = (const float4*)Dpart;
  float4 s = dp[i];
#pragma unroll
  for (int z = 1; z < KSPLIT; ++z) {
    float4 v = dp[(size_t)z * (PROWSP * NJKP / 4) + i];
    s.x += v.x; s.y += v.y; s.z += v.z; s.w += v.w;
  }
  ((float4*)D)[i] = s;
}

// ============ k_S5b: r-split, no atomics; Spart[z][b][q][jk] (SoA-q) ============
__global__ void __launch_bounds__(256) k_S5b(const float* __restrict__ D,
                                             const float* __restrict__ pfc,
                                             float* __restrict__ Spart) {
  int n0 = blockIdx.x * 64;
  int b0 = blockIdx.y * 8;
  int r0 = blockIdx.z * RCH;
  int r1 = r0 + RCH; if (r1 > NCOEF) r1 = NCOEF;
  int tid = threadIdx.x;
  int jk = tid & 63;
  int bg = (tid >> 6) * 2;          // wave-uniform
  const float* Dp  = D + n0 + jk;
  const float* c0p = pfc + (size_t)(b0 + bg + 0) * CSTR;  // wave-uniform base
  const float* c1p = pfc + (size_t)(b0 + bg + 1) * CSTR;
  float a00 = 0.f, a01 = 0.f, a02 = 0.f, a10 = 0.f, a11 = 0.f, a12 = 0.f;
#pragma unroll 2
  for (int r = r0; r < r1; ++r) {
    float d0 = Dp[(size_t)(3 * r + 0) * NJKP];
    float d1 = Dp[(size_t)(3 * r + 1) * NJKP];
    float d2 = Dp[(size_t)(3 * r + 2) * NJKP];
    float c0 = c0p[r];               // s_load (uniform)
    float c1 = c1p[r];
    a00 += c0 * d0; a01 += c0 * d1; a02 += c0 * d2;
    a10 += c1 * d0; a11 += c1 * d1; a12 += c1 * d2;
  }
  int jkg = n0 + jk;
  if (jkg < NJK) {
    float* base = Spart + (size_t)blockIdx.z * SSTRIDE;
    float* o0 = base + ((size_t)(b0 + bg + 0) * 3) * NJK + jkg;
    float* o1 = base + ((size_t)(b0 + bg + 1) * 3) * NJK + jkg;
    o0[0 * NJK] = a00; o0[1 * NJK] = a01; o0[2 * NJK] = a02;
    o1[0 * NJK] = a10; o1[1 * NJK] = a11; o1[2 * NJK] = a12;
  }
}

// ============ k_redS: fold RSP partials into S[b][q][jk] (float4) ============
__global__ void k_redS(const float* __restrict__ Spart, float* __restrict__ S) {
  int i = blockIdx.x * 256 + threadIdx.x;
  if (i >= (int)(SSTRIDE / 4)) return;
  const float4* sp = (const float4*)Spart;
  float4 s = sp[i];
#pragma unroll
  for (int z = 1; z < RSP; ++z) {
    float4 v = sp[(size_t)z * (SSTRIDE / 4) + i];
    s.x += v.x; s.y += v.y; s.z += v.z; s.w += v.w;
  }
  ((float4*)S)[i] = s;
}

// ============ final: joints[b,j,c] = sum_k A[b,k,c,:].[S, c0]; S is [b][q][jk] ========
__global__ void k_final(const float* __restrict__ S, const float* __restrict__ D,
                        const float* __restrict__ A, float* __restrict__ out) {
  int idx = blockIdx.x * 256 + threadIdx.x;
  if (idx >= NBATCH * NJO * 3) return;
  int b = idx / 57, r = idx - b * 57;
  int j = r / 3, c = r - j * 3;
  const float* c0 = D + (size_t)654 * NJKP + j * NJNT;
  const float* S0 = S + ((size_t)b * 3 + 0) * NJK + j * NJNT;
  const float* S1 = S + ((size_t)b * 3 + 1) * NJK + j * NJNT;
  const float* S2 = S + ((size_t)b * 3 + 2) * NJK + j * NJNT;
  float acc = 0.f;
#pragma unroll
  for (int k = 0; k < NJNT; ++k) {
    const float* Ar = A + b * 288 + k * 12 + c * 4;
    acc += Ar[0] * S0[k] + Ar[1] * S1[k] + Ar[2] * S2[k] + Ar[3] * c0[k];
  }
  out[idx] = acc;
}

extern "C" void kernel_launch(void* const* d_in, const int* in_sizes, int n_in,
                              void* d_out, int out_size, void* d_ws, size_t ws_size,
                              hipStream_t stream) {
  const float* beta  = (const float*)d_in[0];
  const float* theta = (const float*)d_in[1];
  const float* vtmpl = (const float*)d_in[2];
  const float* sdirs = (const float*)d_in[3];
  const float* Jreg  = (const float*)d_in[4];
  const float* pdirs = (const float*)d_in[5];
  const float* lbs   = (const float*)d_in[6];
  const float* jreg2 = (const float*)d_in[7];
  float* out = (float*)d_out;

  float* ws    = (float*)d_ws;
  short* Cb    = (short*)ws;                              // 512*6912 bf16
  short* Pb    = Cb + (size_t)NJKP * KPAD;                // 704*6912 bf16
  float* Dpart = (float*)(Pb + (size_t)PROWSP * KPAD);    // 12*704*512 f32
  float* D     = Dpart + (size_t)KSPLIT * PROWSP * NJKP;  // 704*512
  float* S     = D     + (size_t)PROWSP * NJKP;           // 512*3*456
  float* Spart = S     + SSTRIDE;                         // 4*512*3*456
  float* pfc   = Spart + (size_t)RSP * SSTRIDE;           // 512*224
  float* Rs    = pfc   + (size_t)NBATCH * CSTR;           // 512*216
  float* A     = Rs    + (size_t)NBATCH * 216;            // 512*288
  float* jrT   = A     + (size_t)NBATCH * 288;            // 19*6912 (padded)
  float* wT    = jrT   + (size_t)NJO * CSTRV;             // 24*6912 (padded)
  float* SJ    = wT    + (size_t)NJNT * CSTRV;            // 11*72

  kA<<<dim3(TRB + RODB + SJB + PMT), 256, 0, stream>>>(
      jreg2, lbs, Jreg, sdirs, vtmpl, theta, beta, pdirs,
      jrT, wT, SJ, Rs, pfc, Pb);
  k_chainP<<<dim3((NBATCH * NJNT + 255) / 256), 256, 0, stream>>>(beta, SJ, Rs, A);
  kCm<<<dim3(NJKP * C4R / 256), 256, 0, stream>>>(jrT, wT, Cb);
  k_gemm<<<dim3(PROWSP / 64, NJKP / 64, KSPLIT), 256, 0, stream>>>(Pb, Cb, Dpart);
  k_redD<<<dim3(PROWSP * NJKP / 4 / 256), 256, 0, stream>>>(Dpart, D);
  k_S5b<<<dim3(NJKP / 64, NBATCH / 8, RSP), 256, 0, stream>>>(D, pfc, Spart);
  k_redS<<<dim3((SSTRIDE / 4 + 255) / 256), 256, 0, stream>>>(Spart, S);
  k_final<<<dim3((NBATCH * NJO * 3 + 255) / 256), 256, 0, stream>>>(S, D, A, out);
}

// Round 15
// 92.928 us; speedup vs baseline: 2.1450x; 1.0348x over previous
//
#include <hip/hip_runtime.h>
#include <math.h>

#define NV 6890
#define N3 20670       // NV*3
#define NJNT 24
#define NBETA 10
#define NPF 207
#define NJO 19
#define NBATCH 512
#define NJK 456        // NJO*NJNT
#define NJKP 512       // padded jk (GEMM N)
#define NCOEF 218      // [pf 207 | beta 10 | 1]
#define PROWSP 704     // padded P rows (GEMM M)
#define KPAD 6912      // 12 * 576
#define KSPLIT 12
#define KCH 576        // 9 * 64
#define CSTR 224       // pfc row stride
#define CSTRV 6912     // padded jrT/wT row stride (float4-safe)

// kA role boundaries
#define TRB 646        // transpose: ceil(NV*NJNT/256)
#define RODB 48        // rodrigues: NBATCH*NJNT/256
#define SJB 264        // SJ: 24*11
#define PMA 5913       // Pm rows: 219 * 27 chunks
#define PMO 27         // ones-row chunks
#define PMZ 1323       // 49 pad rows * 27
#define PMT (PMA + PMO + PMZ)
// kB role boundaries
#define CHB 48         // chainP: NBATCH*NJNT/256
#define C4R 1728       // short4 per Cb row
#define CMB (NJKP * C4R / 256)   // 3456 kCm blocks
// k_S5b r-split
#define RSP 4
#define RCH 56         // 4*56 = 224 >= 218
#define SSTRIDE ((size_t)NBATCH * 3 * NJK)   // one Spart slice

typedef __attribute__((ext_vector_type(8))) short bfx8;
typedef __attribute__((ext_vector_type(4))) float fx4;

__constant__ int d_par[NJNT] = {0,0,0,0,1,2,3,4,5,6,7,8,9,9,9,12,13,14,16,17,18,19,20,21};
// ancestor path (root..j) per joint, -1 padded; max depth 9
__constant__ int d_path[NJNT][9] = {
  {0,-1,-1,-1,-1,-1,-1,-1,-1},
  {0,1,-1,-1,-1,-1,-1,-1,-1},
  {0,2,-1,-1,-1,-1,-1,-1,-1},
  {0,3,-1,-1,-1,-1,-1,-1,-1},
  {0,1,4,-1,-1,-1,-1,-1,-1},
  {0,2,5,-1,-1,-1,-1,-1,-1},
  {0,3,6,-1,-1,-1,-1,-1,-1},
  {0,1,4,7,-1,-1,-1,-1,-1},
  {0,2,5,8,-1,-1,-1,-1,-1},
  {0,3,6,9,-1,-1,-1,-1,-1},
  {0,1,4,7,10,-1,-1,-1,-1},
  {0,2,5,8,11,-1,-1,-1,-1},
  {0,3,6,9,12,-1,-1,-1,-1},
  {0,3,6,9,13,-1,-1,-1,-1},
  {0,3,6,9,14,-1,-1,-1,-1},
  {0,3,6,9,12,15,-1,-1,-1},
  {0,3,6,9,13,16,-1,-1,-1},
  {0,3,6,9,14,17,-1,-1,-1},
  {0,3,6,9,13,16,18,-1,-1},
  {0,3,6,9,14,17,19,-1,-1},
  {0,3,6,9,13,16,18,20,-1},
  {0,3,6,9,14,17,19,21,-1},
  {0,3,6,9,13,16,18,20,22},
  {0,3,6,9,14,17,19,21,23}};

__device__ inline short f2bf(float f) {
  union { float f; unsigned u; } x; x.f = f;
  unsigned r = (x.u + 0x7fffu + ((x.u >> 16) & 1u)) >> 16;
  return (short)r;
}

// ============ kA: transpose || rodrigues(b,j) || SJ(reads INPUT Jreg) || Pm ============
// All roles consume only kernel INPUTS — no intra-dispatch dependencies.
__global__ void __launch_bounds__(256) kA(const float* __restrict__ jr,
                                          const float* __restrict__ lbs,
                                          const float* __restrict__ Jreg,
                                          const float* __restrict__ sdirs,
                                          const float* __restrict__ vtmpl,
                                          const float* __restrict__ theta,
                                          const float* __restrict__ beta,
                                          const float* __restrict__ pdirs,
                                          float* __restrict__ jrT, float* __restrict__ wT,
                                          float* __restrict__ SJ, float* __restrict__ Rs,
                                          float* __restrict__ pfc,
                                          short* __restrict__ Pb) {
  __shared__ float red[4][3];
  int bx = blockIdx.x, tid = threadIdx.x;
  if (bx < TRB) {
    int idx = bx * 256 + tid;
    if (idx < NV * NJO)  { int v = idx / NJO,  j = idx - v * NJO;  jrT[(size_t)j * CSTRV + v] = jr[idx]; }
    if (idx < NV * NJNT) {
      int v = idx / NJNT, k = idx - v * NJNT;
      wT[(size_t)k * CSTRV + v] = lbs[idx];
    }
  } else if (bx < TRB + RODB) {
    int t2 = (bx - TRB) * 256 + tid;
    int b = t2 / NJNT, j = t2 - b * NJNT;
    float a0 = theta[b * 72 + j * 3 + 0];
    float a1 = theta[b * 72 + j * 3 + 1];
    float a2 = theta[b * 72 + j * 3 + 2];
    float e0 = a0 + 1e-8f, e1 = a1 + 1e-8f, e2 = a2 + 1e-8f;
    float ang = sqrtf(e0 * e0 + e1 * e1 + e2 * e2);
    float inv = 1.0f / ang;
    float h = 0.5f * ang;
    float w = cosf(h), s = sinf(h);
    float x = a0 * inv * s, y = a1 * inv * s, z = a2 * inv * s;
    float R[9];
    R[0] = w*w + x*x - y*y - z*z; R[1] = 2.f*(x*y - w*z); R[2] = 2.f*(x*z + w*y);
    R[3] = 2.f*(x*y + w*z); R[4] = w*w - x*x + y*y - z*z; R[5] = 2.f*(y*z - w*x);
    R[6] = 2.f*(x*z - w*y); R[7] = 2.f*(y*z + w*x); R[8] = w*w - x*x - y*y + z*z;
#pragma unroll
    for (int r = 0; r < 9; ++r) Rs[b * 216 + j * 9 + r] = R[r];
    if (j >= 1) {
#pragma unroll
      for (int r = 0; r < 9; ++r)
        pfc[b * CSTR + (j - 1) * 9 + r] = R[r] - ((r % 4 == 0) ? 1.0f : 0.0f);
    } else {
#pragma unroll
      for (int i = 0; i < NBETA; ++i) pfc[b * CSTR + NPF + i] = beta[b * NBETA + i];
      pfc[b * CSTR + NPF + NBETA] = 1.0f;
    }
  } else if (bx < TRB + RODB + SJB) {
    int s = bx - TRB - RODB;
    int j = s % NJNT, k = s / NJNT;
    const float* src = (k < NBETA) ? (sdirs + (size_t)k * N3) : vtmpl;
    float a0 = 0.f, a1 = 0.f, a2 = 0.f;
    for (int v = tid; v < NV; v += 256) {
      float w = Jreg[v * NJNT + j];
      a0 += w * src[v * 3 + 0];
      a1 += w * src[v * 3 + 1];
      a2 += w * src[v * 3 + 2];
    }
    int lane = tid & 63, wid = tid >> 6;
#pragma unroll
    for (int s2 = 1; s2 < 64; s2 <<= 1) {
      a0 += __shfl_xor(a0, s2); a1 += __shfl_xor(a1, s2); a2 += __shfl_xor(a2, s2);
    }
    if (lane == 0) { red[wid][0] = a0; red[wid][1] = a1; red[wid][2] = a2; }
    __syncthreads();
    if (tid == 0) {
      float* o = SJ + (k * NJNT + j) * 3;
      o[0] = red[0][0] + red[1][0] + red[2][0] + red[3][0];
      o[1] = red[0][1] + red[1][1] + red[2][1] + red[3][1];
      o[2] = red[0][2] + red[1][2] + red[2][2] + red[3][2];
    }
  } else {
    int s4 = bx - TRB - RODB - SJB;
    if (s4 < PMA) {
      int s = s4 / 27, g = s4 - s * 27;
      const float* src; int base;
      if (s < 207)      { src = pdirs + (size_t)s * N3;         base = 3 * s; }
      else if (s < 217) { src = sdirs + (size_t)(s - 207) * N3; base = 621 + 3 * (s - 207); }
      else              { src = vtmpl;                           base = 651; }
      int v = g * 256 + tid;
      float x = 0.f, y = 0.f, z = 0.f;
      if (v < NV) { x = src[3 * v]; y = src[3 * v + 1]; z = src[3 * v + 2]; }
      Pb[(size_t)(base + 0) * KPAD + v] = f2bf(x);
      Pb[(size_t)(base + 1) * KPAD + v] = f2bf(y);
      Pb[(size_t)(base + 2) * KPAD + v] = f2bf(z);
    } else if (s4 < PMA + PMO) {
      int g = s4 - PMA;
      int v = g * 256 + tid;
      Pb[(size_t)654 * KPAD + v] = (v < NV) ? f2bf(1.0f) : (short)0;
    } else {
      int s = s4 - PMA - PMO;
      int row = 655 + s / 27, g = s % 27;
      Pb[(size_t)row * KPAD + g * 256 + tid] = (short)0;
    }
  }
}

// ============ J from SJ/beta, in registers (same summation order as before) ========
__device__ inline void getJ(const float* __restrict__ SJ, const float* bb, int i,
                            float& o0, float& o1, float& o2) {
  int r = i * 3;
  float a0 = SJ[NBETA * 72 + r + 0];
  float a1 = SJ[NBETA * 72 + r + 1];
  float a2 = SJ[NBETA * 72 + r + 2];
#pragma unroll
  for (int k = 0; k < NBETA; ++k) {
    a0 += bb[k] * SJ[k * 72 + r + 0];
    a1 += bb[k] * SJ[k * 72 + r + 1];
    a2 += bb[k] * SJ[k * 72 + r + 2];
  }
  o0 = a0; o1 = a1; o2 = a2;
}

// ============ kB: chainP || kCm — both consume only kA outputs; disjoint writes ======
__global__ void __launch_bounds__(256) kB(const float* __restrict__ beta,
                                          const float* __restrict__ SJ,
                                          const float* __restrict__ Rs,
                                          const float* __restrict__ jrT,
                                          const float* __restrict__ wT,
                                          float* __restrict__ A,
                                          short* __restrict__ Cb) {
  int bx = blockIdx.x, tid = threadIdx.x;
  if (bx < CHB) {
    // ---- chainP: path-product chain with fused J; thread = (b, j) ----
    int idx = bx * 256 + tid;          // exactly NBATCH*NJNT
    int b = idx / NJNT, j = idx - b * NJNT;
    const float* Rb = Rs + b * 216;
    float bb[NBETA];
#pragma unroll
    for (int k = 0; k < NBETA; ++k) bb[k] = beta[b * NBETA + k];
    float jp0, jp1, jp2;
    getJ(SJ, bb, 0, jp0, jp1, jp2);
    float T[12];
#pragma unroll
    for (int r = 0; r < 3; ++r) {
      T[r * 4 + 0] = Rb[r * 3 + 0];
      T[r * 4 + 1] = Rb[r * 3 + 1];
      T[r * 4 + 2] = Rb[r * 3 + 2];
    }
    T[3] = jp0; T[7] = jp1; T[11] = jp2;
    for (int d = 1; d < 9; ++d) {
      int i = d_path[j][d];
      if (i < 0) break;
      float ji0, ji1, ji2;
      getJ(SJ, bb, i, ji0, ji1, ji2);
      float t0 = ji0 - jp0, t1 = ji1 - jp1, t2 = ji2 - jp2;
      const float* R = Rb + i * 9;
      float R0 = R[0], R1 = R[1], R2 = R[2], R3 = R[3], R4 = R[4];
      float R5 = R[5], R6 = R[6], R7 = R[7], R8 = R[8];
#pragma unroll
      for (int r = 0; r < 3; ++r) {
        float a0 = T[r * 4 + 0], a1 = T[r * 4 + 1], a2 = T[r * 4 + 2];
        T[r * 4 + 0] = a0 * R0 + a1 * R3 + a2 * R6;
        T[r * 4 + 1] = a0 * R1 + a1 * R4 + a2 * R7;
        T[r * 4 + 2] = a0 * R2 + a1 * R5 + a2 * R8;
        T[r * 4 + 3] = a0 * t0 + a1 * t1 + a2 * t2 + T[r * 4 + 3];
      }
      jp0 = ji0; jp1 = ji1; jp2 = ji2;
    }
    float* Ab = A + b * 288 + j * 12;
#pragma unroll
    for (int r = 0; r < 3; ++r) {
      float o0 = T[r * 4 + 0], o1 = T[r * 4 + 1], o2 = T[r * 4 + 2];
      Ab[r * 4 + 0] = o0;
      Ab[r * 4 + 1] = o1;
      Ab[r * 4 + 2] = o2;
      Ab[r * 4 + 3] = T[r * 4 + 3] - (o0 * jp0 + o1 * jp1 + o2 * jp2);
    }
  } else {
    // ---- kCm: thread = one short4 of Cb ----
    int idx = (bx - CHB) * 256 + tid;
    int jk = idx / C4R;
    int c4 = idx - jk * C4R;
    int v0 = c4 * 4;
    short4 o;
    if (jk < NJK) {
      int j = jk / NJNT, k = jk - j * NJNT;
      float4 a = *(const float4*)(jrT + (size_t)j * CSTRV + v0);
      float4 w = *(const float4*)(wT + (size_t)k * CSTRV + v0);
      o.x = (v0 + 0 < NV) ? f2bf(a.x * w.x) : (short)0;
      o.y = (v0 + 1 < NV) ? f2bf(a.y * w.y) : (short)0;
      o.z = (v0 + 2 < NV) ? f2bf(a.z * w.z) : (short)0;
      o.w = (v0 + 3 < NV) ? f2bf(a.w * w.w) : (short)0;
    } else {
      o.x = o.y = o.z = o.w = (short)0;
    }
    *(short4*)(Cb + (size_t)jk * KPAD + v0) = o;
  }
}

// ============ MFMA GEMM: Dpart[z][m][n] = sum_k P[m][k]*C[n][k] ============
__global__ void __launch_bounds__(256) k_gemm(const short* __restrict__ Pb,
                                              const short* __restrict__ Cb,
                                              float* __restrict__ Dpart) {
  int m0 = blockIdx.x * 64;
  int n0 = blockIdx.y * 64;
  int kb0 = blockIdx.z * KCH;
  __shared__ __align__(16) short As[64 * 64];
  __shared__ __align__(16) short Bs[64 * 64];
  int t = threadIdx.x;
  int wid = t >> 6, lane = t & 63;
  int frow = wid * 16 + (lane & 15);
  int fgrp = lane >> 4;
  fx4 acc[4];
#pragma unroll
  for (int j = 0; j < 4; ++j)
#pragma unroll
    for (int r = 0; r < 4; ++r) acc[j][r] = 0.f;

  int c0 = t, c1 = t + 256;
  int row0 = c0 >> 3, g0 = c0 & 7, sw0 = g0 ^ (row0 & 7);
  int row1 = c1 >> 3, g1 = c1 & 7, sw1 = g1 ^ (row1 & 7);

  for (int kk = 0; kk < KCH / 64; ++kk) {
    int kb = kb0 + kk * 64;
    *(bfx8*)(As + row0 * 64 + sw0 * 8) = *(const bfx8*)(Pb + (size_t)(m0 + row0) * KPAD + kb + g0 * 8);
    *(bfx8*)(As + row1 * 64 + sw1 * 8) = *(const bfx8*)(Pb + (size_t)(m0 + row1) * KPAD + kb + g1 * 8);
    *(bfx8*)(Bs + row0 * 64 + sw0 * 8) = *(const bfx8*)(Cb + (size_t)(n0 + row0) * KPAD + kb + g0 * 8);
    *(bfx8*)(Bs + row1 * 64 + sw1 * 8) = *(const bfx8*)(Cb + (size_t)(n0 + row1) * KPAD + kb + g1 * 8);
    __syncthreads();
#pragma unroll
    for (int ks = 0; ks < 2; ++ks) {
      int ga = ks * 4 + fgrp;
      bfx8 a = *(const bfx8*)(As + frow * 64 + (ga ^ (frow & 7)) * 8);
#pragma unroll
      for (int j = 0; j < 4; ++j) {
        int bcol = j * 16 + (lane & 15);
        bfx8 b = *(const bfx8*)(Bs + bcol * 64 + (ga ^ (bcol & 7)) * 8);
        acc[j] = __builtin_amdgcn_mfma_f32_16x16x32_bf16(a, b, acc[j], 0, 0, 0);
      }
    }
    __syncthreads();
  }
  float* dst = Dpart + (size_t)blockIdx.z * PROWSP * NJKP
             + (size_t)(m0 + wid * 16 + (lane >> 4) * 4) * NJKP + n0 + (lane & 15);
#pragma unroll
  for (int j = 0; j < 4; ++j)
#pragma unroll
    for (int r = 0; r < 4; ++r)
      dst[(size_t)r * NJKP + j * 16] = acc[j][r];
}

// ============ reduce K-split partials (float4) ============
__global__ void k_redD(const float* __restrict__ Dpart, float* __restrict__ D) {
  int i = blockIdx.x * 256 + threadIdx.x;
  if (i >= PROWSP * NJKP / 4) return;
  const float4* dp = (const float4*)Dpart;
  float4 s = dp[i];
#pragma unroll
  for (int z = 1; z < KSPLIT; ++z) {
    float4 v = dp[(size_t)z * (PROWSP * NJKP / 4) + i];
    s.x += v.x; s.y += v.y; s.z += v.z; s.w += v.w;
  }
  ((float4*)D)[i] = s;
}

// ============ k_S5b: r-split, no atomics; Spart[z][b][q][jk] (SoA-q) ============
__global__ void __launch_bounds__(256) k_S5b(const float* __restrict__ D,
                                             const float* __restrict__ pfc,
                                             float* __restrict__ Spart) {
  int n0 = blockIdx.x * 64;
  int b0 = blockIdx.y * 8;
  int r0 = blockIdx.z * RCH;
  int r1 = r0 + RCH; if (r1 > NCOEF) r1 = NCOEF;
  int tid = threadIdx.x;
  int jk = tid & 63;
  int bg = (tid >> 6) * 2;          // wave-uniform
  const float* Dp  = D + n0 + jk;
  const float* c0p = pfc + (size_t)(b0 + bg + 0) * CSTR;  // wave-uniform base
  const float* c1p = pfc + (size_t)(b0 + bg + 1) * CSTR;
  float a00 = 0.f, a01 = 0.f, a02 = 0.f, a10 = 0.f, a11 = 0.f, a12 = 0.f;
#pragma unroll 2
  for (int r = r0; r < r1; ++r) {
    float d0 = Dp[(size_t)(3 * r + 0) * NJKP];
    float d1 = Dp[(size_t)(3 * r + 1) * NJKP];
    float d2 = Dp[(size_t)(3 * r + 2) * NJKP];
    float c0 = c0p[r];               // s_load (uniform)
    float c1 = c1p[r];
    a00 += c0 * d0; a01 += c0 * d1; a02 += c0 * d2;
    a10 += c1 * d0; a11 += c1 * d1; a12 += c1 * d2;
  }
  int jkg = n0 + jk;
  if (jkg < NJK) {
    float* base = Spart + (size_t)blockIdx.z * SSTRIDE;
    float* o0 = base + ((size_t)(b0 + bg + 0) * 3) * NJK + jkg;
    float* o1 = base + ((size_t)(b0 + bg + 1) * 3) * NJK + jkg;
    o0[0 * NJK] = a00; o0[1 * NJK] = a01; o0[2 * NJK] = a02;
    o1[0 * NJK] = a10; o1[1 * NJK] = a11; o1[2 * NJK] = a12;
  }
}

// ============ k_final2: folds redS (z-sum in redS's order) + joint contraction ========
__global__ void k_final2(const float* __restrict__ Spart, const float* __restrict__ D,
                         const float* __restrict__ A, float* __restrict__ out) {
  int idx = blockIdx.x * 256 + threadIdx.x;
  if (idx >= NBATCH * NJO * 3) return;
  int b = idx / 57, r = idx - b * 57;
  int j = r / 3, c = r - j * 3;
  const float* c0 = D + (size_t)654 * NJKP + j * NJNT;
  const float* Sp0 = Spart + ((size_t)b * 3 + 0) * NJK + j * NJNT;
  const float* Sp1 = Spart + ((size_t)b * 3 + 1) * NJK + j * NJNT;
  const float* Sp2 = Spart + ((size_t)b * 3 + 2) * NJK + j * NJNT;
  float acc = 0.f;
#pragma unroll 4
  for (int k = 0; k < NJNT; ++k) {
    float s0 = Sp0[k], s1 = Sp1[k], s2 = Sp2[k];
#pragma unroll
    for (int z = 1; z < RSP; ++z) {
      s0 += Sp0[z * SSTRIDE + k];
      s1 += Sp1[z * SSTRIDE + k];
      s2 += Sp2[z * SSTRIDE + k];
    }
    const float* Ar = A + b * 288 + k * 12 + c * 4;
    acc += Ar[0] * s0 + Ar[1] * s1 + Ar[2] * s2 + Ar[3] * c0[k];
  }
  out[idx] = acc;
}

extern "C" void kernel_launch(void* const* d_in, const int* in_sizes, int n_in,
                              void* d_out, int out_size, void* d_ws, size_t ws_size,
                              hipStream_t stream) {
  const float* beta  = (const float*)d_in[0];
  const float* theta = (const float*)d_in[1];
  const float* vtmpl = (const float*)d_in[2];
  const float* sdirs = (const float*)d_in[3];
  const float* Jreg  = (const float*)d_in[4];
  const float* pdirs = (const float*)d_in[5];
  const float* lbs   = (const float*)d_in[6];
  const float* jreg2 = (const float*)d_in[7];
  float* out = (float*)d_out;

  float* ws    = (float*)d_ws;
  short* Cb    = (short*)ws;                              // 512*6912 bf16
  short* Pb    = Cb + (size_t)NJKP * KPAD;                // 704*6912 bf16
  float* Dpart = (float*)(Pb + (size_t)PROWSP * KPAD);    // 12*704*512 f32
  float* D     = Dpart + (size_t)KSPLIT * PROWSP * NJKP;  // 704*512
  float* Spart = D     + (size_t)PROWSP * NJKP;           // 4*512*3*456
  float* pfc   = Spart + (size_t)RSP * SSTRIDE;           // 512*224
  float* Rs    = pfc   + (size_t)NBATCH * CSTR;           // 512*216
  float* A     = Rs    + (size_t)NBATCH * 216;            // 512*288
  float* jrT   = A     + (size_t)NBATCH * 288;            // 19*6912 (padded)
  float* wT    = jrT   + (size_t)NJO * CSTRV;             // 24*6912 (padded)
  float* SJ    = wT    + (size_t)NJNT * CSTRV;            // 11*72

  kA<<<dim3(TRB + RODB + SJB + PMT), 256, 0, stream>>>(
      jreg2, lbs, Jreg, sdirs, vtmpl, theta, beta, pdirs,
      jrT, wT, SJ, Rs, pfc, Pb);
  kB<<<dim3(CHB + CMB), 256, 0, stream>>>(beta, SJ, Rs, jrT, wT, A, Cb);
  k_gemm<<<dim3(PROWSP / 64, NJKP / 64, KSPLIT), 256, 0, stream>>>(Pb, Cb, Dpart);
  k_redD<<<dim3(PROWSP * NJKP / 4 / 256), 256, 0, stream>>>(Dpart, D);
  k_S5b<<<dim3(NJKP / 64, NBATCH / 8, RSP), 256, 0, stream>>>(D, pfc, Spart);
  k_final2<<<dim3((NBATCH * NJO * 3 + 255) / 256), 256, 0, stream>>>(Spart, D, A, out);
}

// Round 16
// 92.222 us; speedup vs baseline: 2.1614x; 1.0077x over previous
//
#include <hip/hip_runtime.h>
#include <math.h>

#define NV 6890
#define N3 20670       // NV*3
#define NJNT 24
#define NBETA 10
#define NPF 207
#define NJO 19
#define NBATCH 512
#define NJK 456        // NJO*NJNT
#define NJKP 512       // padded jk (GEMM N)
#define NCOEF 218      // [pf 207 | beta 10 | 1]
#define PROWSP 704     // padded P rows (GEMM M)
#define KPAD 6912      // 12 * 576
#define KSPLIT 12
#define KCH 576        // 9 * 64
#define CSTR 224       // pfc row stride
#define CSTRV 6912     // padded jrT/wT row stride (float4-safe)

// kA role boundaries
#define TR2 54         // LDS-tiled transpose: ceil(NV/128)
#define RODB 48        // rodrigues: NBATCH*NJNT/256
#define SJB 264        // SJ: 24*11
#define PMA 5913       // Pm rows: 219 * 27 chunks
#define PMO 27         // ones-row chunks
#define PMZ 1323       // 49 pad rows * 27
#define PMT (PMA + PMO + PMZ)
// kB role boundaries
#define CHB 48         // chainP: NBATCH*NJNT/256
#define C4R 1728       // short4 per Cb row
#define CMB (NJKP * C4R / 256)   // 3456 kCm blocks
// k_S5b r-split
#define RSP 4
#define RCH 56         // 4*56 = 224 >= 218
#define SSTRIDE ((size_t)NBATCH * 3 * NJK)   // one Spart slice

typedef __attribute__((ext_vector_type(8))) short bfx8;
typedef __attribute__((ext_vector_type(4))) float fx4;

#define LDSP(x) ((__attribute__((address_space(3))) void*)(x))
#define GLBP(x) ((const __attribute__((address_space(1))) void*)(x))

__constant__ int d_par[NJNT] = {0,0,0,0,1,2,3,4,5,6,7,8,9,9,9,12,13,14,16,17,18,19,20,21};
// ancestor path (root..j) per joint, -1 padded; max depth 9
__constant__ int d_path[NJNT][9] = {
  {0,-1,-1,-1,-1,-1,-1,-1,-1},
  {0,1,-1,-1,-1,-1,-1,-1,-1},
  {0,2,-1,-1,-1,-1,-1,-1,-1},
  {0,3,-1,-1,-1,-1,-1,-1,-1},
  {0,1,4,-1,-1,-1,-1,-1,-1},
  {0,2,5,-1,-1,-1,-1,-1,-1},
  {0,3,6,-1,-1,-1,-1,-1,-1},
  {0,1,4,7,-1,-1,-1,-1,-1},
  {0,2,5,8,-1,-1,-1,-1,-1},
  {0,3,6,9,-1,-1,-1,-1,-1},
  {0,1,4,7,10,-1,-1,-1,-1},
  {0,2,5,8,11,-1,-1,-1,-1},
  {0,3,6,9,12,-1,-1,-1,-1},
  {0,3,6,9,13,-1,-1,-1,-1},
  {0,3,6,9,14,-1,-1,-1,-1},
  {0,3,6,9,12,15,-1,-1,-1},
  {0,3,6,9,13,16,-1,-1,-1},
  {0,3,6,9,14,17,-1,-1,-1},
  {0,3,6,9,13,16,18,-1,-1},
  {0,3,6,9,14,17,19,-1,-1},
  {0,3,6,9,13,16,18,20,-1},
  {0,3,6,9,14,17,19,21,-1},
  {0,3,6,9,13,16,18,20,22},
  {0,3,6,9,14,17,19,21,23}};

__device__ inline short f2bf(float f) {
  union { float f; unsigned u; } x; x.f = f;
  unsigned r = (x.u + 0x7fffu + ((x.u >> 16) & 1u)) >> 16;
  return (short)r;
}

// ============ kA: LDS-tiled transpose || rodrigues(b,j) || SJ || Pm ============
// All roles consume only kernel INPUTS — no intra-dispatch dependencies.
__global__ void __launch_bounds__(256) kA(const float* __restrict__ jr,
                                          const float* __restrict__ lbs,
                                          const float* __restrict__ Jreg,
                                          const float* __restrict__ sdirs,
                                          const float* __restrict__ vtmpl,
                                          const float* __restrict__ theta,
                                          const float* __restrict__ beta,
                                          const float* __restrict__ pdirs,
                                          float* __restrict__ jrT, float* __restrict__ wT,
                                          float* __restrict__ SJ, float* __restrict__ Rs,
                                          float* __restrict__ pfc,
                                          short* __restrict__ Pb) {
  __shared__ float red[4][3];
  __shared__ float tj[128 * NJO];    // 9.5KB
  __shared__ float tw[128 * NJNT];   // 12KB
  int bx = blockIdx.x, tid = threadIdx.x;
  if (bx < TR2) {
    // ---- transpose via LDS tile: coalesced reads AND writes ----
    int v0 = bx * 128;
    for (int i = tid; i < 128 * NJO; i += 256) {
      int g = v0 * NJO + i;
      tj[i] = (g < NV * NJO) ? jr[g] : 0.f;
    }
    for (int i = tid; i < 128 * NJNT; i += 256) {
      int g = v0 * NJNT + i;
      tw[i] = (g < NV * NJNT) ? lbs[g] : 0.f;
    }
    __syncthreads();
    for (int i = tid; i < 128 * (NJO + NJNT); i += 256) {
      int r = i >> 7, c = i & 127;
      int v = v0 + c;
      if (v >= NV) continue;
      if (r < NJO) jrT[(size_t)r * CSTRV + v] = tj[c * NJO + r];
      else         wT[(size_t)(r - NJO) * CSTRV + v] = tw[c * NJNT + (r - NJO)];
    }
  } else if (bx < TR2 + RODB) {
    int t2 = (bx - TR2) * 256 + tid;
    int b = t2 / NJNT, j = t2 - b * NJNT;
    float a0 = theta[b * 72 + j * 3 + 0];
    float a1 = theta[b * 72 + j * 3 + 1];
    float a2 = theta[b * 72 + j * 3 + 2];
    float e0 = a0 + 1e-8f, e1 = a1 + 1e-8f, e2 = a2 + 1e-8f;
    float ang = sqrtf(e0 * e0 + e1 * e1 + e2 * e2);
    float inv = 1.0f / ang;
    float h = 0.5f * ang;
    float w = cosf(h), s = sinf(h);
    float x = a0 * inv * s, y = a1 * inv * s, z = a2 * inv * s;
    float R[9];
    R[0] = w*w + x*x - y*y - z*z; R[1] = 2.f*(x*y - w*z); R[2] = 2.f*(x*z + w*y);
    R[3] = 2.f*(x*y + w*z); R[4] = w*w - x*x + y*y - z*z; R[5] = 2.f*(y*z - w*x);
    R[6] = 2.f*(x*z - w*y); R[7] = 2.f*(y*z + w*x); R[8] = w*w - x*x - y*y + z*z;
#pragma unroll
    for (int r = 0; r < 9; ++r) Rs[b * 216 + j * 9 + r] = R[r];
    if (j >= 1) {
#pragma unroll
      for (int r = 0; r < 9; ++r)
        pfc[b * CSTR + (j - 1) * 9 + r] = R[r] - ((r % 4 == 0) ? 1.0f : 0.0f);
    } else {
#pragma unroll
      for (int i = 0; i < NBETA; ++i) pfc[b * CSTR + NPF + i] = beta[b * NBETA + i];
      pfc[b * CSTR + NPF + NBETA] = 1.0f;
    }
  } else if (bx < TR2 + RODB + SJB) {
    int s = bx - TR2 - RODB;
    int j = s % NJNT, k = s / NJNT;
    const float* src = (k < NBETA) ? (sdirs + (size_t)k * N3) : vtmpl;
    float a0 = 0.f, a1 = 0.f, a2 = 0.f;
    for (int v = tid; v < NV; v += 256) {
      float w = Jreg[v * NJNT + j];
      a0 += w * src[v * 3 + 0];
      a1 += w * src[v * 3 + 1];
      a2 += w * src[v * 3 + 2];
    }
    int lane = tid & 63, wid = tid >> 6;
#pragma unroll
    for (int s2 = 1; s2 < 64; s2 <<= 1) {
      a0 += __shfl_xor(a0, s2); a1 += __shfl_xor(a1, s2); a2 += __shfl_xor(a2, s2);
    }
    if (lane == 0) { red[wid][0] = a0; red[wid][1] = a1; red[wid][2] = a2; }
    __syncthreads();
    if (tid == 0) {
      float* o = SJ + (k * NJNT + j) * 3;
      o[0] = red[0][0] + red[1][0] + red[2][0] + red[3][0];
      o[1] = red[0][1] + red[1][1] + red[2][1] + red[3][1];
      o[2] = red[0][2] + red[1][2] + red[2][2] + red[3][2];
    }
  } else {
    int s4 = bx - TR2 - RODB - SJB;
    if (s4 < PMA) {
      int s = s4 / 27, g = s4 - s * 27;
      const float* src; int base;
      if (s < 207)      { src = pdirs + (size_t)s * N3;         base = 3 * s; }
      else if (s < 217) { src = sdirs + (size_t)(s - 207) * N3; base = 621 + 3 * (s - 207); }
      else              { src = vtmpl;                           base = 651; }
      int v = g * 256 + tid;
      float x = 0.f, y = 0.f, z = 0.f;
      if (v < NV) { x = src[3 * v]; y = src[3 * v + 1]; z = src[3 * v + 2]; }
      Pb[(size_t)(base + 0) * KPAD + v] = f2bf(x);
      Pb[(size_t)(base + 1) * KPAD + v] = f2bf(y);
      Pb[(size_t)(base + 2) * KPAD + v] = f2bf(z);
    } else if (s4 < PMA + PMO) {
      int g = s4 - PMA;
      int v = g * 256 + tid;
      Pb[(size_t)654 * KPAD + v] = (v < NV) ? f2bf(1.0f) : (short)0;
    } else {
      int s = s4 - PMA - PMO;
      int row = 655 + s / 27, g = s % 27;
      Pb[(size_t)row * KPAD + g * 256 + tid] = (short)0;
    }
  }
}

// ============ J from SJ/beta, in registers ============
__device__ inline void getJ(const float* __restrict__ SJ, const float* bb, int i,
                            float& o0, float& o1, float& o2) {
  int r = i * 3;
  float a0 = SJ[NBETA * 72 + r + 0];
  float a1 = SJ[NBETA * 72 + r + 1];
  float a2 = SJ[NBETA * 72 + r + 2];
#pragma unroll
  for (int k = 0; k < NBETA; ++k) {
    a0 += bb[k] * SJ[k * 72 + r + 0];
    a1 += bb[k] * SJ[k * 72 + r + 1];
    a2 += bb[k] * SJ[k * 72 + r + 2];
  }
  o0 = a0; o1 = a1; o2 = a2;
}

// ============ kB: chainP || kCm — both consume only kA outputs ============
__global__ void __launch_bounds__(256) kB(const float* __restrict__ beta,
                                          const float* __restrict__ SJ,
                                          const float* __restrict__ Rs,
                                          const float* __restrict__ jrT,
                                          const float* __restrict__ wT,
                                          float* __restrict__ A,
                                          short* __restrict__ Cb) {
  int bx = blockIdx.x, tid = threadIdx.x;
  if (bx < CHB) {
    int idx = bx * 256 + tid;          // exactly NBATCH*NJNT
    int b = idx / NJNT, j = idx - b * NJNT;
    const float* Rb = Rs + b * 216;
    float bb[NBETA];
#pragma unroll
    for (int k = 0; k < NBETA; ++k) bb[k] = beta[b * NBETA + k];
    float jp0, jp1, jp2;
    getJ(SJ, bb, 0, jp0, jp1, jp2);
    float T[12];
#pragma unroll
    for (int r = 0; r < 3; ++r) {
      T[r * 4 + 0] = Rb[r * 3 + 0];
      T[r * 4 + 1] = Rb[r * 3 + 1];
      T[r * 4 + 2] = Rb[r * 3 + 2];
    }
    T[3] = jp0; T[7] = jp1; T[11] = jp2;
    for (int d = 1; d < 9; ++d) {
      int i = d_path[j][d];
      if (i < 0) break;
      float ji0, ji1, ji2;
      getJ(SJ, bb, i, ji0, ji1, ji2);
      float t0 = ji0 - jp0, t1 = ji1 - jp1, t2 = ji2 - jp2;
      const float* R = Rb + i * 9;
      float R0 = R[0], R1 = R[1], R2 = R[2], R3 = R[3], R4 = R[4];
      float R5 = R[5], R6 = R[6], R7 = R[7], R8 = R[8];
#pragma unroll
      for (int r = 0; r < 3; ++r) {
        float a0 = T[r * 4 + 0], a1 = T[r * 4 + 1], a2 = T[r * 4 + 2];
        T[r * 4 + 0] = a0 * R0 + a1 * R3 + a2 * R6;
        T[r * 4 + 1] = a0 * R1 + a1 * R4 + a2 * R7;
        T[r * 4 + 2] = a0 * R2 + a1 * R5 + a2 * R8;
        T[r * 4 + 3] = a0 * t0 + a1 * t1 + a2 * t2 + T[r * 4 + 3];
      }
      jp0 = ji0; jp1 = ji1; jp2 = ji2;
    }
    float* Ab = A + b * 288 + j * 12;
#pragma unroll
    for (int r = 0; r < 3; ++r) {
      float o0 = T[r * 4 + 0], o1 = T[r * 4 + 1], o2 = T[r * 4 + 2];
      Ab[r * 4 + 0] = o0;
      Ab[r * 4 + 1] = o1;
      Ab[r * 4 + 2] = o2;
      Ab[r * 4 + 3] = T[r * 4 + 3] - (o0 * jp0 + o1 * jp1 + o2 * jp2);
    }
  } else {
    int idx = (bx - CHB) * 256 + tid;
    int jk = idx / C4R;
    int c4 = idx - jk * C4R;
    int v0 = c4 * 4;
    short4 o;
    if (jk < NJK) {
      int j = jk / NJNT, k = jk - j * NJNT;
      float4 a = *(const float4*)(jrT + (size_t)j * CSTRV + v0);
      float4 w = *(const float4*)(wT + (size_t)k * CSTRV + v0);
      o.x = (v0 + 0 < NV) ? f2bf(a.x * w.x) : (short)0;
      o.y = (v0 + 1 < NV) ? f2bf(a.y * w.y) : (short)0;
      o.z = (v0 + 2 < NV) ? f2bf(a.z * w.z) : (short)0;
      o.w = (v0 + 3 < NV) ? f2bf(a.w * w.w) : (short)0;
    } else {
      o.x = o.y = o.z = o.w = (short)0;
    }
    *(short4*)(Cb + (size_t)jk * KPAD + v0) = o;
  }
}

// ============ MFMA GEMM with global_load_lds (pre-swizzled source) ============
// Linear LDS dest (wave base + lane*16); source column-group pre-XOR'd so the
// LDS content matches the old swizzled layout exactly (read path unchanged).
__global__ void __launch_bounds__(256) k_gemm(const short* __restrict__ Pb,
                                              const short* __restrict__ Cb,
                                              float* __restrict__ Dpart) {
  int m0 = blockIdx.x * 64;
  int n0 = blockIdx.y * 64;
  int kb0 = blockIdx.z * KCH;
  __shared__ __align__(16) short As[64 * 64];
  __shared__ __align__(16) short Bs[64 * 64];
  int t = threadIdx.x;
  int wid = t >> 6, lane = t & 63;
  int frow = wid * 16 + (lane & 15);
  int fgrp = lane >> 4;
  fx4 acc[4];
#pragma unroll
  for (int j = 0; j < 4; ++j)
#pragma unroll
    for (int r = 0; r < 4; ++r) acc[j][r] = 0.f;

  // staging: wave w covers rows [8w,8w+8) and [32+8w,32+8w+8); lane l ->
  // row-in-chunk = l>>3, linear col-group gl = l&7, source group gsrc = gl ^ (l>>3)
  int lrow = lane >> 3;
  int gsrc = (lane & 7) ^ lrow;
  int rb0 = wid * 8;
  int rb1 = 32 + wid * 8;
  const short* srcA0 = Pb + (size_t)(m0 + rb0 + lrow) * KPAD + kb0 + gsrc * 8;
  const short* srcA1 = Pb + (size_t)(m0 + rb1 + lrow) * KPAD + kb0 + gsrc * 8;
  const short* srcB0 = Cb + (size_t)(n0 + rb0 + lrow) * KPAD + kb0 + gsrc * 8;
  const short* srcB1 = Cb + (size_t)(n0 + rb1 + lrow) * KPAD + kb0 + gsrc * 8;
  short* dstA0 = As + rb0 * 64;
  short* dstA1 = As + rb1 * 64;
  short* dstB0 = Bs + rb0 * 64;
  short* dstB1 = Bs + rb1 * 64;

  for (int kk = 0; kk < KCH / 64; ++kk) {
    __builtin_amdgcn_global_load_lds(GLBP(srcA0), LDSP(dstA0), 16, 0, 0);
    __builtin_amdgcn_global_load_lds(GLBP(srcA1), LDSP(dstA1), 16, 0, 0);
    __builtin_amdgcn_global_load_lds(GLBP(srcB0), LDSP(dstB0), 16, 0, 0);
    __builtin_amdgcn_global_load_lds(GLBP(srcB1), LDSP(dstB1), 16, 0, 0);
    srcA0 += 64; srcA1 += 64; srcB0 += 64; srcB1 += 64;
    __syncthreads();
#pragma unroll
    for (int ks = 0; ks < 2; ++ks) {
      int ga = ks * 4 + fgrp;
      bfx8 a = *(const bfx8*)(As + frow * 64 + (ga ^ (frow & 7)) * 8);
#pragma unroll
      for (int j = 0; j < 4; ++j) {
        int bcol = j * 16 + (lane & 15);
        bfx8 b = *(const bfx8*)(Bs + bcol * 64 + (ga ^ (bcol & 7)) * 8);
        acc[j] = __builtin_amdgcn_mfma_f32_16x16x32_bf16(a, b, acc[j], 0, 0, 0);
      }
    }
    __syncthreads();
  }
  float* dst = Dpart + (size_t)blockIdx.z * PROWSP * NJKP
             + (size_t)(m0 + wid * 16 + (lane >> 4) * 4) * NJKP + n0 + (lane & 15);
#pragma unroll
  for (int j = 0; j < 4; ++j)
#pragma unroll
    for (int r = 0; r < 4; ++r)
      dst[(size_t)r * NJKP + j * 16] = acc[j][r];
}

// ============ reduce K-split partials (float4) ============
__global__ void k_redD(const float* __restrict__ Dpart, float* __restrict__ D) {
  int i = blockIdx.x * 256 + threadIdx.x;
  if (i >= PROWSP * NJKP / 4) return;
  const float4* dp = (const float4*)Dpart;
  float4 s = dp[i];
#pragma unroll
  for (int z = 1; z < KSPLIT; ++z) {
    float4 v = dp[(size_t)z * (PROWSP * NJKP / 4) + i];
    s.x += v.x; s.y += v.y; s.z += v.z; s.w += v.w;
  }
  ((float4*)D)[i] = s;
}

// ============ k_S5b: r-split, no atomics; Spart[z][b][q][jk] (SoA-q) ============
__global__ void __launch_bounds__(256) k_S5b(const float* __restrict__ D,
                                             const float* __restrict__ pfc,
                                             float* __restrict__ Spart) {
  int n0 = blockIdx.x * 64;
  int b0 = blockIdx.y * 8;
  int r0 = blockIdx.z * RCH;
  int r1 = r0 + RCH; if (r1 > NCOEF) r1 = NCOEF;
  int tid = threadIdx.x;
  int jk = tid & 63;
  int bg = (tid >> 6) * 2;          // wave-uniform
  const float* Dp  = D + n0 + jk;
  const float* c0p = pfc + (size_t)(b0 + bg + 0) * CSTR;  // wave-uniform base
  const float* c1p = pfc + (size_t)(b0 + bg + 1) * CSTR;
  float a00 = 0.f, a01 = 0.f, a02 = 0.f, a10 = 0.f, a11 = 0.f, a12 = 0.f;
#pragma unroll 2
  for (int r = r0; r < r1; ++r) {
    float d0 = Dp[(size_t)(3 * r + 0) * NJKP];
    float d1 = Dp[(size_t)(3 * r + 1) * NJKP];
    float d2 = Dp[(size_t)(3 * r + 2) * NJKP];
    float c0 = c0p[r];               // s_load (uniform)
    float c1 = c1p[r];
    a00 += c0 * d0; a01 += c0 * d1; a02 += c0 * d2;
    a10 += c1 * d0; a11 += c1 * d1; a12 += c1 * d2;
  }
  int jkg = n0 + jk;
  if (jkg < NJK) {
    float* base = Spart + (size_t)blockIdx.z * SSTRIDE;
    float* o0 = base + ((size_t)(b0 + bg + 0) * 3) * NJK + jkg;
    float* o1 = base + ((size_t)(b0 + bg + 1) * 3) * NJK + jkg;
    o0[0 * NJK] = a00; o0[1 * NJK] = a01; o0[2 * NJK] = a02;
    o1[0 * NJK] = a10; o1[1 * NJK] = a11; o1[2 * NJK] = a12;
  }
}

// ============ k_final2: folds redS (z-sum in redS's order) + joint contraction ========
__global__ void k_final2(const float* __restrict__ Spart, const float* __restrict__ D,
                         const float* __restrict__ A, float* __restrict__ out) {
  int idx = blockIdx.x * 256 + threadIdx.x;
  if (idx >= NBATCH * NJO * 3) return;
  int b = idx / 57, r = idx - b * 57;
  int j = r / 3, c = r - j * 3;
  const float* c0 = D + (size_t)654 * NJKP + j * NJNT;
  const float* Sp0 = Spart + ((size_t)b * 3 + 0) * NJK + j * NJNT;
  const float* Sp1 = Spart + ((size_t)b * 3 + 1) * NJK + j * NJNT;
  const float* Sp2 = Spart + ((size_t)b * 3 + 2) * NJK + j * NJNT;
  float acc = 0.f;
#pragma unroll 4
  for (int k = 0; k < NJNT; ++k) {
    float s0 = Sp0[k], s1 = Sp1[k], s2 = Sp2[k];
#pragma unroll
    for (int z = 1; z < RSP; ++z) {
      s0 += Sp0[z * SSTRIDE + k];
      s1 += Sp1[z * SSTRIDE + k];
      s2 += Sp2[z * SSTRIDE + k];
    }
    const float* Ar = A + b * 288 + k * 12 + c * 4;
    acc += Ar[0] * s0 + Ar[1] * s1 + Ar[2] * s2 + Ar[3] * c0[k];
  }
  out[idx] = acc;
}

extern "C" void kernel_launch(void* const* d_in, const int* in_sizes, int n_in,
                              void* d_out, int out_size, void* d_ws, size_t ws_size,
                              hipStream_t stream) {
  const float* beta  = (const float*)d_in[0];
  const float* theta = (const float*)d_in[1];
  const float* vtmpl = (const float*)d_in[2];
  const float* sdirs = (const float*)d_in[3];
  const float* Jreg  = (const float*)d_in[4];
  const float* pdirs = (const float*)d_in[5];
  const float* lbs   = (const float*)d_in[6];
  const float* jreg2 = (const float*)d_in[7];
  float* out = (float*)d_out;

  float* ws    = (float*)d_ws;
  short* Cb    = (short*)ws;                              // 512*6912 bf16
  short* Pb    = Cb + (size_t)NJKP * KPAD;                // 704*6912 bf16
  float* Dpart = (float*)(Pb + (size_t)PROWSP * KPAD);    // 12*704*512 f32
  float* D     = Dpart + (size_t)KSPLIT * PROWSP * NJKP;  // 704*512
  float* Spart = D     + (size_t)PROWSP * NJKP;           // 4*512*3*456
  float* pfc   = Spart + (size_t)RSP * SSTRIDE;           // 512*224
  float* Rs    = pfc   + (size_t)NBATCH * CSTR;           // 512*216
  float* A     = Rs    + (size_t)NBATCH * 216;            // 512*288
  float* jrT   = A     + (size_t)NBATCH * 288;            // 19*6912 (padded)
  float* wT    = jrT   + (size_t)NJO * CSTRV;             // 24*6912 (padded)
  float* SJ    = wT    + (size_t)NJNT * CSTRV;            // 11*72

  kA<<<dim3(TR2 + RODB + SJB + PMT), 256, 0, stream>>>(
      jreg2, lbs, Jreg, sdirs, vtmpl, theta, beta, pdirs,
      jrT, wT, SJ, Rs, pfc, Pb);
  kB<<<dim3(CHB + CMB), 256, 0, stream>>>(beta, SJ, Rs, jrT, wT, A, Cb);
  k_gemm<<<dim3(PROWSP / 64, NJKP / 64, KSPLIT), 256, 0, stream>>>(Pb, Cb, Dpart);
  k_redD<<<dim3(PROWSP * NJKP / 4 / 256), 256, 0, stream>>>(Dpart, D);
  k_S5b<<<dim3(NJKP / 64, NBATCH / 8, RSP), 256, 0, stream>>>(D, pfc, Spart);
  k_final2<<<dim3((NBATCH * NJO * 3 + 255) / 256), 256, 0, stream>>>(Spart, D, A, out);
}

// Round 17
// 89.506 us; speedup vs baseline: 2.2270x; 1.0303x over previous
//
#include <hip/hip_runtime.h>
#include <math.h>

#define NV 6890
#define N3 20670       // NV*3
#define NJNT 24
#define NBETA 10
#define NPF 207
#define NJO 19
#define NBATCH 512
#define NJK 456        // NJO*NJNT
#define NJKP 512       // padded jk (GEMM N)
#define NCOEF 218      // [pf 207 | beta 10 | 1]
#define PROWSP 704     // padded P rows (GEMM M)
#define KPAD 6912      // 12 * 576
#define KSPLIT 12
#define KCH 576        // 9 * 64
#define CSTR 224       // pfc row stride
#define CSTRV 6912     // padded jrT/wT row stride (float4-safe)

// kA role boundaries
#define TR2 54         // LDS-tiled transpose: ceil(NV/128)
#define RODB 48        // rodrigues: NBATCH*NJNT/256
#define SJB 264        // SJ: 24*11
#define PMA 5913       // Pm rows: 219 * 27 chunks
#define PMO 27         // ones-row chunks
#define PMZ 1323       // 49 pad rows * 27
#define PMT (PMA + PMO + PMZ)
// kB role boundaries
#define CHB 48         // chainP: NBATCH*NJNT/256
#define C4R 1728       // short4 per Cb row
#define CMB (NJKP * C4R / 256)   // 3456 kCm blocks
// D4: rows 0..217 = (D[3r],D[3r+1],D[3r+2],0); row 218 = (c0,0,0,0)
#define D4R 219
// k_S5b r-split
#define RSP 4
#define RCH 56         // 4*56 = 224 >= 218
#define SSTRIDE ((size_t)NBATCH * 3 * NJK)   // one Spart slice

typedef __attribute__((ext_vector_type(8))) short bfx8;
typedef __attribute__((ext_vector_type(4))) float fx4;

#define LDSP(x) ((__attribute__((address_space(3))) void*)(x))
#define GLBP(x) ((const __attribute__((address_space(1))) void*)(x))

__constant__ int d_par[NJNT] = {0,0,0,0,1,2,3,4,5,6,7,8,9,9,9,12,13,14,16,17,18,19,20,21};
// ancestor path (root..j) per joint, -1 padded; max depth 9
__constant__ int d_path[NJNT][9] = {
  {0,-1,-1,-1,-1,-1,-1,-1,-1},
  {0,1,-1,-1,-1,-1,-1,-1,-1},
  {0,2,-1,-1,-1,-1,-1,-1,-1},
  {0,3,-1,-1,-1,-1,-1,-1,-1},
  {0,1,4,-1,-1,-1,-1,-1,-1},
  {0,2,5,-1,-1,-1,-1,-1,-1},
  {0,3,6,-1,-1,-1,-1,-1,-1},
  {0,1,4,7,-1,-1,-1,-1,-1},
  {0,2,5,8,-1,-1,-1,-1,-1},
  {0,3,6,9,-1,-1,-1,-1,-1},
  {0,1,4,7,10,-1,-1,-1,-1},
  {0,2,5,8,11,-1,-1,-1,-1},
  {0,3,6,9,12,-1,-1,-1,-1},
  {0,3,6,9,13,-1,-1,-1,-1},
  {0,3,6,9,14,-1,-1,-1,-1},
  {0,3,6,9,12,15,-1,-1,-1},
  {0,3,6,9,13,16,-1,-1,-1},
  {0,3,6,9,14,17,-1,-1,-1},
  {0,3,6,9,13,16,18,-1,-1},
  {0,3,6,9,14,17,19,-1,-1},
  {0,3,6,9,13,16,18,20,-1},
  {0,3,6,9,14,17,19,21,-1},
  {0,3,6,9,13,16,18,20,22},
  {0,3,6,9,14,17,19,21,23}};

__device__ inline short f2bf(float f) {
  union { float f; unsigned u; } x; x.f = f;
  unsigned r = (x.u + 0x7fffu + ((x.u >> 16) & 1u)) >> 16;
  return (short)r;
}

// ============ kA: LDS-tiled transpose || rodrigues(b,j) || SJ || Pm ============
// All roles consume only kernel INPUTS — no intra-dispatch dependencies.
__global__ void __launch_bounds__(256) kA(const float* __restrict__ jr,
                                          const float* __restrict__ lbs,
                                          const float* __restrict__ Jreg,
                                          const float* __restrict__ sdirs,
                                          const float* __restrict__ vtmpl,
                                          const float* __restrict__ theta,
                                          const float* __restrict__ beta,
                                          const float* __restrict__ pdirs,
                                          float* __restrict__ jrT, float* __restrict__ wT,
                                          float* __restrict__ SJ, float* __restrict__ Rs,
                                          float* __restrict__ pfc,
                                          short* __restrict__ Pb) {
  __shared__ float red[4][3];
  __shared__ float tj[128 * NJO];    // 9.5KB
  __shared__ float tw[128 * NJNT];   // 12KB
  int bx = blockIdx.x, tid = threadIdx.x;
  if (bx < TR2) {
    // ---- transpose via LDS tile: coalesced reads AND writes ----
    int v0 = bx * 128;
    for (int i = tid; i < 128 * NJO; i += 256) {
      int g = v0 * NJO + i;
      tj[i] = (g < NV * NJO) ? jr[g] : 0.f;
    }
    for (int i = tid; i < 128 * NJNT; i += 256) {
      int g = v0 * NJNT + i;
      tw[i] = (g < NV * NJNT) ? lbs[g] : 0.f;
    }
    __syncthreads();
    for (int i = tid; i < 128 * (NJO + NJNT); i += 256) {
      int r = i >> 7, c = i & 127;
      int v = v0 + c;
      if (v >= NV) continue;
      if (r < NJO) jrT[(size_t)r * CSTRV + v] = tj[c * NJO + r];
      else         wT[(size_t)(r - NJO) * CSTRV + v] = tw[c * NJNT + (r - NJO)];
    }
  } else if (bx < TR2 + RODB) {
    int t2 = (bx - TR2) * 256 + tid;
    int b = t2 / NJNT, j = t2 - b * NJNT;
    float a0 = theta[b * 72 + j * 3 + 0];
    float a1 = theta[b * 72 + j * 3 + 1];
    float a2 = theta[b * 72 + j * 3 + 2];
    float e0 = a0 + 1e-8f, e1 = a1 + 1e-8f, e2 = a2 + 1e-8f;
    float ang = sqrtf(e0 * e0 + e1 * e1 + e2 * e2);
    float inv = 1.0f / ang;
    float h = 0.5f * ang;
    float w = cosf(h), s = sinf(h);
    float x = a0 * inv * s, y = a1 * inv * s, z = a2 * inv * s;
    float R[9];
    R[0] = w*w + x*x - y*y - z*z; R[1] = 2.f*(x*y - w*z); R[2] = 2.f*(x*z + w*y);
    R[3] = 2.f*(x*y + w*z); R[4] = w*w - x*x + y*y - z*z; R[5] = 2.f*(y*z - w*x);
    R[6] = 2.f*(x*z - w*y); R[7] = 2.f*(y*z + w*x); R[8] = w*w - x*x - y*y + z*z;
#pragma unroll
    for (int r = 0; r < 9; ++r) Rs[b * 216 + j * 9 + r] = R[r];
    if (j >= 1) {
#pragma unroll
      for (int r = 0; r < 9; ++r)
        pfc[b * CSTR + (j - 1) * 9 + r] = R[r] - ((r % 4 == 0) ? 1.0f : 0.0f);
    } else {
#pragma unroll
      for (int i = 0; i < NBETA; ++i) pfc[b * CSTR + NPF + i] = beta[b * NBETA + i];
      pfc[b * CSTR + NPF + NBETA] = 1.0f;
    }
  } else if (bx < TR2 + RODB + SJB) {
    int s = bx - TR2 - RODB;
    int j = s % NJNT, k = s / NJNT;
    const float* src = (k < NBETA) ? (sdirs + (size_t)k * N3) : vtmpl;
    float a0 = 0.f, a1 = 0.f, a2 = 0.f;
    for (int v = tid; v < NV; v += 256) {
      float w = Jreg[v * NJNT + j];
      a0 += w * src[v * 3 + 0];
      a1 += w * src[v * 3 + 1];
      a2 += w * src[v * 3 + 2];
    }
    int lane = tid & 63, wid = tid >> 6;
#pragma unroll
    for (int s2 = 1; s2 < 64; s2 <<= 1) {
      a0 += __shfl_xor(a0, s2); a1 += __shfl_xor(a1, s2); a2 += __shfl_xor(a2, s2);
    }
    if (lane == 0) { red[wid][0] = a0; red[wid][1] = a1; red[wid][2] = a2; }
    __syncthreads();
    if (tid == 0) {
      float* o = SJ + (k * NJNT + j) * 3;
      o[0] = red[0][0] + red[1][0] + red[2][0] + red[3][0];
      o[1] = red[0][1] + red[1][1] + red[2][1] + red[3][1];
      o[2] = red[0][2] + red[1][2] + red[2][2] + red[3][2];
    }
  } else {
    int s4 = bx - TR2 - RODB - SJB;
    if (s4 < PMA) {
      int s = s4 / 27, g = s4 - s * 27;
      const float* src; int base;
      if (s < 207)      { src = pdirs + (size_t)s * N3;         base = 3 * s; }
      else if (s < 217) { src = sdirs + (size_t)(s - 207) * N3; base = 621 + 3 * (s - 207); }
      else              { src = vtmpl;                           base = 651; }
      int v = g * 256 + tid;
      float x = 0.f, y = 0.f, z = 0.f;
      if (v < NV) { x = src[3 * v]; y = src[3 * v + 1]; z = src[3 * v + 2]; }
      Pb[(size_t)(base + 0) * KPAD + v] = f2bf(x);
      Pb[(size_t)(base + 1) * KPAD + v] = f2bf(y);
      Pb[(size_t)(base + 2) * KPAD + v] = f2bf(z);
    } else if (s4 < PMA + PMO) {
      int g = s4 - PMA;
      int v = g * 256 + tid;
      Pb[(size_t)654 * KPAD + v] = (v < NV) ? f2bf(1.0f) : (short)0;
    } else {
      int s = s4 - PMA - PMO;
      int row = 655 + s / 27, g = s % 27;
      Pb[(size_t)row * KPAD + g * 256 + tid] = (short)0;
    }
  }
}

// ============ J from SJ/beta, in registers ============
__device__ inline void getJ(const float* __restrict__ SJ, const float* bb, int i,
                            float& o0, float& o1, float& o2) {
  int r = i * 3;
  float a0 = SJ[NBETA * 72 + r + 0];
  float a1 = SJ[NBETA * 72 + r + 1];
  float a2 = SJ[NBETA * 72 + r + 2];
#pragma unroll
  for (int k = 0; k < NBETA; ++k) {
    a0 += bb[k] * SJ[k * 72 + r + 0];
    a1 += bb[k] * SJ[k * 72 + r + 1];
    a2 += bb[k] * SJ[k * 72 + r + 2];
  }
  o0 = a0; o1 = a1; o2 = a2;
}

// ============ kB: chainP || kCm — both consume only kA outputs ============
__global__ void __launch_bounds__(256) kB(const float* __restrict__ beta,
                                          const float* __restrict__ SJ,
                                          const float* __restrict__ Rs,
                                          const float* __restrict__ jrT,
                                          const float* __restrict__ wT,
                                          float* __restrict__ A,
                                          short* __restrict__ Cb) {
  int bx = blockIdx.x, tid = threadIdx.x;
  if (bx < CHB) {
    int idx = bx * 256 + tid;          // exactly NBATCH*NJNT
    int b = idx / NJNT, j = idx - b * NJNT;
    const float* Rb = Rs + b * 216;
    float bb[NBETA];
#pragma unroll
    for (int k = 0; k < NBETA; ++k) bb[k] = beta[b * NBETA + k];
    float jp0, jp1, jp2;
    getJ(SJ, bb, 0, jp0, jp1, jp2);
    float T[12];
#pragma unroll
    for (int r = 0; r < 3; ++r) {
      T[r * 4 + 0] = Rb[r * 3 + 0];
      T[r * 4 + 1] = Rb[r * 3 + 1];
      T[r * 4 + 2] = Rb[r * 3 + 2];
    }
    T[3] = jp0; T[7] = jp1; T[11] = jp2;
    for (int d = 1; d < 9; ++d) {
      int i = d_path[j][d];
      if (i < 0) break;
      float ji0, ji1, ji2;
      getJ(SJ, bb, i, ji0, ji1, ji2);
      float t0 = ji0 - jp0, t1 = ji1 - jp1, t2 = ji2 - jp2;
      const float* R = Rb + i * 9;
      float R0 = R[0], R1 = R[1], R2 = R[2], R3 = R[3], R4 = R[4];
      float R5 = R[5], R6 = R[6], R7 = R[7], R8 = R[8];
#pragma unroll
      for (int r = 0; r < 3; ++r) {
        float a0 = T[r * 4 + 0], a1 = T[r * 4 + 1], a2 = T[r * 4 + 2];
        T[r * 4 + 0] = a0 * R0 + a1 * R3 + a2 * R6;
        T[r * 4 + 1] = a0 * R1 + a1 * R4 + a2 * R7;
        T[r * 4 + 2] = a0 * R2 + a1 * R5 + a2 * R8;
        T[r * 4 + 3] = a0 * t0 + a1 * t1 + a2 * t2 + T[r * 4 + 3];
      }
      jp0 = ji0; jp1 = ji1; jp2 = ji2;
    }
    float* Ab = A + b * 288 + j * 12;
#pragma unroll
    for (int r = 0; r < 3; ++r) {
      float o0 = T[r * 4 + 0], o1 = T[r * 4 + 1], o2 = T[r * 4 + 2];
      Ab[r * 4 + 0] = o0;
      Ab[r * 4 + 1] = o1;
      Ab[r * 4 + 2] = o2;
      Ab[r * 4 + 3] = T[r * 4 + 3] - (o0 * jp0 + o1 * jp1 + o2 * jp2);
    }
  } else {
    int idx = (bx - CHB) * 256 + tid;
    int jk = idx / C4R;
    int c4 = idx - jk * C4R;
    int v0 = c4 * 4;
    short4 o;
    if (jk < NJK) {
      int j = jk / NJNT, k = jk - j * NJNT;
      float4 a = *(const float4*)(jrT + (size_t)j * CSTRV + v0);
      float4 w = *(const float4*)(wT + (size_t)k * CSTRV + v0);
      o.x = (v0 + 0 < NV) ? f2bf(a.x * w.x) : (short)0;
      o.y = (v0 + 1 < NV) ? f2bf(a.y * w.y) : (short)0;
      o.z = (v0 + 2 < NV) ? f2bf(a.z * w.z) : (short)0;
      o.w = (v0 + 3 < NV) ? f2bf(a.w * w.w) : (short)0;
    } else {
      o.x = o.y = o.z = o.w = (short)0;
    }
    *(short4*)(Cb + (size_t)jk * KPAD + v0) = o;
  }
}

// ============ MFMA GEMM with global_load_lds (pre-swizzled source) ============
__global__ void __launch_bounds__(256) k_gemm(const short* __restrict__ Pb,
                                              const short* __restrict__ Cb,
                                              float* __restrict__ Dpart) {
  int m0 = blockIdx.x * 64;
  int n0 = blockIdx.y * 64;
  int kb0 = blockIdx.z * KCH;
  __shared__ __align__(16) short As[64 * 64];
  __shared__ __align__(16) short Bs[64 * 64];
  int t = threadIdx.x;
  int wid = t >> 6, lane = t & 63;
  int frow = wid * 16 + (lane & 15);
  int fgrp = lane >> 4;
  fx4 acc[4];
#pragma unroll
  for (int j = 0; j < 4; ++j)
#pragma unroll
    for (int r = 0; r < 4; ++r) acc[j][r] = 0.f;

  int lrow = lane >> 3;
  int gsrc = (lane & 7) ^ lrow;
  int rb0 = wid * 8;
  int rb1 = 32 + wid * 8;
  const short* srcA0 = Pb + (size_t)(m0 + rb0 + lrow) * KPAD + kb0 + gsrc * 8;
  const short* srcA1 = Pb + (size_t)(m0 + rb1 + lrow) * KPAD + kb0 + gsrc * 8;
  const short* srcB0 = Cb + (size_t)(n0 + rb0 + lrow) * KPAD + kb0 + gsrc * 8;
  const short* srcB1 = Cb + (size_t)(n0 + rb1 + lrow) * KPAD + kb0 + gsrc * 8;
  short* dstA0 = As + rb0 * 64;
  short* dstA1 = As + rb1 * 64;
  short* dstB0 = Bs + rb0 * 64;
  short* dstB1 = Bs + rb1 * 64;

  for (int kk = 0; kk < KCH / 64; ++kk) {
    __builtin_amdgcn_global_load_lds(GLBP(srcA0), LDSP(dstA0), 16, 0, 0);
    __builtin_amdgcn_global_load_lds(GLBP(srcA1), LDSP(dstA1), 16, 0, 0);
    __builtin_amdgcn_global_load_lds(GLBP(srcB0), LDSP(dstB0), 16, 0, 0);
    __builtin_amdgcn_global_load_lds(GLBP(srcB1), LDSP(dstB1), 16, 0, 0);
    srcA0 += 64; srcA1 += 64; srcB0 += 64; srcB1 += 64;
    __syncthreads();
#pragma unroll
    for (int ks = 0; ks < 2; ++ks) {
      int ga = ks * 4 + fgrp;
      bfx8 a = *(const bfx8*)(As + frow * 64 + (ga ^ (frow & 7)) * 8);
#pragma unroll
      for (int j = 0; j < 4; ++j) {
        int bcol = j * 16 + (lane & 15);
        bfx8 b = *(const bfx8*)(Bs + bcol * 64 + (ga ^ (bcol & 7)) * 8);
        acc[j] = __builtin_amdgcn_mfma_f32_16x16x32_bf16(a, b, acc[j], 0, 0, 0);
      }
    }
    __syncthreads();
  }
  float* dst = Dpart + (size_t)blockIdx.z * PROWSP * NJKP
             + (size_t)(m0 + wid * 16 + (lane >> 4) * 4) * NJKP + n0 + (lane & 15);
#pragma unroll
  for (int j = 0; j < 4; ++j)
#pragma unroll
    for (int r = 0; r < 4; ++r)
      dst[(size_t)r * NJKP + j * 16] = acc[j][r];
}

// ============ k_redD4: K-split reduce + repack for S5b ============
// D4[r][jk][4] = (D[3r],D[3r+1],D[3r+2],0) for r<218; row 218 = (c0,0,0,0).
// z-sum in the same ascending order as the old redD (bit-identical values).
__global__ void k_redD4(const float* __restrict__ Dpart, float* __restrict__ D4) {
  int idx = blockIdx.x * 256 + threadIdx.x;   // D4R*NJKP = 112128
  if (idx >= D4R * NJKP) return;
  int r = idx / NJKP, jk = idx - r * NJKP;
  float4 o;
  if (r < NCOEF) {
    float s0 = 0.f, s1 = 0.f, s2 = 0.f;
#pragma unroll
    for (int z = 0; z < KSPLIT; ++z) {
      const float* dp = Dpart + (size_t)z * PROWSP * NJKP + jk;
      s0 += dp[(size_t)(3 * r + 0) * NJKP];
      s1 += dp[(size_t)(3 * r + 1) * NJKP];
      s2 += dp[(size_t)(3 * r + 2) * NJKP];
    }
    o = make_float4(s0, s1, s2, 0.f);
  } else {
    float s = 0.f;
#pragma unroll
    for (int z = 0; z < KSPLIT; ++z)
      s += Dpart[(size_t)z * PROWSP * NJKP + (size_t)654 * NJKP + jk];
    o = make_float4(s, 0.f, 0.f, 0.f);
  }
  ((float4*)D4)[idx] = o;
}

// ============ k_S5b: r-split; ONE float4 load per r-iter (packed D4) ============
__global__ void __launch_bounds__(256) k_S5b(const float* __restrict__ D4,
                                             const float* __restrict__ pfc,
                                             float* __restrict__ Spart) {
  int n0 = blockIdx.x * 64;
  int b0 = blockIdx.y * 8;
  int r0 = blockIdx.z * RCH;
  int r1 = r0 + RCH; if (r1 > NCOEF) r1 = NCOEF;
  int tid = threadIdx.x;
  int jk = tid & 63;
  int bg = (tid >> 6) * 2;          // wave-uniform
  const float4* D4v = (const float4*)D4;
  int jkg = n0 + jk;
  const float* c0p = pfc + (size_t)(b0 + bg + 0) * CSTR;  // wave-uniform base
  const float* c1p = pfc + (size_t)(b0 + bg + 1) * CSTR;
  float a00 = 0.f, a01 = 0.f, a02 = 0.f, a10 = 0.f, a11 = 0.f, a12 = 0.f;
#pragma unroll 4
  for (int r = r0; r < r1; ++r) {
    float4 d = D4v[(size_t)r * NJKP + jkg];
    float c0 = c0p[r];               // s_load (uniform)
    float c1 = c1p[r];
    a00 += c0 * d.x; a01 += c0 * d.y; a02 += c0 * d.z;
    a10 += c1 * d.x; a11 += c1 * d.y; a12 += c1 * d.z;
  }
  if (jkg < NJK) {
    float* base = Spart + (size_t)blockIdx.z * SSTRIDE;
    float* o0 = base + ((size_t)(b0 + bg + 0) * 3) * NJK + jkg;
    float* o1 = base + ((size_t)(b0 + bg + 1) * 3) * NJK + jkg;
    o0[0 * NJK] = a00; o0[1 * NJK] = a01; o0[2 * NJK] = a02;
    o1[0 * NJK] = a10; o1[1 * NJK] = a11; o1[2 * NJK] = a12;
  }
}

// ============ k_final2: folds redS (z-sum in redS's order) + joint contraction ========
// c0 now lives in D4 row 218 (x component, stride-4 floats).
__global__ void k_final2(const float* __restrict__ Spart, const float* __restrict__ D4,
                         const float* __restrict__ A, float* __restrict__ out) {
  int idx = blockIdx.x * 256 + threadIdx.x;
  if (idx >= NBATCH * NJO * 3) return;
  int b = idx / 57, r = idx - b * 57;
  int j = r / 3, c = r - j * 3;
  const float* c0 = D4 + ((size_t)NCOEF * NJKP + j * NJNT) * 4;
  const float* Sp0 = Spart + ((size_t)b * 3 + 0) * NJK + j * NJNT;
  const float* Sp1 = Spart + ((size_t)b * 3 + 1) * NJK + j * NJNT;
  const float* Sp2 = Spart + ((size_t)b * 3 + 2) * NJK + j * NJNT;
  float acc = 0.f;
#pragma unroll 4
  for (int k = 0; k < NJNT; ++k) {
    float s0 = Sp0[k], s1 = Sp1[k], s2 = Sp2[k];
#pragma unroll
    for (int z = 1; z < RSP; ++z) {
      s0 += Sp0[z * SSTRIDE + k];
      s1 += Sp1[z * SSTRIDE + k];
      s2 += Sp2[z * SSTRIDE + k];
    }
    const float* Ar = A + b * 288 + k * 12 + c * 4;
    acc += Ar[0] * s0 + Ar[1] * s1 + Ar[2] * s2 + Ar[3] * c0[k * 4];
  }
  out[idx] = acc;
}

extern "C" void kernel_launch(void* const* d_in, const int* in_sizes, int n_in,
                              void* d_out, int out_size, void* d_ws, size_t ws_size,
                              hipStream_t stream) {
  const float* beta  = (const float*)d_in[0];
  const float* theta = (const float*)d_in[1];
  const float* vtmpl = (const float*)d_in[2];
  const float* sdirs = (const float*)d_in[3];
  const float* Jreg  = (const float*)d_in[4];
  const float* pdirs = (const float*)d_in[5];
  const float* lbs   = (const float*)d_in[6];
  const float* jreg2 = (const float*)d_in[7];
  float* out = (float*)d_out;

  float* ws    = (float*)d_ws;
  short* Cb    = (short*)ws;                              // 512*6912 bf16
  short* Pb    = Cb + (size_t)NJKP * KPAD;                // 704*6912 bf16
  float* Dpart = (float*)(Pb + (size_t)PROWSP * KPAD);    // 12*704*512 f32
  float* D4    = Dpart + (size_t)KSPLIT * PROWSP * NJKP;  // 219*512*4
  float* Spart = D4    + (size_t)D4R * NJKP * 4;          // 4*512*3*456
  float* pfc   = Spart + (size_t)RSP * SSTRIDE;           // 512*224
  float* Rs    = pfc   + (size_t)NBATCH * CSTR;           // 512*216
  float* A     = Rs    + (size_t)NBATCH * 216;            // 512*288
  float* jrT   = A     + (size_t)NBATCH * 288;            // 19*6912 (padded)
  float* wT    = jrT   + (size_t)NJO * CSTRV;             // 24*6912 (padded)
  float* SJ    = wT    + (size_t)NJNT * CSTRV;            // 11*72

  kA<<<dim3(TR2 + RODB + SJB + PMT), 256, 0, stream>>>(
      jreg2, lbs, Jreg, sdirs, vtmpl, theta, beta, pdirs,
      jrT, wT, SJ, Rs, pfc, Pb);
  kB<<<dim3(CHB + CMB), 256, 0, stream>>>(beta, SJ, Rs, jrT, wT, A, Cb);
  k_gemm<<<dim3(PROWSP / 64, NJKP / 64, KSPLIT), 256, 0, stream>>>(Pb, Cb, Dpart);
  k_redD4<<<dim3((D4R * NJKP + 255) / 256), 256, 0, stream>>>(Dpart, D4);
  k_S5b<<<dim3(NJKP / 64, NBATCH / 8, RSP), 256, 0, stream>>>(D4, pfc, Spart);
  k_final2<<<dim3((NBATCH * NJO * 3 + 255) / 256), 256, 0, stream>>>(Spart, D4, A, out);
}

// Round 18
// 86.803 us; speedup vs baseline: 2.2964x; 1.0311x over previous
//
#include <hip/hip_runtime.h>
#include <math.h>

#define NV 6890
#define N3 20670       // NV*3
#define NJNT 24
#define NBETA 10
#define NPF 207
#define NJO 19
#define NBATCH 512
#define NJK 456        // NJO*NJNT
#define NJKP 512       // padded jk (GEMM N)
#define NCOEF 218      // [pf 207 | beta 10 | 1]
#define PROWSP 704     // padded P rows (GEMM M)
#define KPAD 6912      // 12 * 576
#define KSPLIT 12
#define KCH 576        // 9 * 64
#define CSTR 224       // pfc row stride
#define CSTRV 6912     // padded jrT/wT row stride (float4-safe)

// kA role boundaries
#define TR2 54         // LDS-tiled transpose: ceil(NV/128)
#define RODB 48        // rodrigues: NBATCH*NJNT/256
#define SJB 264        // SJ: 24*11
#define PMA 5913       // Pm rows: 219 * 27 chunks
#define PMO 27         // ones-row chunks
#define PMZ 1323       // 49 pad rows * 27
#define PMT (PMA + PMO + PMZ)
// kB role boundaries
#define CHB 48         // chainP: NBATCH*NJNT/256
#define C4R 1728       // short4 per Cb row
#define CMB (NJKP * C4R / 256)   // 3456 kCm blocks
// D4: rows 0..217 = (D[3r],D[3r+1],D[3r+2],0); row 218 = (c0,0,0,0)
#define D4R 219
// k_S5b r-split
#define RSP 2
#define RCH 109        // 2*109 = 218 exactly
#define SSTRIDE ((size_t)NBATCH * 3 * NJK)   // one Spart slice

typedef __attribute__((ext_vector_type(8))) short bfx8;
typedef __attribute__((ext_vector_type(4))) float fx4;

#define LDSP(x) ((__attribute__((address_space(3))) void*)(x))
#define GLBP(x) ((const __attribute__((address_space(1))) void*)(x))

__constant__ int d_par[NJNT] = {0,0,0,0,1,2,3,4,5,6,7,8,9,9,9,12,13,14,16,17,18,19,20,21};
// ancestor path (root..j) per joint, -1 padded; max depth 9
__constant__ int d_path[NJNT][9] = {
  {0,-1,-1,-1,-1,-1,-1,-1,-1},
  {0,1,-1,-1,-1,-1,-1,-1,-1},
  {0,2,-1,-1,-1,-1,-1,-1,-1},
  {0,3,-1,-1,-1,-1,-1,-1,-1},
  {0,1,4,-1,-1,-1,-1,-1,-1},
  {0,2,5,-1,-1,-1,-1,-1,-1},
  {0,3,6,-1,-1,-1,-1,-1,-1},
  {0,1,4,7,-1,-1,-1,-1,-1},
  {0,2,5,8,-1,-1,-1,-1,-1},
  {0,3,6,9,-1,-1,-1,-1,-1},
  {0,1,4,7,10,-1,-1,-1,-1},
  {0,2,5,8,11,-1,-1,-1,-1},
  {0,3,6,9,12,-1,-1,-1,-1},
  {0,3,6,9,13,-1,-1,-1,-1},
  {0,3,6,9,14,-1,-1,-1,-1},
  {0,3,6,9,12,15,-1,-1,-1},
  {0,3,6,9,13,16,-1,-1,-1},
  {0,3,6,9,14,17,-1,-1,-1},
  {0,3,6,9,13,16,18,-1,-1},
  {0,3,6,9,14,17,19,-1,-1},
  {0,3,6,9,13,16,18,20,-1},
  {0,3,6,9,14,17,19,21,-1},
  {0,3,6,9,13,16,18,20,22},
  {0,3,6,9,14,17,19,21,23}};

__device__ inline short f2bf(float f) {
  union { float f; unsigned u; } x; x.f = f;
  unsigned r = (x.u + 0x7fffu + ((x.u >> 16) & 1u)) >> 16;
  return (short)r;
}

// ============ kA: LDS-tiled transpose || rodrigues(b,j) || SJ || Pm ============
// All roles consume only kernel INPUTS — no intra-dispatch dependencies.
__global__ void __launch_bounds__(256) kA(const float* __restrict__ jr,
                                          const float* __restrict__ lbs,
                                          const float* __restrict__ Jreg,
                                          const float* __restrict__ sdirs,
                                          const float* __restrict__ vtmpl,
                                          const float* __restrict__ theta,
                                          const float* __restrict__ beta,
                                          const float* __restrict__ pdirs,
                                          float* __restrict__ jrT, float* __restrict__ wT,
                                          float* __restrict__ SJ, float* __restrict__ Rs,
                                          float* __restrict__ pfc,
                                          short* __restrict__ Pb) {
  __shared__ float red[4][3];
  __shared__ float tj[128 * NJO];    // 9.5KB
  __shared__ float tw[128 * NJNT];   // 12KB
  int bx = blockIdx.x, tid = threadIdx.x;
  if (bx < TR2) {
    // ---- transpose via LDS tile: coalesced reads AND writes ----
    int v0 = bx * 128;
    for (int i = tid; i < 128 * NJO; i += 256) {
      int g = v0 * NJO + i;
      tj[i] = (g < NV * NJO) ? jr[g] : 0.f;
    }
    for (int i = tid; i < 128 * NJNT; i += 256) {
      int g = v0 * NJNT + i;
      tw[i] = (g < NV * NJNT) ? lbs[g] : 0.f;
    }
    __syncthreads();
    for (int i = tid; i < 128 * (NJO + NJNT); i += 256) {
      int r = i >> 7, c = i & 127;
      int v = v0 + c;
      if (v >= NV) continue;
      if (r < NJO) jrT[(size_t)r * CSTRV + v] = tj[c * NJO + r];
      else         wT[(size_t)(r - NJO) * CSTRV + v] = tw[c * NJNT + (r - NJO)];
    }
  } else if (bx < TR2 + RODB) {
    int t2 = (bx - TR2) * 256 + tid;
    int b = t2 / NJNT, j = t2 - b * NJNT;
    float a0 = theta[b * 72 + j * 3 + 0];
    float a1 = theta[b * 72 + j * 3 + 1];
    float a2 = theta[b * 72 + j * 3 + 2];
    float e0 = a0 + 1e-8f, e1 = a1 + 1e-8f, e2 = a2 + 1e-8f;
    float ang = sqrtf(e0 * e0 + e1 * e1 + e2 * e2);
    float inv = 1.0f / ang;
    float h = 0.5f * ang;
    float w = cosf(h), s = sinf(h);
    float x = a0 * inv * s, y = a1 * inv * s, z = a2 * inv * s;
    float R[9];
    R[0] = w*w + x*x - y*y - z*z; R[1] = 2.f*(x*y - w*z); R[2] = 2.f*(x*z + w*y);
    R[3] = 2.f*(x*y + w*z); R[4] = w*w - x*x + y*y - z*z; R[5] = 2.f*(y*z - w*x);
    R[6] = 2.f*(x*z - w*y); R[7] = 2.f*(y*z + w*x); R[8] = w*w - x*x - y*y + z*z;
#pragma unroll
    for (int r = 0; r < 9; ++r) Rs[b * 216 + j * 9 + r] = R[r];
    if (j >= 1) {
#pragma unroll
      for (int r = 0; r < 9; ++r)
        pfc[b * CSTR + (j - 1) * 9 + r] = R[r] - ((r % 4 == 0) ? 1.0f : 0.0f);
    } else {
#pragma unroll
      for (int i = 0; i < NBETA; ++i) pfc[b * CSTR + NPF + i] = beta[b * NBETA + i];
      pfc[b * CSTR + NPF + NBETA] = 1.0f;
    }
  } else if (bx < TR2 + RODB + SJB) {
    int s = bx - TR2 - RODB;
    int j = s % NJNT, k = s / NJNT;
    const float* src = (k < NBETA) ? (sdirs + (size_t)k * N3) : vtmpl;
    float a0 = 0.f, a1 = 0.f, a2 = 0.f;
    for (int v = tid; v < NV; v += 256) {
      float w = Jreg[v * NJNT + j];
      a0 += w * src[v * 3 + 0];
      a1 += w * src[v * 3 + 1];
      a2 += w * src[v * 3 + 2];
    }
    int lane = tid & 63, wid = tid >> 6;
#pragma unroll
    for (int s2 = 1; s2 < 64; s2 <<= 1) {
      a0 += __shfl_xor(a0, s2); a1 += __shfl_xor(a1, s2); a2 += __shfl_xor(a2, s2);
    }
    if (lane == 0) { red[wid][0] = a0; red[wid][1] = a1; red[wid][2] = a2; }
    __syncthreads();
    if (tid == 0) {
      float* o = SJ + (k * NJNT + j) * 3;
      o[0] = red[0][0] + red[1][0] + red[2][0] + red[3][0];
      o[1] = red[0][1] + red[1][1] + red[2][1] + red[3][1];
      o[2] = red[0][2] + red[1][2] + red[2][2] + red[3][2];
    }
  } else {
    int s4 = bx - TR2 - RODB - SJB;
    if (s4 < PMA) {
      int s = s4 / 27, g = s4 - s * 27;
      const float* src; int base;
      if (s < 207)      { src = pdirs + (size_t)s * N3;         base = 3 * s; }
      else if (s < 217) { src = sdirs + (size_t)(s - 207) * N3; base = 621 + 3 * (s - 207); }
      else              { src = vtmpl;                           base = 651; }
      int v = g * 256 + tid;
      float x = 0.f, y = 0.f, z = 0.f;
      if (v < NV) { x = src[3 * v]; y = src[3 * v + 1]; z = src[3 * v + 2]; }
      Pb[(size_t)(base + 0) * KPAD + v] = f2bf(x);
      Pb[(size_t)(base + 1) * KPAD + v] = f2bf(y);
      Pb[(size_t)(base + 2) * KPAD + v] = f2bf(z);
    } else if (s4 < PMA + PMO) {
      int g = s4 - PMA;
      int v = g * 256 + tid;
      Pb[(size_t)654 * KPAD + v] = (v < NV) ? f2bf(1.0f) : (short)0;
    } else {
      int s = s4 - PMA - PMO;
      int row = 655 + s / 27, g = s % 27;
      Pb[(size_t)row * KPAD + g * 256 + tid] = (short)0;
    }
  }
}

// ============ J from SJ/beta, in registers ============
__device__ inline void getJ(const float* __restrict__ SJ, const float* bb, int i,
                            float& o0, float& o1, float& o2) {
  int r = i * 3;
  float a0 = SJ[NBETA * 72 + r + 0];
  float a1 = SJ[NBETA * 72 + r + 1];
  float a2 = SJ[NBETA * 72 + r + 2];
#pragma unroll
  for (int k = 0; k < NBETA; ++k) {
    a0 += bb[k] * SJ[k * 72 + r + 0];
    a1 += bb[k] * SJ[k * 72 + r + 1];
    a2 += bb[k] * SJ[k * 72 + r + 2];
  }
  o0 = a0; o1 = a1; o2 = a2;
}

// ============ kB: chainP || kCm — both consume only kA outputs ============
__global__ void __launch_bounds__(256) kB(const float* __restrict__ beta,
                                          const float* __restrict__ SJ,
                                          const float* __restrict__ Rs,
                                          const float* __restrict__ jrT,
                                          const float* __restrict__ wT,
                                          float* __restrict__ A,
                                          short* __restrict__ Cb) {
  int bx = blockIdx.x, tid = threadIdx.x;
  if (bx < CHB) {
    int idx = bx * 256 + tid;          // exactly NBATCH*NJNT
    int b = idx / NJNT, j = idx - b * NJNT;
    const float* Rb = Rs + b * 216;
    float bb[NBETA];
#pragma unroll
    for (int k = 0; k < NBETA; ++k) bb[k] = beta[b * NBETA + k];
    float jp0, jp1, jp2;
    getJ(SJ, bb, 0, jp0, jp1, jp2);
    float T[12];
#pragma unroll
    for (int r = 0; r < 3; ++r) {
      T[r * 4 + 0] = Rb[r * 3 + 0];
      T[r * 4 + 1] = Rb[r * 3 + 1];
      T[r * 4 + 2] = Rb[r * 3 + 2];
    }
    T[3] = jp0; T[7] = jp1; T[11] = jp2;
    for (int d = 1; d < 9; ++d) {
      int i = d_path[j][d];
      if (i < 0) break;
      float ji0, ji1, ji2;
      getJ(SJ, bb, i, ji0, ji1, ji2);
      float t0 = ji0 - jp0, t1 = ji1 - jp1, t2 = ji2 - jp2;
      const float* R = Rb + i * 9;
      float R0 = R[0], R1 = R[1], R2 = R[2], R3 = R[3], R4 = R[4];
      float R5 = R[5], R6 = R[6], R7 = R[7], R8 = R[8];
#pragma unroll
      for (int r = 0; r < 3; ++r) {
        float a0 = T[r * 4 + 0], a1 = T[r * 4 + 1], a2 = T[r * 4 + 2];
        T[r * 4 + 0] = a0 * R0 + a1 * R3 + a2 * R6;
        T[r * 4 + 1] = a0 * R1 + a1 * R4 + a2 * R7;
        T[r * 4 + 2] = a0 * R2 + a1 * R5 + a2 * R8;
        T[r * 4 + 3] = a0 * t0 + a1 * t1 + a2 * t2 + T[r * 4 + 3];
      }
      jp0 = ji0; jp1 = ji1; jp2 = ji2;
    }
    float* Ab = A + b * 288 + j * 12;
#pragma unroll
    for (int r = 0; r < 3; ++r) {
      float o0 = T[r * 4 + 0], o1 = T[r * 4 + 1], o2 = T[r * 4 + 2];
      Ab[r * 4 + 0] = o0;
      Ab[r * 4 + 1] = o1;
      Ab[r * 4 + 2] = o2;
      Ab[r * 4 + 3] = T[r * 4 + 3] - (o0 * jp0 + o1 * jp1 + o2 * jp2);
    }
  } else {
    int idx = (bx - CHB) * 256 + tid;
    int jk = idx / C4R;
    int c4 = idx - jk * C4R;
    int v0 = c4 * 4;
    short4 o;
    if (jk < NJK) {
      int j = jk / NJNT, k = jk - j * NJNT;
      float4 a = *(const float4*)(jrT + (size_t)j * CSTRV + v0);
      float4 w = *(const float4*)(wT + (size_t)k * CSTRV + v0);
      o.x = (v0 + 0 < NV) ? f2bf(a.x * w.x) : (short)0;
      o.y = (v0 + 1 < NV) ? f2bf(a.y * w.y) : (short)0;
      o.z = (v0 + 2 < NV) ? f2bf(a.z * w.z) : (short)0;
      o.w = (v0 + 3 < NV) ? f2bf(a.w * w.w) : (short)0;
    } else {
      o.x = o.y = o.z = o.w = (short)0;
    }
    *(short4*)(Cb + (size_t)jk * KPAD + v0) = o;
  }
}

// ============ MFMA GEMM with global_load_lds (pre-swizzled source) ============
__global__ void __launch_bounds__(256) k_gemm(const short* __restrict__ Pb,
                                              const short* __restrict__ Cb,
                                              float* __restrict__ Dpart) {
  int m0 = blockIdx.x * 64;
  int n0 = blockIdx.y * 64;
  int kb0 = blockIdx.z * KCH;
  __shared__ __align__(16) short As[64 * 64];
  __shared__ __align__(16) short Bs[64 * 64];
  int t = threadIdx.x;
  int wid = t >> 6, lane = t & 63;
  int frow = wid * 16 + (lane & 15);
  int fgrp = lane >> 4;
  fx4 acc[4];
#pragma unroll
  for (int j = 0; j < 4; ++j)
#pragma unroll
    for (int r = 0; r < 4; ++r) acc[j][r] = 0.f;

  int lrow = lane >> 3;
  int gsrc = (lane & 7) ^ lrow;
  int rb0 = wid * 8;
  int rb1 = 32 + wid * 8;
  const short* srcA0 = Pb + (size_t)(m0 + rb0 + lrow) * KPAD + kb0 + gsrc * 8;
  const short* srcA1 = Pb + (size_t)(m0 + rb1 + lrow) * KPAD + kb0 + gsrc * 8;
  const short* srcB0 = Cb + (size_t)(n0 + rb0 + lrow) * KPAD + kb0 + gsrc * 8;
  const short* srcB1 = Cb + (size_t)(n0 + rb1 + lrow) * KPAD + kb0 + gsrc * 8;
  short* dstA0 = As + rb0 * 64;
  short* dstA1 = As + rb1 * 64;
  short* dstB0 = Bs + rb0 * 64;
  short* dstB1 = Bs + rb1 * 64;

  for (int kk = 0; kk < KCH / 64; ++kk) {
    __builtin_amdgcn_global_load_lds(GLBP(srcA0), LDSP(dstA0), 16, 0, 0);
    __builtin_amdgcn_global_load_lds(GLBP(srcA1), LDSP(dstA1), 16, 0, 0);
    __builtin_amdgcn_global_load_lds(GLBP(srcB0), LDSP(dstB0), 16, 0, 0);
    __builtin_amdgcn_global_load_lds(GLBP(srcB1), LDSP(dstB1), 16, 0, 0);
    srcA0 += 64; srcA1 += 64; srcB0 += 64; srcB1 += 64;
    __syncthreads();
#pragma unroll
    for (int ks = 0; ks < 2; ++ks) {
      int ga = ks * 4 + fgrp;
      bfx8 a = *(const bfx8*)(As + frow * 64 + (ga ^ (frow & 7)) * 8);
#pragma unroll
      for (int j = 0; j < 4; ++j) {
        int bcol = j * 16 + (lane & 15);
        bfx8 b = *(const bfx8*)(Bs + bcol * 64 + (ga ^ (bcol & 7)) * 8);
        acc[j] = __builtin_amdgcn_mfma_f32_16x16x32_bf16(a, b, acc[j], 0, 0, 0);
      }
    }
    __syncthreads();
  }
  float* dst = Dpart + (size_t)blockIdx.z * PROWSP * NJKP
             + (size_t)(m0 + wid * 16 + (lane >> 4) * 4) * NJKP + n0 + (lane & 15);
#pragma unroll
  for (int j = 0; j < 4; ++j)
#pragma unroll
    for (int r = 0; r < 4; ++r)
      dst[(size_t)r * NJKP + j * 16] = acc[j][r];
}

// ============ k_redD4: K-split reduce + repack for S5b ============
__global__ void k_redD4(const float* __restrict__ Dpart, float* __restrict__ D4) {
  int idx = blockIdx.x * 256 + threadIdx.x;   // D4R*NJKP = 112128
  if (idx >= D4R * NJKP) return;
  int r = idx / NJKP, jk = idx - r * NJKP;
  float4 o;
  if (r < NCOEF) {
    float s0 = 0.f, s1 = 0.f, s2 = 0.f;
#pragma unroll
    for (int z = 0; z < KSPLIT; ++z) {
      const float* dp = Dpart + (size_t)z * PROWSP * NJKP + jk;
      s0 += dp[(size_t)(3 * r + 0) * NJKP];
      s1 += dp[(size_t)(3 * r + 1) * NJKP];
      s2 += dp[(size_t)(3 * r + 2) * NJKP];
    }
    o = make_float4(s0, s1, s2, 0.f);
  } else {
    float s = 0.f;
#pragma unroll
    for (int z = 0; z < KSPLIT; ++z)
      s += Dpart[(size_t)z * PROWSP * NJKP + (size_t)654 * NJKP + jk];
    o = make_float4(s, 0.f, 0.f, 0.f);
  }
  ((float4*)D4)[idx] = o;
}

// ============ k_S5b: r-split; ONE float4 load per r-iter (packed D4) ============
__global__ void __launch_bounds__(256) k_S5b(const float* __restrict__ D4,
                                             const float* __restrict__ pfc,
                                             float* __restrict__ Spart) {
  int n0 = blockIdx.x * 64;
  int b0 = blockIdx.y * 8;
  int r0 = blockIdx.z * RCH;
  int r1 = r0 + RCH; if (r1 > NCOEF) r1 = NCOEF;
  int tid = threadIdx.x;
  int jk = tid & 63;
  int bg = (tid >> 6) * 2;          // wave-uniform
  const float4* D4v = (const float4*)D4;
  int jkg = n0 + jk;
  const float* c0p = pfc + (size_t)(b0 + bg + 0) * CSTR;  // wave-uniform base
  const float* c1p = pfc + (size_t)(b0 + bg + 1) * CSTR;
  float a00 = 0.f, a01 = 0.f, a02 = 0.f, a10 = 0.f, a11 = 0.f, a12 = 0.f;
#pragma unroll 4
  for (int r = r0; r < r1; ++r) {
    float4 d = D4v[(size_t)r * NJKP + jkg];
    float c0 = c0p[r];               // s_load (uniform)
    float c1 = c1p[r];
    a00 += c0 * d.x; a01 += c0 * d.y; a02 += c0 * d.z;
    a10 += c1 * d.x; a11 += c1 * d.y; a12 += c1 * d.z;
  }
  if (jkg < NJK) {
    float* base = Spart + (size_t)blockIdx.z * SSTRIDE;
    float* o0 = base + ((size_t)(b0 + bg + 0) * 3) * NJK + jkg;
    float* o1 = base + ((size_t)(b0 + bg + 1) * 3) * NJK + jkg;
    o0[0 * NJK] = a00; o0[1 * NJK] = a01; o0[2 * NJK] = a02;
    o1[0 * NJK] = a10; o1[1 * NJK] = a11; o1[2 * NJK] = a12;
  }
}

// ============ k_final3: LDS-staged epilogue; 2 batches/block, all-coalesced ============
// Stages Spart (z-summed in ascending order — identical to old redS), A, and c0
// into LDS; compute is pure LDS+FMA. Bit-identical to final2.
__global__ void __launch_bounds__(128) k_final3(const float* __restrict__ Spart,
                                                const float* __restrict__ D4,
                                                const float* __restrict__ A,
                                                float* __restrict__ out) {
  __shared__ float S_ls[2 * 3 * NJK];   // 10.9KB
  __shared__ float A_ls[2 * 288];       // 2.3KB
  __shared__ float c0_ls[NJK];          // 1.8KB
  int blk = blockIdx.x, tid = threadIdx.x;
  int b0 = blk * 2;
  size_t sbase = (size_t)(b0 * 3) * NJK;
  // stage Spart z0+z1 (ascending z order)
  for (int i = tid; i < 2 * 3 * NJK; i += 128)
    S_ls[i] = Spart[sbase + i] + Spart[SSTRIDE + sbase + i];
  // stage A for both batches (contiguous)
  for (int i = tid; i < 2 * 288; i += 128)
    A_ls[i] = A[(size_t)b0 * 288 + i];
  // stage c0 (strided x-components of D4 row 218)
  for (int i = tid; i < NJK; i += 128)
    c0_ls[i] = D4[((size_t)NCOEF * NJKP + i) * 4];
  __syncthreads();
  if (tid >= 2 * NJO * 3) return;
  int bq = tid / 57, r = tid - bq * 57;
  int j = r / 3, c = r - j * 3;
  const float* S0 = S_ls + (bq * 3 + 0) * NJK + j * NJNT;
  const float* S1 = S_ls + (bq * 3 + 1) * NJK + j * NJNT;
  const float* S2 = S_ls + (bq * 3 + 2) * NJK + j * NJNT;
  const float* Ab = A_ls + bq * 288;
  const float* cc = c0_ls + j * NJNT;
  float acc = 0.f;
#pragma unroll 4
  for (int k = 0; k < NJNT; ++k) {
    const float* Ar = Ab + k * 12 + c * 4;
    acc += Ar[0] * S0[k] + Ar[1] * S1[k] + Ar[2] * S2[k] + Ar[3] * cc[k];
  }
  out[(size_t)(b0 + bq) * 57 + r] = acc;
}

extern "C" void kernel_launch(void* const* d_in, const int* in_sizes, int n_in,
                              void* d_out, int out_size, void* d_ws, size_t ws_size,
                              hipStream_t stream) {
  const float* beta  = (const float*)d_in[0];
  const float* theta = (const float*)d_in[1];
  const float* vtmpl = (const float*)d_in[2];
  const float* sdirs = (const float*)d_in[3];
  const float* Jreg  = (const float*)d_in[4];
  const float* pdirs = (const float*)d_in[5];
  const float* lbs   = (const float*)d_in[6];
  const float* jreg2 = (const float*)d_in[7];
  float* out = (float*)d_out;

  float* ws    = (float*)d_ws;
  short* Cb    = (short*)ws;                              // 512*6912 bf16
  short* Pb    = Cb + (size_t)NJKP * KPAD;                // 704*6912 bf16
  float* Dpart = (float*)(Pb + (size_t)PROWSP * KPAD);    // 12*704*512 f32
  float* D4    = Dpart + (size_t)KSPLIT * PROWSP * NJKP;  // 219*512*4
  float* Spart = D4    + (size_t)D4R * NJKP * 4;          // 2*512*3*456
  float* pfc   = Spart + (size_t)RSP * SSTRIDE;           // 512*224
  float* Rs    = pfc   + (size_t)NBATCH * CSTR;           // 512*216
  float* A     = Rs    + (size_t)NBATCH * 216;            // 512*288
  float* jrT   = A     + (size_t)NBATCH * 288;            // 19*6912 (padded)
  float* wT    = jrT   + (size_t)NJO * CSTRV;             // 24*6912 (padded)
  float* SJ    = wT    + (size_t)NJNT * CSTRV;            // 11*72

  kA<<<dim3(TR2 + RODB + SJB + PMT), 256, 0, stream>>>(
      jreg2, lbs, Jreg, sdirs, vtmpl, theta, beta, pdirs,
      jrT, wT, SJ, Rs, pfc, Pb);
  kB<<<dim3(CHB + CMB), 256, 0, stream>>>(beta, SJ, Rs, jrT, wT, A, Cb);
  k_gemm<<<dim3(PROWSP / 64, NJKP / 64, KSPLIT), 256, 0, stream>>>(Pb, Cb, Dpart);
  k_redD4<<<dim3((D4R * NJKP + 255) / 256), 256, 0, stream>>>(Dpart, D4);
  k_S5b<<<dim3(NJKP / 64, NBATCH / 8, RSP), 256, 0, stream>>>(D4, pfc, Spart);
  k_final3<<<dim3(NBATCH / 2), 128, 0, stream>>>(Spart, D4, A, out);
}

// Round 19
// 79.431 us; speedup vs baseline: 2.5095x; 1.0928x over previous
//
#include <hip/hip_runtime.h>
#include <math.h>

#define NV 6890
#define N3 20670       // NV*3
#define NJNT 24
#define NBETA 10
#define NPF 207
#define NJO 19
#define NBATCH 512
#define NJK 456        // NJO*NJNT
#define NJKP 512       // padded jk (GEMM N)
#define NCOEF 218      // [pf 207 | beta 10 | 1]
#define PROWSP 768     // padded P rows (GEMM M, 128-row tiles)
#define KPAD 6912      // 12 * 576
#define KSPLIT 12
#define KCH 576        // 9 * 64
#define CSTR 224       // pfc row stride
#define CSTRV 6912     // padded jrT/wT row stride (float4-safe)

// kA role boundaries
#define TR2 54         // LDS-tiled transpose: ceil(NV/128)
#define RODB 48        // rodrigues: NBATCH*NJNT/256
#define SJB 264        // SJ: 24*11
#define PMA 5913       // Pm rows: 219 * 27 chunks
#define PMO 27         // ones-row chunks
#define PMZ 3051       // 113 pad rows (655..767) * 27
#define PMT (PMA + PMO + PMZ)
// kB role boundaries
#define CHB 48         // chainP: NBATCH*NJNT/256
#define C4R 1728       // short4 per Cb row
#define CMB (NJKP * C4R / 256)   // 3456 kCm blocks
// D4: rows 0..217 = (D[3r],D[3r+1],D[3r+2],0); row 218 = (c0,0,0,0)
#define D4R 219
// k_S5b r-split
#define RSP 2
#define RCH 109        // 2*109 = 218 exactly
#define SSTRIDE ((size_t)NBATCH * 3 * NJK)   // one Spart slice

typedef __attribute__((ext_vector_type(8))) short bfx8;
typedef __attribute__((ext_vector_type(4))) float fx4;

#define LDSP(x) ((__attribute__((address_space(3))) void*)(x))
#define GLBP(x) ((const __attribute__((address_space(1))) void*)(x))

__constant__ int d_par[NJNT] = {0,0,0,0,1,2,3,4,5,6,7,8,9,9,9,12,13,14,16,17,18,19,20,21};
// ancestor path (root..j) per joint, -1 padded; max depth 9
__constant__ int d_path[NJNT][9] = {
  {0,-1,-1,-1,-1,-1,-1,-1,-1},
  {0,1,-1,-1,-1,-1,-1,-1,-1},
  {0,2,-1,-1,-1,-1,-1,-1,-1},
  {0,3,-1,-1,-1,-1,-1,-1,-1},
  {0,1,4,-1,-1,-1,-1,-1,-1},
  {0,2,5,-1,-1,-1,-1,-1,-1},
  {0,3,6,-1,-1,-1,-1,-1,-1},
  {0,1,4,7,-1,-1,-1,-1,-1},
  {0,2,5,8,-1,-1,-1,-1,-1},
  {0,3,6,9,-1,-1,-1,-1,-1},
  {0,1,4,7,10,-1,-1,-1,-1},
  {0,2,5,8,11,-1,-1,-1,-1},
  {0,3,6,9,12,-1,-1,-1,-1},
  {0,3,6,9,13,-1,-1,-1,-1},
  {0,3,6,9,14,-1,-1,-1,-1},
  {0,3,6,9,12,15,-1,-1,-1},
  {0,3,6,9,13,16,-1,-1,-1},
  {0,3,6,9,14,17,-1,-1,-1},
  {0,3,6,9,13,16,18,-1,-1},
  {0,3,6,9,14,17,19,-1,-1},
  {0,3,6,9,13,16,18,20,-1},
  {0,3,6,9,14,17,19,21,-1},
  {0,3,6,9,13,16,18,20,22},
  {0,3,6,9,14,17,19,21,23}};

__device__ inline short f2bf(float f) {
  union { float f; unsigned u; } x; x.f = f;
  unsigned r = (x.u + 0x7fffu + ((x.u >> 16) & 1u)) >> 16;
  return (short)r;
}

// ============ kA: LDS-tiled transpose || rodrigues(b,j) || SJ || Pm ============
// All roles consume only kernel INPUTS — no intra-dispatch dependencies.
__global__ void __launch_bounds__(256) kA(const float* __restrict__ jr,
                                          const float* __restrict__ lbs,
                                          const float* __restrict__ Jreg,
                                          const float* __restrict__ sdirs,
                                          const float* __restrict__ vtmpl,
                                          const float* __restrict__ theta,
                                          const float* __restrict__ beta,
                                          const float* __restrict__ pdirs,
                                          float* __restrict__ jrT, float* __restrict__ wT,
                                          float* __restrict__ SJ, float* __restrict__ Rs,
                                          float* __restrict__ pfc,
                                          short* __restrict__ Pb) {
  __shared__ float red[4][3];
  __shared__ float tj[128 * NJO];    // 9.5KB
  __shared__ float tw[128 * NJNT];   // 12KB
  int bx = blockIdx.x, tid = threadIdx.x;
  if (bx < TR2) {
    // ---- transpose via LDS tile: coalesced reads AND writes ----
    int v0 = bx * 128;
    for (int i = tid; i < 128 * NJO; i += 256) {
      int g = v0 * NJO + i;
      tj[i] = (g < NV * NJO) ? jr[g] : 0.f;
    }
    for (int i = tid; i < 128 * NJNT; i += 256) {
      int g = v0 * NJNT + i;
      tw[i] = (g < NV * NJNT) ? lbs[g] : 0.f;
    }
    __syncthreads();
    for (int i = tid; i < 128 * (NJO + NJNT); i += 256) {
      int r = i >> 7, c = i & 127;
      int v = v0 + c;
      if (v >= NV) continue;
      if (r < NJO) jrT[(size_t)r * CSTRV + v] = tj[c * NJO + r];
      else         wT[(size_t)(r - NJO) * CSTRV + v] = tw[c * NJNT + (r - NJO)];
    }
  } else if (bx < TR2 + RODB) {
    int t2 = (bx - TR2) * 256 + tid;
    int b = t2 / NJNT, j = t2 - b * NJNT;
    float a0 = theta[b * 72 + j * 3 + 0];
    float a1 = theta[b * 72 + j * 3 + 1];
    float a2 = theta[b * 72 + j * 3 + 2];
    float e0 = a0 + 1e-8f, e1 = a1 + 1e-8f, e2 = a2 + 1e-8f;
    float ang = sqrtf(e0 * e0 + e1 * e1 + e2 * e2);
    float inv = 1.0f / ang;
    float h = 0.5f * ang;
    float w = cosf(h), s = sinf(h);
    float x = a0 * inv * s, y = a1 * inv * s, z = a2 * inv * s;
    float R[9];
    R[0] = w*w + x*x - y*y - z*z; R[1] = 2.f*(x*y - w*z); R[2] = 2.f*(x*z + w*y);
    R[3] = 2.f*(x*y + w*z); R[4] = w*w - x*x + y*y - z*z; R[5] = 2.f*(y*z - w*x);
    R[6] = 2.f*(x*z - w*y); R[7] = 2.f*(y*z + w*x); R[8] = w*w - x*x - y*y + z*z;
#pragma unroll
    for (int r = 0; r < 9; ++r) Rs[b * 216 + j * 9 + r] = R[r];
    if (j >= 1) {
#pragma unroll
      for (int r = 0; r < 9; ++r)
        pfc[b * CSTR + (j - 1) * 9 + r] = R[r] - ((r % 4 == 0) ? 1.0f : 0.0f);
    } else {
#pragma unroll
      for (int i = 0; i < NBETA; ++i) pfc[b * CSTR + NPF + i] = beta[b * NBETA + i];
      pfc[b * CSTR + NPF + NBETA] = 1.0f;
    }
  } else if (bx < TR2 + RODB + SJB) {
    int s = bx - TR2 - RODB;
    int j = s % NJNT, k = s / NJNT;
    const float* src = (k < NBETA) ? (sdirs + (size_t)k * N3) : vtmpl;
    float a0 = 0.f, a1 = 0.f, a2 = 0.f;
    for (int v = tid; v < NV; v += 256) {
      float w = Jreg[v * NJNT + j];
      a0 += w * src[v * 3 + 0];
      a1 += w * src[v * 3 + 1];
      a2 += w * src[v * 3 + 2];
    }
    int lane = tid & 63, wid = tid >> 6;
#pragma unroll
    for (int s2 = 1; s2 < 64; s2 <<= 1) {
      a0 += __shfl_xor(a0, s2); a1 += __shfl_xor(a1, s2); a2 += __shfl_xor(a2, s2);
    }
    if (lane == 0) { red[wid][0] = a0; red[wid][1] = a1; red[wid][2] = a2; }
    __syncthreads();
    if (tid == 0) {
      float* o = SJ + (k * NJNT + j) * 3;
      o[0] = red[0][0] + red[1][0] + red[2][0] + red[3][0];
      o[1] = red[0][1] + red[1][1] + red[2][1] + red[3][1];
      o[2] = red[0][2] + red[1][2] + red[2][2] + red[3][2];
    }
  } else {
    int s4 = bx - TR2 - RODB - SJB;
    if (s4 < PMA) {
      int s = s4 / 27, g = s4 - s * 27;
      const float* src; int base;
      if (s < 207)      { src = pdirs + (size_t)s * N3;         base = 3 * s; }
      else if (s < 217) { src = sdirs + (size_t)(s - 207) * N3; base = 621 + 3 * (s - 207); }
      else              { src = vtmpl;                           base = 651; }
      int v = g * 256 + tid;
      float x = 0.f, y = 0.f, z = 0.f;
      if (v < NV) { x = src[3 * v]; y = src[3 * v + 1]; z = src[3 * v + 2]; }
      Pb[(size_t)(base + 0) * KPAD + v] = f2bf(x);
      Pb[(size_t)(base + 1) * KPAD + v] = f2bf(y);
      Pb[(size_t)(base + 2) * KPAD + v] = f2bf(z);
    } else if (s4 < PMA + PMO) {
      int g = s4 - PMA;
      int v = g * 256 + tid;
      Pb[(size_t)654 * KPAD + v] = (v < NV) ? f2bf(1.0f) : (short)0;
    } else {
      int s = s4 - PMA - PMO;
      int row = 655 + s / 27, g = s % 27;
      Pb[(size_t)row * KPAD + g * 256 + tid] = (short)0;
    }
  }
}

// ============ J from SJ/beta, in registers ============
__device__ inline void getJ(const float* __restrict__ SJ, const float* bb, int i,
                            float& o0, float& o1, float& o2) {
  int r = i * 3;
  float a0 = SJ[NBETA * 72 + r + 0];
  float a1 = SJ[NBETA * 72 + r + 1];
  float a2 = SJ[NBETA * 72 + r + 2];
#pragma unroll
  for (int k = 0; k < NBETA; ++k) {
    a0 += bb[k] * SJ[k * 72 + r + 0];
    a1 += bb[k] * SJ[k * 72 + r + 1];
    a2 += bb[k] * SJ[k * 72 + r + 2];
  }
  o0 = a0; o1 = a1; o2 = a2;
}

// ============ kB: chainP || kCm — both consume only kA outputs ============
__global__ void __launch_bounds__(256) kB(const float* __restrict__ beta,
                                          const float* __restrict__ SJ,
                                          const float* __restrict__ Rs,
                                          const float* __restrict__ jrT,
                                          const float* __restrict__ wT,
                                          float* __restrict__ A,
                                          short* __restrict__ Cb) {
  int bx = blockIdx.x, tid = threadIdx.x;
  if (bx < CHB) {
    int idx = bx * 256 + tid;          // exactly NBATCH*NJNT
    int b = idx / NJNT, j = idx - b * NJNT;
    const float* Rb = Rs + b * 216;
    float bb[NBETA];
#pragma unroll
    for (int k = 0; k < NBETA; ++k) bb[k] = beta[b * NBETA + k];
    float jp0, jp1, jp2;
    getJ(SJ, bb, 0, jp0, jp1, jp2);
    float T[12];
#pragma unroll
    for (int r = 0; r < 3; ++r) {
      T[r * 4 + 0] = Rb[r * 3 + 0];
      T[r * 4 + 1] = Rb[r * 3 + 1];
      T[r * 4 + 2] = Rb[r * 3 + 2];
    }
    T[3] = jp0; T[7] = jp1; T[11] = jp2;
    for (int d = 1; d < 9; ++d) {
      int i = d_path[j][d];
      if (i < 0) break;
      float ji0, ji1, ji2;
      getJ(SJ, bb, i, ji0, ji1, ji2);
      float t0 = ji0 - jp0, t1 = ji1 - jp1, t2 = ji2 - jp2;
      const float* R = Rb + i * 9;
      float R0 = R[0], R1 = R[1], R2 = R[2], R3 = R[3], R4 = R[4];
      float R5 = R[5], R6 = R[6], R7 = R[7], R8 = R[8];
#pragma unroll
      for (int r = 0; r < 3; ++r) {
        float a0 = T[r * 4 + 0], a1 = T[r * 4 + 1], a2 = T[r * 4 + 2];
        T[r * 4 + 0] = a0 * R0 + a1 * R3 + a2 * R6;
        T[r * 4 + 1] = a0 * R1 + a1 * R4 + a2 * R7;
        T[r * 4 + 2] = a0 * R2 + a1 * R5 + a2 * R8;
        T[r * 4 + 3] = a0 * t0 + a1 * t1 + a2 * t2 + T[r * 4 + 3];
      }
      jp0 = ji0; jp1 = ji1; jp2 = ji2;
    }
    float* Ab = A + b * 288 + j * 12;
#pragma unroll
    for (int r = 0; r < 3; ++r) {
      float o0 = T[r * 4 + 0], o1 = T[r * 4 + 1], o2 = T[r * 4 + 2];
      Ab[r * 4 + 0] = o0;
      Ab[r * 4 + 1] = o1;
      Ab[r * 4 + 2] = o2;
      Ab[r * 4 + 3] = T[r * 4 + 3] - (o0 * jp0 + o1 * jp1 + o2 * jp2);
    }
  } else {
    int idx = (bx - CHB) * 256 + tid;
    int jk = idx / C4R;
    int c4 = idx - jk * C4R;
    int v0 = c4 * 4;
    short4 o;
    if (jk < NJK) {
      int j = jk / NJNT, k = jk - j * NJNT;
      float4 a = *(const float4*)(jrT + (size_t)j * CSTRV + v0);
      float4 w = *(const float4*)(wT + (size_t)k * CSTRV + v0);
      o.x = (v0 + 0 < NV) ? f2bf(a.x * w.x) : (short)0;
      o.y = (v0 + 1 < NV) ? f2bf(a.y * w.y) : (short)0;
      o.z = (v0 + 2 < NV) ? f2bf(a.z * w.z) : (short)0;
      o.w = (v0 + 3 < NV) ? f2bf(a.w * w.w) : (short)0;
    } else {
      o.x = o.y = o.z = o.w = (short)0;
    }
    *(short4*)(Cb + (size_t)jk * KPAD + v0) = o;
  }
}

// ============ MFMA GEMM: 128(M)x64(N) tile, 16 MFMA/wave/K-step ============
// Linear LDS dest via global_load_lds; source col-group pre-XOR'd (g ^= row&7)
// so the read path's swizzle is unchanged. Same per-element MFMA K-order as the
// 64x64 version -> bit-identical D.
__global__ void __launch_bounds__(256) k_gemm(const short* __restrict__ Pb,
                                              const short* __restrict__ Cb,
                                              float* __restrict__ Dpart) {
  int m0 = blockIdx.x * 128;  // 6
  int n0 = blockIdx.y * 64;   // 8
  int kb0 = blockIdx.z * KCH; // 12
  __shared__ __align__(16) short As[128 * 64];  // 16KB
  __shared__ __align__(16) short Bs[64 * 64];   // 8KB
  int t = threadIdx.x;
  int wid = t >> 6, lane = t & 63;
  int fgrp = lane >> 4;
  fx4 acc[2][4];
#pragma unroll
  for (int r2 = 0; r2 < 2; ++r2)
#pragma unroll
    for (int j = 0; j < 4; ++j)
#pragma unroll
      for (int r = 0; r < 4; ++r) acc[r2][j][r] = 0.f;

  int lrow = lane >> 3;
  int gsrc = (lane & 7) ^ lrow;
  const short* sA[4]; short* dA[4];
#pragma unroll
  for (int i = 0; i < 4; ++i) {
    int rb = wid * 8 + i * 32;
    sA[i] = Pb + (size_t)(m0 + rb + lrow) * KPAD + kb0 + gsrc * 8;
    dA[i] = As + rb * 64;
  }
  const short* sB[2]; short* dB[2];
#pragma unroll
  for (int i = 0; i < 2; ++i) {
    int rb = wid * 8 + i * 32;
    sB[i] = Cb + (size_t)(n0 + rb + lrow) * KPAD + kb0 + gsrc * 8;
    dB[i] = Bs + rb * 64;
  }

  for (int kk = 0; kk < KCH / 64; ++kk) {
#pragma unroll
    for (int i = 0; i < 4; ++i) {
      __builtin_amdgcn_global_load_lds(GLBP(sA[i]), LDSP(dA[i]), 16, 0, 0);
      sA[i] += 64;
    }
#pragma unroll
    for (int i = 0; i < 2; ++i) {
      __builtin_amdgcn_global_load_lds(GLBP(sB[i]), LDSP(dB[i]), 16, 0, 0);
      sB[i] += 64;
    }
    __syncthreads();
#pragma unroll
    for (int ks = 0; ks < 2; ++ks) {
      int ga = ks * 4 + fgrp;
#pragma unroll
      for (int r2 = 0; r2 < 2; ++r2) {
        int arow = wid * 32 + r2 * 16 + (lane & 15);
        bfx8 a = *(const bfx8*)(As + arow * 64 + (ga ^ (arow & 7)) * 8);
#pragma unroll
        for (int j = 0; j < 4; ++j) {
          int bcol = j * 16 + (lane & 15);
          bfx8 b = *(const bfx8*)(Bs + bcol * 64 + (ga ^ (bcol & 7)) * 8);
          acc[r2][j] = __builtin_amdgcn_mfma_f32_16x16x32_bf16(a, b, acc[r2][j], 0, 0, 0);
        }
      }
    }
    __syncthreads();
  }
  float* dz = Dpart + (size_t)blockIdx.z * PROWSP * NJKP;
#pragma unroll
  for (int r2 = 0; r2 < 2; ++r2) {
    float* dst = dz + (size_t)(m0 + wid * 32 + r2 * 16 + (lane >> 4) * 4) * NJKP
               + n0 + (lane & 15);
#pragma unroll
    for (int j = 0; j < 4; ++j)
#pragma unroll
      for (int r = 0; r < 4; ++r)
        dst[(size_t)r * NJKP + j * 16] = acc[r2][j][r];
  }
}

// ============ k_redD4: K-split reduce + repack for S5b ============
__global__ void k_redD4(const float* __restrict__ Dpart, float* __restrict__ D4) {
  int idx = blockIdx.x * 256 + threadIdx.x;   // D4R*NJKP = 112128
  if (idx >= D4R * NJKP) return;
  int r = idx / NJKP, jk = idx - r * NJKP;
  float4 o;
  if (r < NCOEF) {
    float s0 = 0.f, s1 = 0.f, s2 = 0.f;
#pragma unroll
    for (int z = 0; z < KSPLIT; ++z) {
      const float* dp = Dpart + (size_t)z * PROWSP * NJKP + jk;
      s0 += dp[(size_t)(3 * r + 0) * NJKP];
      s1 += dp[(size_t)(3 * r + 1) * NJKP];
      s2 += dp[(size_t)(3 * r + 2) * NJKP];
    }
    o = make_float4(s0, s1, s2, 0.f);
  } else {
    float s = 0.f;
#pragma unroll
    for (int z = 0; z < KSPLIT; ++z)
      s += Dpart[(size_t)z * PROWSP * NJKP + (size_t)654 * NJKP + jk];
    o = make_float4(s, 0.f, 0.f, 0.f);
  }
  ((float4*)D4)[idx] = o;
}

// ============ k_S5b: r-split; ONE float4 load per r-iter (packed D4) ============
__global__ void __launch_bounds__(256) k_S5b(const float* __restrict__ D4,
                                             const float* __restrict__ pfc,
                                             float* __restrict__ Spart) {
  int n0 = blockIdx.x * 64;
  int b0 = blockIdx.y * 8;
  int r0 = blockIdx.z * RCH;
  int r1 = r0 + RCH; if (r1 > NCOEF) r1 = NCOEF;
  int tid = threadIdx.x;
  int jk = tid & 63;
  int bg = (tid >> 6) * 2;          // wave-uniform
  const float4* D4v = (const float4*)D4;
  int jkg = n0 + jk;
  const float* c0p = pfc + (size_t)(b0 + bg + 0) * CSTR;  // wave-uniform base
  const float* c1p = pfc + (size_t)(b0 + bg + 1) * CSTR;
  float a00 = 0.f, a01 = 0.f, a02 = 0.f, a10 = 0.f, a11 = 0.f, a12 = 0.f;
#pragma unroll 4
  for (int r = r0; r < r1; ++r) {
    float4 d = D4v[(size_t)r * NJKP + jkg];
    float c0 = c0p[r];               // s_load (uniform)
    float c1 = c1p[r];
    a00 += c0 * d.x; a01 += c0 * d.y; a02 += c0 * d.z;
    a10 += c1 * d.x; a11 += c1 * d.y; a12 += c1 * d.z;
  }
  if (jkg < NJK) {
    float* base = Spart + (size_t)blockIdx.z * SSTRIDE;
    float* o0 = base + ((size_t)(b0 + bg + 0) * 3) * NJK + jkg;
    float* o1 = base + ((size_t)(b0 + bg + 1) * 3) * NJK + jkg;
    o0[0 * NJK] = a00; o0[1 * NJK] = a01; o0[2 * NJK] = a02;
    o1[0 * NJK] = a10; o1[1 * NJK] = a11; o1[2 * NJK] = a12;
  }
}

// ============ k_final3: LDS-staged epilogue; 2 batches/block, all-coalesced ============
__global__ void __launch_bounds__(128) k_final3(const float* __restrict__ Spart,
                                                const float* __restrict__ D4,
                                                const float* __restrict__ A,
                                                float* __restrict__ out) {
  __shared__ float S_ls[2 * 3 * NJK];   // 10.9KB
  __shared__ float A_ls[2 * 288];       // 2.3KB
  __shared__ float c0_ls[NJK];          // 1.8KB
  int blk = blockIdx.x, tid = threadIdx.x;
  int b0 = blk * 2;
  size_t sbase = (size_t)(b0 * 3) * NJK;
  for (int i = tid; i < 2 * 3 * NJK; i += 128)
    S_ls[i] = Spart[sbase + i] + Spart[SSTRIDE + sbase + i];
  for (int i = tid; i < 2 * 288; i += 128)
    A_ls[i] = A[(size_t)b0 * 288 + i];
  for (int i = tid; i < NJK; i += 128)
    c0_ls[i] = D4[((size_t)NCOEF * NJKP + i) * 4];
  __syncthreads();
  if (tid >= 2 * NJO * 3) return;
  int bq = tid / 57, r = tid - bq * 57;
  int j = r / 3, c = r - j * 3;
  const float* S0 = S_ls + (bq * 3 + 0) * NJK + j * NJNT;
  const float* S1 = S_ls + (bq * 3 + 1) * NJK + j * NJNT;
  const float* S2 = S_ls + (bq * 3 + 2) * NJK + j * NJNT;
  const float* Ab = A_ls + bq * 288;
  const float* cc = c0_ls + j * NJNT;
  float acc = 0.f;
#pragma unroll 4
  for (int k = 0; k < NJNT; ++k) {
    const float* Ar = Ab + k * 12 + c * 4;
    acc += Ar[0] * S0[k] + Ar[1] * S1[k] + Ar[2] * S2[k] + Ar[3] * cc[k];
  }
  out[(size_t)(b0 + bq) * 57 + r] = acc;
}

extern "C" void kernel_launch(void* const* d_in, const int* in_sizes, int n_in,
                              void* d_out, int out_size, void* d_ws, size_t ws_size,
                              hipStream_t stream) {
  const float* beta  = (const float*)d_in[0];
  const float* theta = (const float*)d_in[1];
  const float* vtmpl = (const float*)d_in[2];
  const float* sdirs = (const float*)d_in[3];
  const float* Jreg  = (const float*)d_in[4];
  const float* pdirs = (const float*)d_in[5];
  const float* lbs   = (const float*)d_in[6];
  const float* jreg2 = (const float*)d_in[7];
  float* out = (float*)d_out;

  float* ws    = (float*)d_ws;
  short* Cb    = (short*)ws;                              // 512*6912 bf16
  short* Pb    = Cb + (size_t)NJKP * KPAD;                // 768*6912 bf16
  float* Dpart = (float*)(Pb + (size_t)PROWSP * KPAD);    // 12*768*512 f32
  float* D4    = Dpart + (size_t)KSPLIT * PROWSP * NJKP;  // 219*512*4
  float* Spart = D4    + (size_t)D4R * NJKP * 4;          // 2*512*3*456
  float* pfc   = Spart + (size_t)RSP * SSTRIDE;           // 512*224
  float* Rs    = pfc   + (size_t)NBATCH * CSTR;           // 512*216
  float* A     = Rs    + (size_t)NBATCH * 216;            // 512*288
  float* jrT   = A     + (size_t)NBATCH * 288;            // 19*6912 (padded)
  float* wT    = jrT   + (size_t)NJO * CSTRV;             // 24*6912 (padded)
  float* SJ    = wT    + (size_t)NJNT * CSTRV;            // 11*72

  kA<<<dim3(TR2 + RODB + SJB + PMT), 256, 0, stream>>>(
      jreg2, lbs, Jreg, sdirs, vtmpl, theta, beta, pdirs,
      jrT, wT, SJ, Rs, pfc, Pb);
  kB<<<dim3(CHB + CMB), 256, 0, stream>>>(beta, SJ, Rs, jrT, wT, A, Cb);
  k_gemm<<<dim3(PROWSP / 128, NJKP / 64, KSPLIT), 256, 0, stream>>>(Pb, Cb, Dpart);
  k_redD4<<<dim3((D4R * NJKP + 255) / 256), 256, 0, stream>>>(Dpart, D4);
  k_S5b<<<dim3(NJKP / 64, NBATCH / 8, RSP), 256, 0, stream>>>(D4, pfc, Spart);
  k_final3<<<dim3(NBATCH / 2), 128, 0, stream>>>(Spart, D4, A, out);
}